// Round 1
// baseline (2362.024 us; speedup 1.0000x reference)
//
#include <hip/hip_runtime.h>
#include <stdint.h>

typedef unsigned long long u64;
typedef uint32_t u32;

#define NB 32            // batch
#define NKP 1024         // keypoints per image
#define ROWN (NKP*NKP)   // matches row length
#define NSAMP 512        // NUM_SAMPLES
#define ITM 4            // IT_MATCHES
#define ITR 8            // IT_RANSAC
#define CAPC 16384       // speculative candidate capacity per (iter,b)
#define NBIN 2048        // fine histogram bins over key range [2.0, 32.0)
#define KBASE 0xC0000000u  // monotone key of +2.0f

struct Keys { u32 km[ITM][2]; u32 kr[ITM][ITR][2]; };

// ---------------- threefry2x32 (JAX-compatible, 20 rounds) ----------------
__host__ __device__ static inline u32 rotl32(u32 x, int d) { return (x << d) | (x >> (32 - d)); }

__host__ __device__ static inline void tf2x32(u32 k0, u32 k1, u32 x0, u32 x1, u32& o0, u32& o1)
{
    u32 ks2 = k0 ^ k1 ^ 0x1BD11BDAu;
    x0 += k0; x1 += k1;
#define TFR(r) { x0 += x1; x1 = rotl32(x1, r); x1 ^= x0; }
    TFR(13) TFR(15) TFR(26) TFR(6)
    x0 += k1; x1 += ks2 + 1u;
    TFR(17) TFR(29) TFR(16) TFR(24)
    x0 += ks2; x1 += k0 + 2u;
    TFR(13) TFR(15) TFR(26) TFR(6)
    x0 += k0; x1 += k1 + 3u;
    TFR(17) TFR(29) TFR(16) TFR(24)
    x0 += k1; x1 += ks2 + 4u;
    TFR(13) TFR(15) TFR(26) TFR(6)
    x0 += ks2; x1 += k0 + 5u;
#undef TFR
    o0 = x0; o1 = x1;
}

// uniform(key, shape, 1e-6, 1-1e-6) bit-faithful to JAX (partitionable mode):
// bits = o0 ^ o1 at counter (0, flat_index); u = (bits>>9 | 1.0f) - 1; u*span+min; max(min,u)
#define G_MINV 1e-6f
#define G_MAXV ((float)(1.0 - 1e-6))
#define G_SPAN (G_MAXV - G_MINV)

__device__ static inline float u_from_bits(u32 bits) {
    float f = __uint_as_float((bits >> 9) | 0x3f800000u) - 1.0f;
    float u = __fadd_rn(__fmul_rn(f, G_SPAN), G_MINV);  // no FMA contraction (match XLA)
    return fmaxf(G_MINV, u);
}

// monotone float->uint key (order-preserving for all non-NaN)
__device__ static inline u32 fkey(float v) {
    u32 u = __float_as_uint(v);
    return (u & 0x80000000u) ? ~u : (u | 0x80000000u);
}

// 64-lane butterfly sum (uniform result on all lanes)
__device__ static inline float wred(float v) {
    #pragma unroll
    for (int o = 1; o < 64; o <<= 1) v += __shfl_xor(v, o, 64);
    return v;
}

__device__ static inline u64 shfl_xor_u64(u64 v, int mask) {
    u32 lo = (u32)v, hi = (u32)(v >> 32);
    lo = __shfl_xor(lo, mask, 64);
    hi = __shfl_xor(hi, mask, 64);
    return ((u64)hi << 32) | (u64)lo;
}

// ---------------- 3x3 Kabsch via double-precision Jacobi SVD ----------------
// Mirrors: U,S,Vt = svd(H); V; d = det(V@Ut); R = (V*diag(1,1,d)) @ Ut
__device__ static void kabsch(const float Hf[9], float Rf[9])
{
    double H00=Hf[0],H01=Hf[1],H02=Hf[2];
    double H10=Hf[3],H11=Hf[4],H12=Hf[5];
    double H20=Hf[6],H21=Hf[7],H22=Hf[8];
    double A00 = H00*H00 + H10*H10 + H20*H20;
    double A01 = H00*H01 + H10*H11 + H20*H21;
    double A02 = H00*H02 + H10*H12 + H20*H22;
    double A11 = H01*H01 + H11*H11 + H21*H21;
    double A12 = H01*H02 + H11*H12 + H21*H22;
    double A22 = H02*H02 + H12*H12 + H22*H22;
    double V00=1,V10=0,V20=0;  // eigvec column 0 = (V00,V10,V20)
    double V01=0,V11=1,V21=0;
    double V02=0,V12=0,V22=1;
#define JROT(App,Aqq,Apq,Apr,Aqr, Vp0,Vp1,Vp2, Vq0,Vq1,Vq2) \
    if (fabs(Apq) > 0.0) { \
        double th = (Aqq - App) / (2.0 * Apq); \
        double tt = copysign(1.0, th) / (fabs(th) + sqrt(1.0 + th*th)); \
        double cc = 1.0 / sqrt(1.0 + tt*tt); \
        double ss = tt * cc; \
        double npp = App - tt*Apq, nqq = Aqq + tt*Apq; \
        double npr = cc*Apr - ss*Aqr, nqr = ss*Apr + cc*Aqr; \
        App = npp; Aqq = nqq; Apq = 0.0; Apr = npr; Aqr = nqr; \
        double tv; \
        tv = cc*Vp0 - ss*Vq0; Vq0 = ss*Vp0 + cc*Vq0; Vp0 = tv; \
        tv = cc*Vp1 - ss*Vq1; Vq1 = ss*Vp1 + cc*Vq1; Vp1 = tv; \
        tv = cc*Vp2 - ss*Vq2; Vq2 = ss*Vp2 + cc*Vq2; Vp2 = tv; \
    }
    for (int sw = 0; sw < 10; ++sw) {
        JROT(A00,A11,A01, A02,A12, V00,V10,V20, V01,V11,V21);
        JROT(A00,A22,A02, A01,A12, V00,V10,V20, V02,V12,V22);
        JROT(A11,A22,A12, A01,A02, V01,V11,V21, V02,V12,V22);
    }
#undef JROT
    double l0=A00, l1=A11, l2=A22;
    double e0[3]={V00,V10,V20}, e1[3]={V01,V11,V21}, e2[3]={V02,V12,V22};
    if (l0 < l1) { double t=l0;l0=l1;l1=t; for(int c=0;c<3;++c){double s=e0[c];e0[c]=e1[c];e1[c]=s;} }
    if (l0 < l2) { double t=l0;l0=l2;l2=t; for(int c=0;c<3;++c){double s=e0[c];e0[c]=e2[c];e2[c]=s;} }
    if (l1 < l2) { double t=l1;l1=l2;l2=t; for(int c=0;c<3;++c){double s=e1[c];e1[c]=e2[c];e2[c]=s;} }
    double u0[3], u1[3], u2[3];
#define HMUL(e,u) { u[0]=H00*e[0]+H01*e[1]+H02*e[2]; u[1]=H10*e[0]+H11*e[1]+H12*e[2]; u[2]=H20*e[0]+H21*e[1]+H22*e[2]; }
    HMUL(e0,u0) HMUL(e1,u1) HMUL(e2,u2)
#undef HMUL
    double s0 = sqrt(u0[0]*u0[0]+u0[1]*u0[1]+u0[2]*u0[2]);
    double s1 = sqrt(u1[0]*u1[0]+u1[1]*u1[1]+u1[2]*u1[2]);
    double s2 = sqrt(u2[0]*u2[0]+u2[1]*u2[1]+u2[2]*u2[2]);
    double eps = 1e-12 + 1e-6 * s0;
    if (s0 > 0.0) { u0[0]/=s0; u0[1]/=s0; u0[2]/=s0; } else { u0[0]=1.0; u0[1]=0.0; u0[2]=0.0; }
    if (s1 > eps) { u1[0]/=s1; u1[1]/=s1; u1[2]/=s1; }
    else {
        double ax0 = (fabs(u0[0]) < 0.9) ? 1.0 : 0.0;
        double ax1 = 1.0 - ax0;
        double dd = ax0*u0[0] + ax1*u0[1];
        double w0 = ax0 - dd*u0[0], w1 = ax1 - dd*u0[1], w2 = -dd*u0[2];
        double nn = sqrt(w0*w0+w1*w1+w2*w2);
        u1[0]=w0/nn; u1[1]=w1/nn; u1[2]=w2/nn;
    }
    if (s2 > eps) { u2[0]/=s2; u2[1]/=s2; u2[2]/=s2; }
    else {
        u2[0] = u0[1]*u1[2] - u0[2]*u1[1];
        u2[1] = u0[2]*u1[0] - u0[0]*u1[2];
        u2[2] = u0[0]*u1[1] - u0[1]*u1[0];
    }
    // M = V @ U^T ; det
    double M[3][3];
    #pragma unroll
    for (int i2=0;i2<3;++i2)
      #pragma unroll
      for (int j2=0;j2<3;++j2)
        M[i2][j2] = e0[i2]*u0[j2] + e1[i2]*u1[j2] + e2[i2]*u2[j2];
    double det = M[0][0]*(M[1][1]*M[2][2]-M[1][2]*M[2][1])
               - M[0][1]*(M[1][0]*M[2][2]-M[1][2]*M[2][0])
               + M[0][2]*(M[1][0]*M[2][1]-M[1][1]*M[2][0]);
    #pragma unroll
    for (int i2=0;i2<3;++i2)
      #pragma unroll
      for (int j2=0;j2<3;++j2)
        Rf[i2*3+j2] = (float)(e0[i2]*u0[j2] + e1[i2]*u1[j2] + det*(e2[i2]*u2[j2]));
}

__device__ static inline float dist1(const float R[9], const float t[3], const float x[3], const float y[3])
{
    float a = R[0]*x[0]+R[1]*x[1]+R[2]*x[2]+t[0]-y[0];
    float b = R[3]*x[0]+R[4]*x[1]+R[5]*x[2]+t[1]-y[1];
    float c = R[6]*x[0]+R[7]*x[1]+R[8]*x[2]+t[2]-y[2];
    return sqrtf(a*a+b*b+c*c);
}

// weighted Procrustes over the wave's 512 samples (8 per lane); uniform result
__device__ static void proc512(const float (&X)[8][3], const float (&Y)[8][3], const float (&w)[8],
                               float R[9], float t[3])
{
    float sw = 0.f;
    #pragma unroll
    for (int q=0;q<8;++q) sw += w[q];
    float S = wred(sw) + 1e-8f;
    float wn[8];
    #pragma unroll
    for (int q=0;q<8;++q) wn[q] = w[q] / S;
    float mx[3], my[3];
    #pragma unroll
    for (int c=0;c<3;++c) {
        float ax=0.f, ay=0.f;
        #pragma unroll
        for (int q=0;q<8;++q) { ax += wn[q]*X[q][c]; ay += wn[q]*Y[q][c]; }
        mx[c] = wred(ax); my[c] = wred(ay);
    }
    float Hf[9];
    #pragma unroll
    for (int ci=0;ci<3;++ci)
      #pragma unroll
      for (int cj=0;cj<3;++cj) {
        float h=0.f;
        #pragma unroll
        for (int q=0;q<8;++q) h += wn[q]*(X[q][ci]-mx[ci])*(Y[q][cj]-my[cj]);
        Hf[ci*3+cj] = wred(h);
      }
    kabsch(Hf, R);
    #pragma unroll
    for (int c=0;c<3;++c) t[c] = my[c] - (R[c*3+0]*mx[0] + R[c*3+1]*mx[1] + R[c*3+2]*mx[2]);
}

// 3x3 inverse, pivoted Gauss-Jordan (mirrors jnp.linalg.inv up to ulps)
__device__ static void inv3(const float* __restrict__ Kin, float* __restrict__ out)
{
    float a[3][6];
    for (int r=0;r<3;++r) for (int c=0;c<3;++c) { a[r][c]=Kin[r*3+c]; a[r][c+3] = (r==c)?1.f:0.f; }
    for (int col=0; col<3; ++col) {
        int piv = col;
        for (int r=col+1;r<3;++r) if (fabsf(a[r][col]) > fabsf(a[piv][col])) piv = r;
        if (piv != col) for (int c=0;c<6;++c) { float tt=a[col][c]; a[col][c]=a[piv][c]; a[piv][c]=tt; }
        float pv = a[col][col];
        for (int c=0;c<6;++c) a[col][c] /= pv;
        for (int r=0;r<3;++r) if (r != col) {
            float f = a[r][col];
            if (f != 0.f) for (int c=0;c<6;++c) a[r][c] -= f * a[col][c];
        }
    }
    for (int r=0;r<3;++r) for (int c=0;c<3;++c) out[r*3+c] = a[r][c+3];
}

// ---------------- workspace layout ----------------
static const size_t OFF_HIST = 0;                                          // u32[ITM*NB*NBIN]
static const size_t OFF_CNT  = OFF_HIST + (size_t)ITM*NB*NBIN*4;           // u32[ITM*NB]
static const size_t OFF_CUT  = OFF_CNT  + (size_t)ITM*NB*4;                // u32[ITM*NB*2]
static const size_t OFF_SC   = OFF_CUT  + (size_t)ITM*NB*2*4;              // f32[ITM*NB*ITR]
static const size_t OFF_LV   = OFF_SC   + (size_t)ITM*NB*ITR*4;            // f32[ITM*NB*ITR]
static const size_t OFF_SAMP = OFF_LV   + (size_t)ITM*NB*ITR*4;            // f32[ITM*NB*NSAMP*8]
static const size_t OFF_CAND = OFF_SAMP + (size_t)ITM*NB*NSAMP*8*4;        // u64[ITM*NB*CAPC]
static const size_t ZERO_BYTES = OFF_CUT;  // zero hist + counters each call

// ---------------- Kernel A: scan matches, fine hist + speculative collect ----------------
__global__ __launch_bounds__(256) void kA(const float* __restrict__ mat, Keys keys,
                                          u32* __restrict__ ghist, u32* __restrict__ gcnt,
                                          u64* __restrict__ cand)
{
    __shared__ u32 lh[ITM*NBIN];   // 32 KB
    int tid = threadIdx.x;
    int b = blockIdx.y;
    for (int idx = tid; idx < ITM*NBIN; idx += 256) lh[idx] = 0;
    __syncthreads();
    const float4* rowp = reinterpret_cast<const float4*>(mat + (size_t)b * ROWN);
    int base = blockIdx.x * 16384;     // float4 units; 16 chunks cover 262144 float4/row
    for (int itc = 0; itc < 64; ++itc) {
        int f4 = base + itc*256 + tid;
        float4 m4 = rowp[f4];
        float mv[4] = {m4.x, m4.y, m4.z, m4.w};
        u32 j0 = (u32)f4 * 4u;
        #pragma unroll
        for (int e = 0; e < 4; ++e) {
            u32 j = j0 + (u32)e;
            u32 flat = (u32)b * (u32)ROWN + j;
            float lg = 0.f; bool has = false;
            #pragma unroll
            for (int i = 0; i < ITM; ++i) {
                u32 o0, o1; tf2x32(keys.km[i][0], keys.km[i][1], 0u, flat, o0, o1);
                float u = u_from_bits(o0 ^ o1);
                // v > 4 requires gumbel > 3.9999 => u > 0.98185 ; 0.98 is a safe early-out
                if (u > 0.98f) {
                    if (!has) { lg = logf(mv[e] + 1e-12f); has = true; }
                    float g = -logf(-logf(u));
                    float v = lg + g;
                    if (v > 4.0f) {
                        u32 key = fkey(v);
                        u32 bin = (key - KBASE) >> 14;
                        if (bin > (u32)(NBIN-1)) bin = NBIN-1;
                        atomicAdd(&lh[i*NBIN + (int)bin], 1u);
                        u32 pos = atomicAdd(&gcnt[i*NB + b], 1u);
                        if (pos < CAPC)
                            cand[((size_t)(i*NB + b))*CAPC + pos] = ((u64)key << 32) | (u64)(u32)(~j);
                    }
                }
            }
        }
    }
    __syncthreads();
    for (int idx = tid; idx < ITM*NBIN; idx += 256) {
        u32 c = lh[idx];
        if (c) {
            int i = idx / NBIN, bin = idx % NBIN;
            atomicAdd(&ghist[((size_t)(i*NB + b))*NBIN + bin], c);
        }
    }
}

// ---------------- Kernel B: find exact rank-512 cut bin per (iter,b) ----------------
__global__ __launch_bounds__(64) void kB(const u32* __restrict__ ghist, const u32* __restrict__ gcnt,
                                         u32* __restrict__ cut)
{
    int ib = blockIdx.x;
    int lane = threadIdx.x;
    const u32* h = ghist + (size_t)ib * NBIN;
    __shared__ u32 gs[64];
    u32 ssum = 0;
    int top = NBIN-1 - lane*32;
    for (int k = 0; k < 32; ++k) ssum += h[top - k];
    gs[lane] = ssum;
    __syncthreads();
    if (lane == 0) {
        u32 cum = 0; int cutbin = -1;
        for (int g = 0; g < 64; ++g) {
            if (cum + gs[g] >= (u32)NSAMP) {
                int t2 = NBIN-1 - g*32;
                for (int k = 0; k < 32; ++k) {
                    u32 c = h[t2 - k];
                    if (cum + c >= (u32)NSAMP) { cutbin = t2 - k; break; }
                    cum += c;
                }
                break;
            }
            cum += gs[g];
        }
        u32 ok = (cutbin >= 0) && (gcnt[ib] <= (u32)CAPC);
        cut[ib*2+0] = ok ? (KBASE + ((u32)cutbin << 14)) : 0u;
        cut[ib*2+1] = ok;
    }
}

// ---------------- Kernel D: select+sort top-512, build sample tables ----------------
__global__ __launch_bounds__(256) void kD(const float* __restrict__ mat,
        const float* __restrict__ kps0, const float* __restrict__ dep0,
        const float* __restrict__ kps1, const float* __restrict__ dep1,
        const float* __restrict__ K0, const float* __restrict__ K1,
        const u64* __restrict__ cand, const u32* __restrict__ gcnt, const u32* __restrict__ cut,
        float* __restrict__ samp)
{
    int ib = blockIdx.x;
    int b = ib % NB;
    int tid = threadIdx.x;
    __shared__ u64 buf[2048];
    __shared__ u32 nkeep;
    __shared__ float Ki[2][9];
    for (int idx = tid; idx < 2048; idx += 256) buf[idx] = 0ull;
    if (tid == 0) nkeep = 0;
    __syncthreads();
    u32 cutkey = cut[ib*2+0];
    u32 n = gcnt[ib]; if (n > (u32)CAPC) n = CAPC;
    const u64* cd = cand + (size_t)ib * CAPC;
    for (u32 idx = tid; idx < n; idx += 256) {
        u64 c = cd[idx];
        if ((u32)(c >> 32) >= cutkey) {
            u32 p = atomicAdd(&nkeep, 1u);
            if (p < 2048u) buf[p] = c;
        }
    }
    __syncthreads();
    // bitonic ascending; pads (0) sink to the front; top-512 = buf[2047-r]
    for (int k = 2; k <= 2048; k <<= 1) {
        for (int j = k >> 1; j > 0; j >>= 1) {
            for (int i2 = tid; i2 < 2048; i2 += 256) {
                int ixj = i2 ^ j;
                if (ixj > i2) {
                    bool up = ((i2 & k) == 0);
                    u64 a = buf[i2], c2 = buf[ixj];
                    bool dosw = up ? (a > c2) : (a < c2);
                    if (dosw) { buf[i2] = c2; buf[ixj] = a; }
                }
            }
            __syncthreads();
        }
    }
    if (tid == 0) { inv3(K0 + (size_t)b*9, Ki[0]); inv3(K1 + (size_t)b*9, Ki[1]); }
    __syncthreads();
    for (int r = tid; r < NSAMP; r += 256) {
        u64 c = buf[2047 - r];
        u32 j = (~(u32)(c & 0xFFFFFFFFull)) & (u32)(ROWN - 1);
        int i0 = (int)(j >> 10);
        int i1 = (int)(j & 1023u);
        float uu0 = kps0[(size_t)b*2*NKP + i0];
        float vv0 = kps0[(size_t)b*2*NKP + NKP + i0];
        float dd0 = dep0[(size_t)b*2*NKP + i0];
        float uu1 = kps1[(size_t)b*2*NKP + i1];
        float vv1 = kps1[(size_t)b*2*NKP + NKP + i1];
        float dd1 = dep1[(size_t)b*2*NKP + i1];
        float r0 = Ki[0][0]*uu0 + Ki[0][1]*vv0 + Ki[0][2];
        float r1 = Ki[0][3]*uu0 + Ki[0][4]*vv0 + Ki[0][5];
        float r2 = Ki[0][6]*uu0 + Ki[0][7]*vv0 + Ki[0][8];
        float q0 = Ki[1][0]*uu1 + Ki[1][1]*vv1 + Ki[1][2];
        float q1 = Ki[1][3]*uu1 + Ki[1][4]*vv1 + Ki[1][5];
        float q2 = Ki[1][6]*uu1 + Ki[1][7]*vv1 + Ki[1][8];
        float w = mat[(size_t)b*ROWN + j];
        float* sp = samp + ((size_t)ib*NSAMP + r)*8;
        sp[0] = dd0*r0; sp[1] = dd0*r1; sp[2] = dd0*r2;
        sp[3] = dd1*q0; sp[4] = dd1*q1; sp[5] = dd1*q2;
        sp[6] = logf(w + 1e-12f);
        sp[7] = 0.f;
    }
}

// ---------------- Kernel E: one wave per RANSAC hypothesis ----------------
__global__ __launch_bounds__(64) void kE(const float* __restrict__ samp, const float* __restrict__ Tmat,
                                         Keys keys, float* __restrict__ scoreArr, float* __restrict__ lvArr)
{
    int blk = blockIdx.x;
    int kk = blk & 7;
    int ib = blk >> 3;
    int i = ib / NB;
    int b = ib % NB;
    int lane = threadIdx.x;
    const float* s = samp + (size_t)ib * NSAMP * 8;
    float X[8][3], Y[8][3], lw[8];
    #pragma unroll
    for (int q = 0; q < 8; ++q) {
        const float4* p = reinterpret_cast<const float4*>(s + (size_t)(q*64 + lane)*8);
        float4 a0 = p[0], a1 = p[1];
        X[q][0]=a0.x; X[q][1]=a0.y; X[q][2]=a0.z;
        Y[q][0]=a0.w; Y[q][1]=a1.x; Y[q][2]=a1.y;
        lw[q]=a1.z;
    }
    // inner gumbel + composite keys
    u64 comp[8];
    #pragma unroll
    for (int q = 0; q < 8; ++q) {
        u32 j = (u32)(q*64 + lane);
        u32 o0,o1; tf2x32(keys.kr[i][kk][0], keys.kr[i][kk][1], 0u, (u32)(b*NSAMP) + j, o0,o1);
        float u = u_from_bits(o0^o1);
        float g = -logf(-logf(u));
        float v = lw[q] + g;
        comp[q] = ((u64)fkey(v) << 32) | (u64)(u32)(~j);
    }
    // top-5 (value desc, index asc) via 5 wave arg-max rounds
    int ridx[5];
    #pragma unroll
    for (int r = 0; r < 5; ++r) {
        u64 m = comp[0];
        #pragma unroll
        for (int q=1;q<8;++q) if (comp[q] > m) m = comp[q];
        #pragma unroll
        for (int o=1;o<64;o<<=1) { u64 x = shfl_xor_u64(m,o); if (x > m) m = x; }
        ridx[r] = (int)((~(u32)(m & 0xFFFFFFFFull)) & (u32)(NSAMP-1));
        #pragma unroll
        for (int q=0;q<8;++q) if (comp[q] == m) comp[q] = 0ull;
    }
    // 5-point Procrustes (uniform weights) — all lanes compute identically
    float Xk[5][3], Yk[5][3];
    #pragma unroll
    for (int r=0;r<5;++r) {
        const float* p = s + (size_t)ridx[r]*8;
        Xk[r][0]=p[0]; Xk[r][1]=p[1]; Xk[r][2]=p[2];
        Yk[r][0]=p[3]; Yk[r][1]=p[4]; Yk[r][2]=p[5];
    }
    float S5 = 5.0f + 1e-8f;
    float wn5 = 1.0f / S5;
    float mx[3]={0,0,0}, my[3]={0,0,0};
    #pragma unroll
    for (int r=0;r<5;++r) {
        #pragma unroll
        for (int c=0;c<3;++c) { mx[c] += wn5*Xk[r][c]; my[c] += wn5*Yk[r][c]; }
    }
    float Hf[9] = {0,0,0,0,0,0,0,0,0};
    #pragma unroll
    for (int r=0;r<5;++r)
      #pragma unroll
      for (int ci=0;ci<3;++ci)
        #pragma unroll
        for (int cj=0;cj<3;++cj)
          Hf[ci*3+cj] += wn5*(Xk[r][ci]-mx[ci])*(Yk[r][cj]-my[cj]);
    float Rpre[9], tpre[3];
    kabsch(Hf, Rpre);
    #pragma unroll
    for (int c=0;c<3;++c) tpre[c] = my[c] - (Rpre[c*3+0]*mx[0] + Rpre[c*3+1]*mx[1] + Rpre[c*3+2]*mx[2]);
    // score over all 512 samples
    const float BETAF = (float)(5.0/0.15);
    float partial = 0.f;
    #pragma unroll
    for (int q=0;q<8;++q) {
        float d = dist1(Rpre, tpre, X[q], Y[q]);
        float z = BETAF * (0.15f - d);
        partial += 1.0f / (1.0f + expf(-z));
    }
    float score = wred(partial);
    // refinement (4 steps, exact do-gating)
    float inlref[8];
    #pragma unroll
    for (int q=0;q<8;++q) {
        int j = q*64 + lane;
        inlref[q] = (j==ridx[0] || j==ridx[1] || j==ridx[2] || j==ridx[3] || j==ridx[4]) ? 1.0f : 0.0f;
    }
    float Rd[9], td[3];
    #pragma unroll
    for (int c2=0;c2<9;++c2) Rd[c2]=Rpre[c2];
    td[0]=tpre[0]; td[1]=tpre[1]; td[2]=tpre[2];
    float inl_pre = 0.f;
    for (int step=0; step<4; ++step) {
        float inl[8]; float csum = 0.f;
        #pragma unroll
        for (int q=0;q<8;++q) {
            float d = dist1(Rd, td, X[q], Y[q]);
            inl[q] = (d < 0.15f) ? 1.0f : 0.0f;
            csum += inl[q];
        }
        float cnt = wred(csum);
        bool doit = (cnt >= 5.0f) && (cnt > inl_pre);
        inl_pre = cnt;
        if (doit) {
            #pragma unroll
            for (int q=0;q<8;++q) inlref[q] = inl[q];
            proc512(X, Y, inlref, Rd, td);
        }
    }
    // final Procrustes + pose loss
    float Rfin[9], tfin[3];
    proc512(X, Y, inlref, Rfin, tfin);
    const float* Tb = Tmat + (size_t)b*16;
    float tr = 0.f;
    #pragma unroll
    for (int ci=0;ci<3;++ci)
      #pragma unroll
      for (int cj=0;cj<3;++cj)
        tr += Rfin[ci*3+cj] * Tb[ci*4+cj];
    float cosang = (tr - 1.0f) * 0.5f;
    cosang = fminf(fmaxf(cosang, -0.999999f), 0.999999f);
    float ang = acosf(cosang);
    float d0 = tfin[0]-Tb[3], d1 = tfin[1]-Tb[7], d2 = tfin[2]-Tb[11];
    float terr = sqrtf(d0*d0 + d1*d1 + d2*d2);
    float lr = 0.5f * tanhf(ang / 0.5f);
    float lt = 0.5f * tanhf(terr / 0.5f);
    float lv = 0.5f * (lr + lt);
    if (lane == 0) { scoreArr[blk] = score; lvArr[blk] = lv; }
}

// ---------------- Kernel F: softmax mixing + output ----------------
__global__ void kF(const float* __restrict__ scoreArr, const float* __restrict__ lvArr, float* __restrict__ out)
{
    int b = threadIdx.x;
    if (b >= NB) return;
    const float NULLSC = (float)(0.35 * 512.0);
    float total = 0.f;
    for (int i = 0; i < ITM; ++i) {
        float x[9], lvv[9], ee[9];
        for (int k = 0; k < 8; ++k) {
            x[k] = scoreArr[(i*NB + b)*ITR + k] / 10.0f;
            lvv[k] = lvArr[(i*NB + b)*ITR + k];
        }
        x[8] = NULLSC / 10.0f;
        lvv[8] = 0.5f;
        float m = x[0];
        for (int k = 1; k < 9; ++k) m = fmaxf(m, x[k]);
        float Ssum = 0.f;
        for (int k = 0; k < 9; ++k) { ee[k] = expf(x[k] - m); Ssum += ee[k]; }
        float acc = 0.f;
        for (int k = 0; k < 9; ++k) acc += lvv[k] * (ee[k] / Ssum);
        total += acc;
    }
    out[b] = total / 4.0f;
}

// ---------------- host ----------------
extern "C" void kernel_launch(void* const* d_in, const int* in_sizes, int n_in,
                              void* d_out, int out_size, void* d_ws, size_t ws_size,
                              hipStream_t stream)
{
    (void)in_sizes; (void)n_in; (void)out_size; (void)ws_size;
    const float* mat  = (const float*)d_in[0];
    const float* kps0 = (const float*)d_in[1];
    const float* dep0 = (const float*)d_in[2];
    const float* kps1 = (const float*)d_in[3];
    const float* dep1 = (const float*)d_in[4];
    const float* K0   = (const float*)d_in[5];
    const float* K1   = (const float*)d_in[6];
    const float* Tm   = (const float*)d_in[8];
    float* out = (float*)d_out;

    // JAX key schedule: key(42) -> (0,42); split() in partitionable (fold-like) mode:
    // out_j = threefry2x32(key, (0, j)); key=out[0], derived=out[1]
    Keys keys;
    {
        u32 k0 = 0u, k1 = 42u;
        for (int i = 0; i < ITM; ++i) {
            u32 a0,a1,b0,b1;
            tf2x32(k0,k1, 0u,0u, a0,a1);
            tf2x32(k0,k1, 0u,1u, b0,b1);
            k0=a0; k1=a1; keys.km[i][0]=b0; keys.km[i][1]=b1;
            for (int kk = 0; kk < ITR; ++kk) {
                tf2x32(k0,k1, 0u,0u, a0,a1);
                tf2x32(k0,k1, 0u,1u, b0,b1);
                k0=a0; k1=a1; keys.kr[i][kk][0]=b0; keys.kr[i][kk][1]=b1;
            }
        }
    }
    char* ws = (char*)d_ws;
    u32* ghist      = (u32*)(ws + OFF_HIST);
    u32* gcnt       = (u32*)(ws + OFF_CNT);
    u32* cut        = (u32*)(ws + OFF_CUT);
    float* scoreArr = (float*)(ws + OFF_SC);
    float* lvArr    = (float*)(ws + OFF_LV);
    float* samp     = (float*)(ws + OFF_SAMP);
    u64* cand       = (u64*)(ws + OFF_CAND);

    hipMemsetAsync(d_ws, 0, ZERO_BYTES, stream);
    kA<<<dim3(16, NB), 256, 0, stream>>>(mat, keys, ghist, gcnt, cand);
    kB<<<ITM*NB, 64, 0, stream>>>(ghist, gcnt, cut);
    kD<<<ITM*NB, 256, 0, stream>>>(mat, kps0, dep0, kps1, dep1, K0, K1, cand, gcnt, cut, samp);
    kE<<<ITM*NB*ITR, 64, 0, stream>>>(samp, Tm, keys, scoreArr, lvArr);
    kF<<<1, 64, 0, stream>>>(scoreArr, lvArr, out);
}

// Round 2
// 2347.499 us; speedup vs baseline: 1.0062x; 1.0062x over previous
//
#include <hip/hip_runtime.h>
#include <stdint.h>

typedef unsigned long long u64;
typedef uint32_t u32;

#define NB 32            // batch
#define NKP 1024         // keypoints per image
#define ROWN (NKP*NKP)   // matches row length
#define NSAMP 512        // NUM_SAMPLES
#define ITM 4            // IT_MATCHES
#define ITR 8            // IT_RANSAC
#define CAPC 16384       // speculative candidate capacity per (iter,b)
#define NBIN 2048        // fine histogram bins over key range [2.0, 32.0)
#define KBASE 0xC0000000u  // monotone key of +2.0f

struct Keys { u32 km[ITM][2]; u32 kr[ITM][ITR][2]; };

// ---------------- threefry2x32 (JAX-compatible, 20 rounds) ----------------
__host__ __device__ static inline u32 rotl32(u32 x, int d) { return (x << d) | (x >> (32 - d)); }

__host__ __device__ static inline void tf2x32(u32 k0, u32 k1, u32 x0, u32 x1, u32& o0, u32& o1)
{
    u32 ks2 = k0 ^ k1 ^ 0x1BD11BDAu;
    x0 += k0; x1 += k1;
#define TFR(r) { x0 += x1; x1 = rotl32(x1, r); x1 ^= x0; }
    TFR(13) TFR(15) TFR(26) TFR(6)
    x0 += k1; x1 += ks2 + 1u;
    TFR(17) TFR(29) TFR(16) TFR(24)
    x0 += ks2; x1 += k0 + 2u;
    TFR(13) TFR(15) TFR(26) TFR(6)
    x0 += k0; x1 += k1 + 3u;
    TFR(17) TFR(29) TFR(16) TFR(24)
    x0 += k1; x1 += ks2 + 4u;
    TFR(13) TFR(15) TFR(26) TFR(6)
    x0 += ks2; x1 += k0 + 5u;
#undef TFR
    o0 = x0; o1 = x1;
}

// uniform(key, shape, 1e-6, 1-1e-6) bit-faithful to JAX (partitionable mode):
// bits = o0 ^ o1 at counter (0, flat_index); u = (bits>>9 | 1.0f) - 1; u*span+min; max(min,u)
#define G_MINV 1e-6f
#define G_MAXV ((float)(1.0 - 1e-6))
#define G_SPAN (G_MAXV - G_MINV)

__device__ static inline float u_from_bits(u32 bits) {
    float f = __uint_as_float((bits >> 9) | 0x3f800000u) - 1.0f;
    float u = __fadd_rn(__fmul_rn(f, G_SPAN), G_MINV);  // no FMA contraction (match XLA)
    return fmaxf(G_MINV, u);
}

// integer early-out: (bits>>9) >= 8220000  =>  u > ~0.97995, a strict superset of
// the u > 0.98186 needed for gumbel > 4 - log(max m). Survivors get the exact path.
#define EARLY_TH 8220000u

// monotone float->uint key (order-preserving for all non-NaN)
__device__ static inline u32 fkey(float v) {
    u32 u = __float_as_uint(v);
    return (u & 0x80000000u) ? ~u : (u | 0x80000000u);
}

// 64-lane butterfly sum (uniform result on all lanes)
__device__ static inline float wred(float v) {
    #pragma unroll
    for (int o = 1; o < 64; o <<= 1) v += __shfl_xor(v, o, 64);
    return v;
}

__device__ static inline u64 shfl_xor_u64(u64 v, int mask) {
    u32 lo = (u32)v, hi = (u32)(v >> 32);
    lo = __shfl_xor(lo, mask, 64);
    hi = __shfl_xor(hi, mask, 64);
    return ((u64)hi << 32) | (u64)lo;
}

// ---------------- 3x3 Kabsch via double-precision Jacobi SVD ----------------
__device__ static void kabsch(const float Hf[9], float Rf[9])
{
    double H00=Hf[0],H01=Hf[1],H02=Hf[2];
    double H10=Hf[3],H11=Hf[4],H12=Hf[5];
    double H20=Hf[6],H21=Hf[7],H22=Hf[8];
    double A00 = H00*H00 + H10*H10 + H20*H20;
    double A01 = H00*H01 + H10*H11 + H20*H21;
    double A02 = H00*H02 + H10*H12 + H20*H22;
    double A11 = H01*H01 + H11*H11 + H21*H21;
    double A12 = H01*H02 + H11*H12 + H21*H22;
    double A22 = H02*H02 + H12*H12 + H22*H22;
    double V00=1,V10=0,V20=0;
    double V01=0,V11=1,V21=0;
    double V02=0,V12=0,V22=1;
#define JROT(App,Aqq,Apq,Apr,Aqr, Vp0,Vp1,Vp2, Vq0,Vq1,Vq2) \
    if (fabs(Apq) > 0.0) { \
        double th = (Aqq - App) / (2.0 * Apq); \
        double tt = copysign(1.0, th) / (fabs(th) + sqrt(1.0 + th*th)); \
        double cc = 1.0 / sqrt(1.0 + tt*tt); \
        double ss = tt * cc; \
        double npp = App - tt*Apq, nqq = Aqq + tt*Apq; \
        double npr = cc*Apr - ss*Aqr, nqr = ss*Apr + cc*Aqr; \
        App = npp; Aqq = nqq; Apq = 0.0; Apr = npr; Aqr = nqr; \
        double tv; \
        tv = cc*Vp0 - ss*Vq0; Vq0 = ss*Vp0 + cc*Vq0; Vp0 = tv; \
        tv = cc*Vp1 - ss*Vq1; Vq1 = ss*Vp1 + cc*Vq1; Vp1 = tv; \
        tv = cc*Vp2 - ss*Vq2; Vq2 = ss*Vp2 + cc*Vq2; Vp2 = tv; \
    }
    for (int sw = 0; sw < 10; ++sw) {
        JROT(A00,A11,A01, A02,A12, V00,V10,V20, V01,V11,V21);
        JROT(A00,A22,A02, A01,A12, V00,V10,V20, V02,V12,V22);
        JROT(A11,A22,A12, A01,A02, V01,V11,V21, V02,V12,V22);
    }
#undef JROT
    double l0=A00, l1=A11, l2=A22;
    double e0[3]={V00,V10,V20}, e1[3]={V01,V11,V21}, e2[3]={V02,V12,V22};
    if (l0 < l1) { double t=l0;l0=l1;l1=t; for(int c=0;c<3;++c){double s=e0[c];e0[c]=e1[c];e1[c]=s;} }
    if (l0 < l2) { double t=l0;l0=l2;l2=t; for(int c=0;c<3;++c){double s=e0[c];e0[c]=e2[c];e2[c]=s;} }
    if (l1 < l2) { double t=l1;l1=l2;l2=t; for(int c=0;c<3;++c){double s=e1[c];e1[c]=e2[c];e2[c]=s;} }
    double u0[3], u1[3], u2[3];
#define HMUL(e,u) { u[0]=H00*e[0]+H01*e[1]+H02*e[2]; u[1]=H10*e[0]+H11*e[1]+H12*e[2]; u[2]=H20*e[0]+H21*e[1]+H22*e[2]; }
    HMUL(e0,u0) HMUL(e1,u1) HMUL(e2,u2)
#undef HMUL
    double s0 = sqrt(u0[0]*u0[0]+u0[1]*u0[1]+u0[2]*u0[2]);
    double s1 = sqrt(u1[0]*u1[0]+u1[1]*u1[1]+u1[2]*u1[2]);
    double s2 = sqrt(u2[0]*u2[0]+u2[1]*u2[1]+u2[2]*u2[2]);
    double eps = 1e-12 + 1e-6 * s0;
    if (s0 > 0.0) { u0[0]/=s0; u0[1]/=s0; u0[2]/=s0; } else { u0[0]=1.0; u0[1]=0.0; u0[2]=0.0; }
    if (s1 > eps) { u1[0]/=s1; u1[1]/=s1; u1[2]/=s1; }
    else {
        double ax0 = (fabs(u0[0]) < 0.9) ? 1.0 : 0.0;
        double ax1 = 1.0 - ax0;
        double dd = ax0*u0[0] + ax1*u0[1];
        double w0 = ax0 - dd*u0[0], w1 = ax1 - dd*u0[1], w2 = -dd*u0[2];
        double nn = sqrt(w0*w0+w1*w1+w2*w2);
        u1[0]=w0/nn; u1[1]=w1/nn; u1[2]=w2/nn;
    }
    if (s2 > eps) { u2[0]/=s2; u2[1]/=s2; u2[2]/=s2; }
    else {
        u2[0] = u0[1]*u1[2] - u0[2]*u1[1];
        u2[1] = u0[2]*u1[0] - u0[0]*u1[2];
        u2[2] = u0[0]*u1[1] - u0[1]*u1[0];
    }
    double M[3][3];
    #pragma unroll
    for (int i2=0;i2<3;++i2)
      #pragma unroll
      for (int j2=0;j2<3;++j2)
        M[i2][j2] = e0[i2]*u0[j2] + e1[i2]*u1[j2] + e2[i2]*u2[j2];
    double det = M[0][0]*(M[1][1]*M[2][2]-M[1][2]*M[2][1])
               - M[0][1]*(M[1][0]*M[2][2]-M[1][2]*M[2][0])
               + M[0][2]*(M[1][0]*M[2][1]-M[1][1]*M[2][0]);
    #pragma unroll
    for (int i2=0;i2<3;++i2)
      #pragma unroll
      for (int j2=0;j2<3;++j2)
        Rf[i2*3+j2] = (float)(e0[i2]*u0[j2] + e1[i2]*u1[j2] + det*(e2[i2]*u2[j2]));
}

__device__ static inline float dist1(const float R[9], const float t[3], const float x[3], const float y[3])
{
    float a = R[0]*x[0]+R[1]*x[1]+R[2]*x[2]+t[0]-y[0];
    float b = R[3]*x[0]+R[4]*x[1]+R[5]*x[2]+t[1]-y[1];
    float c = R[6]*x[0]+R[7]*x[1]+R[8]*x[2]+t[2]-y[2];
    return sqrtf(a*a+b*b+c*c);
}

// weighted Procrustes over the wave's 512 samples (8 per lane); uniform result
__device__ static void proc512(const float (&X)[8][3], const float (&Y)[8][3], const float (&w)[8],
                               float R[9], float t[3])
{
    float sw = 0.f;
    #pragma unroll
    for (int q=0;q<8;++q) sw += w[q];
    float S = wred(sw) + 1e-8f;
    float wn[8];
    #pragma unroll
    for (int q=0;q<8;++q) wn[q] = w[q] / S;
    float mx[3], my[3];
    #pragma unroll
    for (int c=0;c<3;++c) {
        float ax=0.f, ay=0.f;
        #pragma unroll
        for (int q=0;q<8;++q) { ax += wn[q]*X[q][c]; ay += wn[q]*Y[q][c]; }
        mx[c] = wred(ax); my[c] = wred(ay);
    }
    float Hf[9];
    #pragma unroll
    for (int ci=0;ci<3;++ci)
      #pragma unroll
      for (int cj=0;cj<3;++cj) {
        float h=0.f;
        #pragma unroll
        for (int q=0;q<8;++q) h += wn[q]*(X[q][ci]-mx[ci])*(Y[q][cj]-my[cj]);
        Hf[ci*3+cj] = wred(h);
      }
    kabsch(Hf, R);
    #pragma unroll
    for (int c=0;c<3;++c) t[c] = my[c] - (R[c*3+0]*mx[0] + R[c*3+1]*mx[1] + R[c*3+2]*mx[2]);
}

// 3x3 inverse, pivoted Gauss-Jordan (mirrors jnp.linalg.inv up to ulps)
__device__ static void inv3(const float* __restrict__ Kin, float* __restrict__ out)
{
    float a[3][6];
    for (int r=0;r<3;++r) for (int c=0;c<3;++c) { a[r][c]=Kin[r*3+c]; a[r][c+3] = (r==c)?1.f:0.f; }
    for (int col=0; col<3; ++col) {
        int piv = col;
        for (int r=col+1;r<3;++r) if (fabsf(a[r][col]) > fabsf(a[piv][col])) piv = r;
        if (piv != col) for (int c=0;c<6;++c) { float tt=a[col][c]; a[col][c]=a[piv][c]; a[piv][c]=tt; }
        float pv = a[col][col];
        for (int c=0;c<6;++c) a[col][c] /= pv;
        for (int r=0;r<3;++r) if (r != col) {
            float f = a[r][col];
            if (f != 0.f) for (int c=0;c<6;++c) a[r][c] -= f * a[col][c];
        }
    }
    for (int r=0;r<3;++r) for (int c=0;c<3;++c) out[r*3+c] = a[r][c+3];
}

// ---------------- workspace layout ----------------
static const size_t OFF_HIST = 0;                                          // u32[ITM*NB*NBIN]
static const size_t OFF_CNT  = OFF_HIST + (size_t)ITM*NB*NBIN*4;           // u32[ITM*NB]
static const size_t OFF_CUT  = OFF_CNT  + (size_t)ITM*NB*4;                // u32[ITM*NB*2]
static const size_t OFF_SC   = OFF_CUT  + (size_t)ITM*NB*2*4;              // f32[ITM*NB*ITR]
static const size_t OFF_LV   = OFF_SC   + (size_t)ITM*NB*ITR*4;            // f32[ITM*NB*ITR]
static const size_t OFF_SAMP = OFF_LV   + (size_t)ITM*NB*ITR*4;            // f32[ITM*NB*NSAMP*8]
static const size_t OFF_CAND = OFF_SAMP + (size_t)ITM*NB*NSAMP*8*4;        // u64[ITM*NB*CAPC]
static const size_t ZERO_BYTES = OFF_CUT;  // zero hist + counters each call

// ---------------- Kernel A: scan matches, global hist + speculative collect ----------------
// Grid: dim3(64, NB), 256 threads. 2048 blocks = 8 blocks/CU = 32 waves/CU (100% occupancy).
__global__ __launch_bounds__(256) void kA(const float* __restrict__ mat, Keys keys,
                                          u32* __restrict__ ghist, u32* __restrict__ gcnt,
                                          u64* __restrict__ cand)
{
    int tid = threadIdx.x;
    int lane = tid & 63;
    int b = blockIdx.y;
    const float4* rowp = reinterpret_cast<const float4*>(mat + (size_t)b * ROWN);
    int base = blockIdx.x * 4096;     // float4 units; 64 chunks of 4096 cover 262144 float4/row
    for (int itc = 0; itc < 16; ++itc) {
        int f4 = base + itc*256 + tid;
        float4 m4 = rowp[f4];
        float mv[4] = {m4.x, m4.y, m4.z, m4.w};
        u32 j0 = (u32)f4 * 4u;
        #pragma unroll
        for (int e = 0; e < 4; ++e) {
            u32 j = j0 + (u32)e;
            u32 flat = (u32)b * (u32)ROWN + j;
            float lg = logf(mv[e] + 1e-12f);   // unconditional: cheaper than divergent lazy path
            #pragma unroll
            for (int i = 0; i < ITM; ++i) {
                u32 o0, o1; tf2x32(keys.km[i][0], keys.km[i][1], 0u, flat, o0, o1);
                u32 bits = o0 ^ o1;
                bool hit = false;
                float v = 0.f;
                if ((bits >> 9) >= EARLY_TH) {       // ~2% of lanes
                    float u = u_from_bits(bits);
                    float g = -logf(-logf(u));
                    v = lg + g;
                    hit = (v > 4.0f);
                }
                u64 mask = __ballot(hit);
                if (hit) {
                    u32 key = fkey(v);
                    u32 bin = (key - KBASE) >> 14;
                    if (bin > (u32)(NBIN-1)) bin = NBIN-1;
                    atomicAdd(&ghist[((size_t)(i*NB + b))*NBIN + (int)bin], 1u);
                    // wave-aggregated counter bump
                    int leader = __ffsll((long long)mask) - 1;
                    u32 basep = 0;
                    if (lane == leader) basep = atomicAdd(&gcnt[i*NB + b], (u32)__popcll(mask));
                    basep = (u32)__shfl((int)basep, leader, 64);
                    u32 pos = basep + (u32)__popcll(mask & ((1ull << lane) - 1ull));
                    if (pos < CAPC)
                        cand[((size_t)(i*NB + b))*CAPC + pos] = ((u64)key << 32) | (u64)(u32)(~j);
                }
            }
        }
    }
}

// ---------------- Kernel B: find exact rank-512 cut bin per (iter,b) ----------------
__global__ __launch_bounds__(64) void kB(const u32* __restrict__ ghist, const u32* __restrict__ gcnt,
                                         u32* __restrict__ cut)
{
    int ib = blockIdx.x;
    int lane = threadIdx.x;
    const u32* h = ghist + (size_t)ib * NBIN;
    __shared__ u32 gs[64];
    u32 ssum = 0;
    int top = NBIN-1 - lane*32;
    for (int k = 0; k < 32; ++k) ssum += h[top - k];
    gs[lane] = ssum;
    __syncthreads();
    if (lane == 0) {
        u32 cum = 0; int cutbin = -1;
        for (int g = 0; g < 64; ++g) {
            if (cum + gs[g] >= (u32)NSAMP) {
                int t2 = NBIN-1 - g*32;
                for (int k = 0; k < 32; ++k) {
                    u32 c = h[t2 - k];
                    if (cum + c >= (u32)NSAMP) { cutbin = t2 - k; break; }
                    cum += c;
                }
                break;
            }
            cum += gs[g];
        }
        u32 ok = (cutbin >= 0) && (gcnt[ib] <= (u32)CAPC);
        cut[ib*2+0] = ok ? (KBASE + ((u32)cutbin << 14)) : 0u;
        cut[ib*2+1] = ok;
    }
}

// ---------------- Kernel D: select+sort top-512, build sample tables ----------------
__global__ __launch_bounds__(256) void kD(const float* __restrict__ mat,
        const float* __restrict__ kps0, const float* __restrict__ dep0,
        const float* __restrict__ kps1, const float* __restrict__ dep1,
        const float* __restrict__ K0, const float* __restrict__ K1,
        const u64* __restrict__ cand, const u32* __restrict__ gcnt, const u32* __restrict__ cut,
        float* __restrict__ samp)
{
    int ib = blockIdx.x;
    int b = ib % NB;
    int tid = threadIdx.x;
    __shared__ u64 buf[2048];
    __shared__ u32 nkeep;
    __shared__ float Ki[2][9];
    for (int idx = tid; idx < 2048; idx += 256) buf[idx] = 0ull;
    if (tid == 0) nkeep = 0;
    __syncthreads();
    u32 cutkey = cut[ib*2+0];
    u32 n = gcnt[ib]; if (n > (u32)CAPC) n = CAPC;
    const u64* cd = cand + (size_t)ib * CAPC;
    for (u32 idx = tid; idx < n; idx += 256) {
        u64 c = cd[idx];
        if ((u32)(c >> 32) >= cutkey) {
            u32 p = atomicAdd(&nkeep, 1u);
            if (p < 2048u) buf[p] = c;
        }
    }
    __syncthreads();
    // bitonic ascending; pads (0) sink to the front; top-512 = buf[2047-r]
    for (int k = 2; k <= 2048; k <<= 1) {
        for (int j = k >> 1; j > 0; j >>= 1) {
            for (int i2 = tid; i2 < 2048; i2 += 256) {
                int ixj = i2 ^ j;
                if (ixj > i2) {
                    bool up = ((i2 & k) == 0);
                    u64 a = buf[i2], c2 = buf[ixj];
                    bool dosw = up ? (a > c2) : (a < c2);
                    if (dosw) { buf[i2] = c2; buf[ixj] = a; }
                }
            }
            __syncthreads();
        }
    }
    if (tid == 0) { inv3(K0 + (size_t)b*9, Ki[0]); inv3(K1 + (size_t)b*9, Ki[1]); }
    __syncthreads();
    for (int r = tid; r < NSAMP; r += 256) {
        u64 c = buf[2047 - r];
        u32 j = (~(u32)(c & 0xFFFFFFFFull)) & (u32)(ROWN - 1);
        int i0 = (int)(j >> 10);
        int i1 = (int)(j & 1023u);
        float uu0 = kps0[(size_t)b*2*NKP + i0];
        float vv0 = kps0[(size_t)b*2*NKP + NKP + i0];
        float dd0 = dep0[(size_t)b*2*NKP + i0];
        float uu1 = kps1[(size_t)b*2*NKP + i1];
        float vv1 = kps1[(size_t)b*2*NKP + NKP + i1];
        float dd1 = dep1[(size_t)b*2*NKP + i1];
        float r0 = Ki[0][0]*uu0 + Ki[0][1]*vv0 + Ki[0][2];
        float r1 = Ki[0][3]*uu0 + Ki[0][4]*vv0 + Ki[0][5];
        float r2 = Ki[0][6]*uu0 + Ki[0][7]*vv0 + Ki[0][8];
        float q0 = Ki[1][0]*uu1 + Ki[1][1]*vv1 + Ki[1][2];
        float q1 = Ki[1][3]*uu1 + Ki[1][4]*vv1 + Ki[1][5];
        float q2 = Ki[1][6]*uu1 + Ki[1][7]*vv1 + Ki[1][8];
        float w = mat[(size_t)b*ROWN + j];
        float* sp = samp + ((size_t)ib*NSAMP + r)*8;
        sp[0] = dd0*r0; sp[1] = dd0*r1; sp[2] = dd0*r2;
        sp[3] = dd1*q0; sp[4] = dd1*q1; sp[5] = dd1*q2;
        sp[6] = logf(w + 1e-12f);
        sp[7] = 0.f;
    }
}

// ---------------- Kernel E: one wave per RANSAC hypothesis ----------------
__global__ __launch_bounds__(64) void kE(const float* __restrict__ samp, const float* __restrict__ Tmat,
                                         Keys keys, float* __restrict__ scoreArr, float* __restrict__ lvArr)
{
    int blk = blockIdx.x;
    int kk = blk & 7;
    int ib = blk >> 3;
    int i = ib / NB;
    int b = ib % NB;
    int lane = threadIdx.x;
    const float* s = samp + (size_t)ib * NSAMP * 8;
    float X[8][3], Y[8][3], lw[8];
    #pragma unroll
    for (int q = 0; q < 8; ++q) {
        const float4* p = reinterpret_cast<const float4*>(s + (size_t)(q*64 + lane)*8);
        float4 a0 = p[0], a1 = p[1];
        X[q][0]=a0.x; X[q][1]=a0.y; X[q][2]=a0.z;
        Y[q][0]=a0.w; Y[q][1]=a1.x; Y[q][2]=a1.y;
        lw[q]=a1.z;
    }
    // inner gumbel + composite keys
    u64 comp[8];
    #pragma unroll
    for (int q = 0; q < 8; ++q) {
        u32 j = (u32)(q*64 + lane);
        u32 o0,o1; tf2x32(keys.kr[i][kk][0], keys.kr[i][kk][1], 0u, (u32)(b*NSAMP) + j, o0,o1);
        float u = u_from_bits(o0^o1);
        float g = -logf(-logf(u));
        float v = lw[q] + g;
        comp[q] = ((u64)fkey(v) << 32) | (u64)(u32)(~j);
    }
    // top-5 (value desc, index asc) via 5 wave arg-max rounds
    int ridx[5];
    #pragma unroll
    for (int r = 0; r < 5; ++r) {
        u64 m = comp[0];
        #pragma unroll
        for (int q=1;q<8;++q) if (comp[q] > m) m = comp[q];
        #pragma unroll
        for (int o=1;o<64;o<<=1) { u64 x = shfl_xor_u64(m,o); if (x > m) m = x; }
        ridx[r] = (int)((~(u32)(m & 0xFFFFFFFFull)) & (u32)(NSAMP-1));
        #pragma unroll
        for (int q=0;q<8;++q) if (comp[q] == m) comp[q] = 0ull;
    }
    // 5-point Procrustes (uniform weights) — all lanes compute identically
    float Xk[5][3], Yk[5][3];
    #pragma unroll
    for (int r=0;r<5;++r) {
        const float* p = s + (size_t)ridx[r]*8;
        Xk[r][0]=p[0]; Xk[r][1]=p[1]; Xk[r][2]=p[2];
        Yk[r][0]=p[3]; Yk[r][1]=p[4]; Yk[r][2]=p[5];
    }
    float S5 = 5.0f + 1e-8f;
    float wn5 = 1.0f / S5;
    float mx[3]={0,0,0}, my[3]={0,0,0};
    #pragma unroll
    for (int r=0;r<5;++r) {
        #pragma unroll
        for (int c=0;c<3;++c) { mx[c] += wn5*Xk[r][c]; my[c] += wn5*Yk[r][c]; }
    }
    float Hf[9] = {0,0,0,0,0,0,0,0,0};
    #pragma unroll
    for (int r=0;r<5;++r)
      #pragma unroll
      for (int ci=0;ci<3;++ci)
        #pragma unroll
        for (int cj=0;cj<3;++cj)
          Hf[ci*3+cj] += wn5*(Xk[r][ci]-mx[ci])*(Yk[r][cj]-my[cj]);
    float Rpre[9], tpre[3];
    kabsch(Hf, Rpre);
    #pragma unroll
    for (int c=0;c<3;++c) tpre[c] = my[c] - (Rpre[c*3+0]*mx[0] + Rpre[c*3+1]*mx[1] + Rpre[c*3+2]*mx[2]);
    // score over all 512 samples
    const float BETAF = (float)(5.0/0.15);
    float partial = 0.f;
    #pragma unroll
    for (int q=0;q<8;++q) {
        float d = dist1(Rpre, tpre, X[q], Y[q]);
        float z = BETAF * (0.15f - d);
        partial += 1.0f / (1.0f + expf(-z));
    }
    float score = wred(partial);
    // refinement (4 steps, exact do-gating)
    float inlref[8];
    #pragma unroll
    for (int q=0;q<8;++q) {
        int j = q*64 + lane;
        inlref[q] = (j==ridx[0] || j==ridx[1] || j==ridx[2] || j==ridx[3] || j==ridx[4]) ? 1.0f : 0.0f;
    }
    float Rd[9], td[3];
    #pragma unroll
    for (int c2=0;c2<9;++c2) Rd[c2]=Rpre[c2];
    td[0]=tpre[0]; td[1]=tpre[1]; td[2]=tpre[2];
    float inl_pre = 0.f;
    for (int step=0; step<4; ++step) {
        float inl[8]; float csum = 0.f;
        #pragma unroll
        for (int q=0;q<8;++q) {
            float d = dist1(Rd, td, X[q], Y[q]);
            inl[q] = (d < 0.15f) ? 1.0f : 0.0f;
            csum += inl[q];
        }
        float cnt = wred(csum);
        bool doit = (cnt >= 5.0f) && (cnt > inl_pre);
        inl_pre = cnt;
        if (doit) {
            #pragma unroll
            for (int q=0;q<8;++q) inlref[q] = inl[q];
            proc512(X, Y, inlref, Rd, td);
        }
    }
    // final Procrustes + pose loss
    float Rfin[9], tfin[3];
    proc512(X, Y, inlref, Rfin, tfin);
    const float* Tb = Tmat + (size_t)b*16;
    float tr = 0.f;
    #pragma unroll
    for (int ci=0;ci<3;++ci)
      #pragma unroll
      for (int cj=0;cj<3;++cj)
        tr += Rfin[ci*3+cj] * Tb[ci*4+cj];
    float cosang = (tr - 1.0f) * 0.5f;
    cosang = fminf(fmaxf(cosang, -0.999999f), 0.999999f);
    float ang = acosf(cosang);
    float d0 = tfin[0]-Tb[3], d1 = tfin[1]-Tb[7], d2 = tfin[2]-Tb[11];
    float terr = sqrtf(d0*d0 + d1*d1 + d2*d2);
    float lr = 0.5f * tanhf(ang / 0.5f);
    float lt = 0.5f * tanhf(terr / 0.5f);
    float lv = 0.5f * (lr + lt);
    if (lane == 0) { scoreArr[blk] = score; lvArr[blk] = lv; }
}

// ---------------- Kernel F: softmax mixing + output ----------------
__global__ void kF(const float* __restrict__ scoreArr, const float* __restrict__ lvArr, float* __restrict__ out)
{
    int b = threadIdx.x;
    if (b >= NB) return;
    const float NULLSC = (float)(0.35 * 512.0);
    float total = 0.f;
    for (int i = 0; i < ITM; ++i) {
        float x[9], lvv[9], ee[9];
        for (int k = 0; k < 8; ++k) {
            x[k] = scoreArr[(i*NB + b)*ITR + k] / 10.0f;
            lvv[k] = lvArr[(i*NB + b)*ITR + k];
        }
        x[8] = NULLSC / 10.0f;
        lvv[8] = 0.5f;
        float m = x[0];
        for (int k = 1; k < 9; ++k) m = fmaxf(m, x[k]);
        float Ssum = 0.f;
        for (int k = 0; k < 9; ++k) { ee[k] = expf(x[k] - m); Ssum += ee[k]; }
        float acc = 0.f;
        for (int k = 0; k < 9; ++k) acc += lvv[k] * (ee[k] / Ssum);
        total += acc;
    }
    out[b] = total / 4.0f;
}

// ---------------- host ----------------
extern "C" void kernel_launch(void* const* d_in, const int* in_sizes, int n_in,
                              void* d_out, int out_size, void* d_ws, size_t ws_size,
                              hipStream_t stream)
{
    (void)in_sizes; (void)n_in; (void)out_size; (void)ws_size;
    const float* mat  = (const float*)d_in[0];
    const float* kps0 = (const float*)d_in[1];
    const float* dep0 = (const float*)d_in[2];
    const float* kps1 = (const float*)d_in[3];
    const float* dep1 = (const float*)d_in[4];
    const float* K0   = (const float*)d_in[5];
    const float* K1   = (const float*)d_in[6];
    const float* Tm   = (const float*)d_in[8];
    float* out = (float*)d_out;

    // JAX key schedule: key(42) -> (0,42); split() in partitionable (fold-like) mode
    Keys keys;
    {
        u32 k0 = 0u, k1 = 42u;
        for (int i = 0; i < ITM; ++i) {
            u32 a0,a1,b0,b1;
            tf2x32(k0,k1, 0u,0u, a0,a1);
            tf2x32(k0,k1, 0u,1u, b0,b1);
            k0=a0; k1=a1; keys.km[i][0]=b0; keys.km[i][1]=b1;
            for (int kk = 0; kk < ITR; ++kk) {
                tf2x32(k0,k1, 0u,0u, a0,a1);
                tf2x32(k0,k1, 0u,1u, b0,b1);
                k0=a0; k1=a1; keys.kr[i][kk][0]=b0; keys.kr[i][kk][1]=b1;
            }
        }
    }
    char* ws = (char*)d_ws;
    u32* ghist      = (u32*)(ws + OFF_HIST);
    u32* gcnt       = (u32*)(ws + OFF_CNT);
    u32* cut        = (u32*)(ws + OFF_CUT);
    float* scoreArr = (float*)(ws + OFF_SC);
    float* lvArr    = (float*)(ws + OFF_LV);
    float* samp     = (float*)(ws + OFF_SAMP);
    u64* cand       = (u64*)(ws + OFF_CAND);

    hipMemsetAsync(d_ws, 0, ZERO_BYTES, stream);
    kA<<<dim3(64, NB), 256, 0, stream>>>(mat, keys, ghist, gcnt, cand);
    kB<<<ITM*NB, 64, 0, stream>>>(ghist, gcnt, cut);
    kD<<<ITM*NB, 256, 0, stream>>>(mat, kps0, dep0, kps1, dep1, K0, K1, cand, gcnt, cut, samp);
    kE<<<ITM*NB*ITR, 64, 0, stream>>>(samp, Tm, keys, scoreArr, lvArr);
    kF<<<1, 64, 0, stream>>>(scoreArr, lvArr, out);
}

// Round 3
// 460.660 us; speedup vs baseline: 5.1275x; 5.0959x over previous
//
#include <hip/hip_runtime.h>
#include <stdint.h>

typedef unsigned long long u64;
typedef uint32_t u32;

#define NB 32            // batch
#define NKP 1024         // keypoints per image
#define ROWN (NKP*NKP)   // matches row length
#define NSAMP 512        // NUM_SAMPLES
#define ITM 4            // IT_MATCHES
#define ITR 8            // IT_RANSAC
#define NBIN 2048        // fine histogram bins over key range [2.0, 32.0)
#define KBASE 0xC0000000u  // monotone key of +2.0f
#define CHUNKS 64        // blocks per row (blockIdx.x)
#define SLOTS 256        // per-(i,chunk) candidate capacity (mean ~150, +8.6 sigma)

struct Keys { u32 km[ITM][2]; u32 kr[ITM][ITR][2]; };

// ---------------- threefry2x32 (JAX-compatible, 20 rounds) ----------------
__host__ __device__ static inline u32 rotl32(u32 x, int d) { return (x << d) | (x >> (32 - d)); }

__host__ __device__ static inline void tf2x32(u32 k0, u32 k1, u32 x0, u32 x1, u32& o0, u32& o1)
{
    u32 ks2 = k0 ^ k1 ^ 0x1BD11BDAu;
    x0 += k0; x1 += k1;
#define TFR(r) { x0 += x1; x1 = rotl32(x1, r); x1 ^= x0; }
    TFR(13) TFR(15) TFR(26) TFR(6)
    x0 += k1; x1 += ks2 + 1u;
    TFR(17) TFR(29) TFR(16) TFR(24)
    x0 += ks2; x1 += k0 + 2u;
    TFR(13) TFR(15) TFR(26) TFR(6)
    x0 += k0; x1 += k1 + 3u;
    TFR(17) TFR(29) TFR(16) TFR(24)
    x0 += k1; x1 += ks2 + 4u;
    TFR(13) TFR(15) TFR(26) TFR(6)
    x0 += ks2; x1 += k0 + 5u;
#undef TFR
    o0 = x0; o1 = x1;
}

// uniform(key, shape, 1e-6, 1-1e-6) bit-faithful to JAX (partitionable mode)
#define G_MINV 1e-6f
#define G_MAXV ((float)(1.0 - 1e-6))
#define G_SPAN (G_MAXV - G_MINV)

__device__ static inline float u_from_bits(u32 bits) {
    float f = __uint_as_float((bits >> 9) | 0x3f800000u) - 1.0f;
    float u = __fadd_rn(__fmul_rn(f, G_SPAN), G_MINV);  // no FMA contraction (match XLA)
    return fmaxf(G_MINV, u);
}

// integer early-out: (bits>>9) >= 8220000 => u > ~0.97995, strict superset of u>0.98186
// needed for gumbel > 4 - log(max m). Survivors get the exact float path.
#define EARLY_TH 8220000u

// monotone float->uint key (order-preserving for all non-NaN)
__device__ static inline u32 fkey(float v) {
    u32 u = __float_as_uint(v);
    return (u & 0x80000000u) ? ~u : (u | 0x80000000u);
}

// 64-lane butterfly sum (uniform result on all lanes)
__device__ static inline float wred(float v) {
    #pragma unroll
    for (int o = 1; o < 64; o <<= 1) v += __shfl_xor(v, o, 64);
    return v;
}

__device__ static inline u64 shfl_xor_u64(u64 v, int mask) {
    u32 lo = (u32)v, hi = (u32)(v >> 32);
    lo = __shfl_xor(lo, mask, 64);
    hi = __shfl_xor(hi, mask, 64);
    return ((u64)hi << 32) | (u64)lo;
}

// ---------------- 3x3 Kabsch via double-precision Jacobi SVD ----------------
__device__ static void kabsch(const float Hf[9], float Rf[9])
{
    double H00=Hf[0],H01=Hf[1],H02=Hf[2];
    double H10=Hf[3],H11=Hf[4],H12=Hf[5];
    double H20=Hf[6],H21=Hf[7],H22=Hf[8];
    double A00 = H00*H00 + H10*H10 + H20*H20;
    double A01 = H00*H01 + H10*H11 + H20*H21;
    double A02 = H00*H02 + H10*H12 + H20*H22;
    double A11 = H01*H01 + H11*H11 + H21*H21;
    double A12 = H01*H02 + H11*H12 + H21*H22;
    double A22 = H02*H02 + H12*H12 + H22*H22;
    double V00=1,V10=0,V20=0;
    double V01=0,V11=1,V21=0;
    double V02=0,V12=0,V22=1;
#define JROT(App,Aqq,Apq,Apr,Aqr, Vp0,Vp1,Vp2, Vq0,Vq1,Vq2) \
    if (fabs(Apq) > 0.0) { \
        double th = (Aqq - App) / (2.0 * Apq); \
        double tt = copysign(1.0, th) / (fabs(th) + sqrt(1.0 + th*th)); \
        double cc = 1.0 / sqrt(1.0 + tt*tt); \
        double ss = tt * cc; \
        double npp = App - tt*Apq, nqq = Aqq + tt*Apq; \
        double npr = cc*Apr - ss*Aqr, nqr = ss*Apr + cc*Aqr; \
        App = npp; Aqq = nqq; Apq = 0.0; Apr = npr; Aqr = nqr; \
        double tv; \
        tv = cc*Vp0 - ss*Vq0; Vq0 = ss*Vp0 + cc*Vq0; Vp0 = tv; \
        tv = cc*Vp1 - ss*Vq1; Vq1 = ss*Vp1 + cc*Vq1; Vp1 = tv; \
        tv = cc*Vp2 - ss*Vq2; Vq2 = ss*Vp2 + cc*Vq2; Vp2 = tv; \
    }
    for (int sw = 0; sw < 10; ++sw) {
        JROT(A00,A11,A01, A02,A12, V00,V10,V20, V01,V11,V21);
        JROT(A00,A22,A02, A01,A12, V00,V10,V20, V02,V12,V22);
        JROT(A11,A22,A12, A01,A02, V01,V11,V21, V02,V12,V22);
    }
#undef JROT
    double l0=A00, l1=A11, l2=A22;
    double e0[3]={V00,V10,V20}, e1[3]={V01,V11,V21}, e2[3]={V02,V12,V22};
    if (l0 < l1) { double t=l0;l0=l1;l1=t; for(int c=0;c<3;++c){double s=e0[c];e0[c]=e1[c];e1[c]=s;} }
    if (l0 < l2) { double t=l0;l0=l2;l2=t; for(int c=0;c<3;++c){double s=e0[c];e0[c]=e2[c];e2[c]=s;} }
    if (l1 < l2) { double t=l1;l1=l2;l2=t; for(int c=0;c<3;++c){double s=e1[c];e1[c]=e2[c];e2[c]=s;} }
    double u0[3], u1[3], u2[3];
#define HMUL(e,u) { u[0]=H00*e[0]+H01*e[1]+H02*e[2]; u[1]=H10*e[0]+H11*e[1]+H12*e[2]; u[2]=H20*e[0]+H21*e[1]+H22*e[2]; }
    HMUL(e0,u0) HMUL(e1,u1) HMUL(e2,u2)
#undef HMUL
    double s0 = sqrt(u0[0]*u0[0]+u0[1]*u0[1]+u0[2]*u0[2]);
    double s1 = sqrt(u1[0]*u1[0]+u1[1]*u1[1]+u1[2]*u1[2]);
    double s2 = sqrt(u2[0]*u2[0]+u2[1]*u2[1]+u2[2]*u2[2]);
    double eps = 1e-12 + 1e-6 * s0;
    if (s0 > 0.0) { u0[0]/=s0; u0[1]/=s0; u0[2]/=s0; } else { u0[0]=1.0; u0[1]=0.0; u0[2]=0.0; }
    if (s1 > eps) { u1[0]/=s1; u1[1]/=s1; u1[2]/=s1; }
    else {
        double ax0 = (fabs(u0[0]) < 0.9) ? 1.0 : 0.0;
        double ax1 = 1.0 - ax0;
        double dd = ax0*u0[0] + ax1*u0[1];
        double w0 = ax0 - dd*u0[0], w1 = ax1 - dd*u0[1], w2 = -dd*u0[2];
        double nn = sqrt(w0*w0+w1*w1+w2*w2);
        u1[0]=w0/nn; u1[1]=w1/nn; u1[2]=w2/nn;
    }
    if (s2 > eps) { u2[0]/=s2; u2[1]/=s2; u2[2]/=s2; }
    else {
        u2[0] = u0[1]*u1[2] - u0[2]*u1[1];
        u2[1] = u0[2]*u1[0] - u0[0]*u1[2];
        u2[2] = u0[0]*u1[1] - u0[1]*u1[0];
    }
    double M[3][3];
    #pragma unroll
    for (int i2=0;i2<3;++i2)
      #pragma unroll
      for (int j2=0;j2<3;++j2)
        M[i2][j2] = e0[i2]*u0[j2] + e1[i2]*u1[j2] + e2[i2]*u2[j2];
    double det = M[0][0]*(M[1][1]*M[2][2]-M[1][2]*M[2][1])
               - M[0][1]*(M[1][0]*M[2][2]-M[1][2]*M[2][0])
               + M[0][2]*(M[1][0]*M[2][1]-M[1][1]*M[2][0]);
    #pragma unroll
    for (int i2=0;i2<3;++i2)
      #pragma unroll
      for (int j2=0;j2<3;++j2)
        Rf[i2*3+j2] = (float)(e0[i2]*u0[j2] + e1[i2]*u1[j2] + det*(e2[i2]*u2[j2]));
}

__device__ static inline float dist1(const float R[9], const float t[3], const float x[3], const float y[3])
{
    float a = R[0]*x[0]+R[1]*x[1]+R[2]*x[2]+t[0]-y[0];
    float b = R[3]*x[0]+R[4]*x[1]+R[5]*x[2]+t[1]-y[1];
    float c = R[6]*x[0]+R[7]*x[1]+R[8]*x[2]+t[2]-y[2];
    return sqrtf(a*a+b*b+c*c);
}

// weighted Procrustes over the wave's 512 samples (8 per lane); uniform result
__device__ static void proc512(const float (&X)[8][3], const float (&Y)[8][3], const float (&w)[8],
                               float R[9], float t[3])
{
    float sw = 0.f;
    #pragma unroll
    for (int q=0;q<8;++q) sw += w[q];
    float S = wred(sw) + 1e-8f;
    float wn[8];
    #pragma unroll
    for (int q=0;q<8;++q) wn[q] = w[q] / S;
    float mx[3], my[3];
    #pragma unroll
    for (int c=0;c<3;++c) {
        float ax=0.f, ay=0.f;
        #pragma unroll
        for (int q=0;q<8;++q) { ax += wn[q]*X[q][c]; ay += wn[q]*Y[q][c]; }
        mx[c] = wred(ax); my[c] = wred(ay);
    }
    float Hf[9];
    #pragma unroll
    for (int ci=0;ci<3;++ci)
      #pragma unroll
      for (int cj=0;cj<3;++cj) {
        float h=0.f;
        #pragma unroll
        for (int q=0;q<8;++q) h += wn[q]*(X[q][ci]-mx[ci])*(Y[q][cj]-my[cj]);
        Hf[ci*3+cj] = wred(h);
      }
    kabsch(Hf, R);
    #pragma unroll
    for (int c=0;c<3;++c) t[c] = my[c] - (R[c*3+0]*mx[0] + R[c*3+1]*mx[1] + R[c*3+2]*mx[2]);
}

// 3x3 inverse, pivoted Gauss-Jordan (mirrors jnp.linalg.inv up to ulps)
__device__ static void inv3(const float* __restrict__ Kin, float* __restrict__ out)
{
    float a[3][6];
    for (int r=0;r<3;++r) for (int c=0;c<3;++c) { a[r][c]=Kin[r*3+c]; a[r][c+3] = (r==c)?1.f:0.f; }
    for (int col=0; col<3; ++col) {
        int piv = col;
        for (int r=col+1;r<3;++r) if (fabsf(a[r][col]) > fabsf(a[piv][col])) piv = r;
        if (piv != col) for (int c=0;c<6;++c) { float tt=a[col][c]; a[col][c]=a[piv][c]; a[piv][c]=tt; }
        float pv = a[col][col];
        for (int c=0;c<6;++c) a[col][c] /= pv;
        for (int r=0;r<3;++r) if (r != col) {
            float f = a[r][col];
            if (f != 0.f) for (int c=0;c<6;++c) a[r][c] -= f * a[col][c];
        }
    }
    for (int r=0;r<3;++r) for (int c=0;c<3;++c) out[r*3+c] = a[r][c+3];
}

// ---------------- workspace layout ----------------
static const size_t OFF_CNTS = 0;                                           // u32[ITM*NB*CHUNKS]
static const size_t OFF_SC   = OFF_CNTS + (size_t)ITM*NB*CHUNKS*4;          // f32[ITM*NB*ITR]
static const size_t OFF_LV   = OFF_SC   + (size_t)ITM*NB*ITR*4;             // f32[ITM*NB*ITR]
static const size_t OFF_SAMP = OFF_LV   + (size_t)ITM*NB*ITR*4;             // f32[ITM*NB*NSAMP*8]
static const size_t OFF_CAND = OFF_SAMP + (size_t)ITM*NB*NSAMP*8*4;         // u64[ITM*NB*CHUNKS*SLOTS]

// ---------------- Kernel A: scan matches -> per-block private candidate lists ----------------
// Grid dim3(CHUNKS, NB) x 256. NO global atomics; LDS append lists only.
__global__ __launch_bounds__(256) void kA(const float* __restrict__ mat, Keys keys,
                                          u64* __restrict__ candC, u32* __restrict__ cnts)
{
    __shared__ u64 lists[ITM][SLOTS];   // 8 KB
    __shared__ u32 lcnt[ITM];
    int tid = threadIdx.x;
    int b = blockIdx.y;
    int chunk = blockIdx.x;
    if (tid < ITM) lcnt[tid] = 0;
    __syncthreads();
    const float4* rowp = reinterpret_cast<const float4*>(mat + (size_t)b * ROWN);
    int base = chunk * 4096;     // float4 units
    for (int itc = 0; itc < 16; ++itc) {
        int f4 = base + itc*256 + tid;
        float4 m4 = rowp[f4];
        float mv[4] = {m4.x, m4.y, m4.z, m4.w};
        u32 j0 = (u32)f4 * 4u;
        #pragma unroll
        for (int e = 0; e < 4; ++e) {
            u32 j = j0 + (u32)e;
            u32 flat = (u32)b * (u32)ROWN + j;
            float lg = logf(mv[e] + 1e-12f);
            #pragma unroll
            for (int i = 0; i < ITM; ++i) {
                u32 o0, o1; tf2x32(keys.km[i][0], keys.km[i][1], 0u, flat, o0, o1);
                u32 bits = o0 ^ o1;
                if ((bits >> 9) >= EARLY_TH) {       // ~2% of lanes
                    float u = u_from_bits(bits);
                    float g = -logf(-logf(u));
                    float v = lg + g;
                    if (v > 4.0f) {
                        u32 p = atomicAdd(&lcnt[i], 1u);   // LDS atomic: intra-CU, cheap
                        if (p < (u32)SLOTS)
                            lists[i][p] = ((u64)fkey(v) << 32) | (u64)(u32)(~j);
                    }
                }
            }
        }
    }
    __syncthreads();
    #pragma unroll
    for (int i = 0; i < ITM; ++i) {
        u32 n = lcnt[i]; if (n > (u32)SLOTS) n = SLOTS;
        for (u32 s = tid; s < n; s += 256)
            candC[(((size_t)(i*NB + b))*CHUNKS + chunk)*SLOTS + s] = lists[i][s];
    }
    if (tid < ITM) cnts[((size_t)(tid*NB + b))*CHUNKS + chunk] = min(lcnt[tid], (u32)SLOTS);
}

// ---------------- Kernel D: hist+cut+select+sort+backproject, one block per (iter,b) ----------------
__global__ __launch_bounds__(256) void kD(const float* __restrict__ mat,
        const float* __restrict__ kps0, const float* __restrict__ dep0,
        const float* __restrict__ kps1, const float* __restrict__ dep1,
        const float* __restrict__ K0, const float* __restrict__ K1,
        const u64* __restrict__ candC, const u32* __restrict__ cnts,
        float* __restrict__ samp)
{
    int ib = blockIdx.x;
    int b = ib % NB;
    int tid = threadIdx.x;
    __shared__ u32 hist[NBIN];     // 8 KB
    __shared__ u64 buf[2048];      // 16 KB
    __shared__ u32 ccnt[CHUNKS];
    __shared__ u32 gs[64];
    __shared__ u32 nkeep, cutkey_s;
    __shared__ float Ki[2][9];
    for (int idx = tid; idx < NBIN; idx += 256) hist[idx] = 0;
    for (int idx = tid; idx < 2048; idx += 256) buf[idx] = 0ull;
    if (tid < CHUNKS) ccnt[tid] = cnts[(size_t)ib*CHUNKS + tid];
    if (tid == 0) nkeep = 0;
    __syncthreads();
    const u64* cd = candC + (size_t)ib * CHUNKS * SLOTS;
    // pass 1: histogram of candidate keys
    for (int t = tid; t < CHUNKS*SLOTS; t += 256) {
        int c = t >> 8, s = t & (SLOTS-1);
        if ((u32)s < ccnt[c]) {
            u32 key = (u32)(cd[t] >> 32);
            u32 bin = (key - KBASE) >> 14;
            if (bin > (u32)(NBIN-1)) bin = NBIN-1;
            atomicAdd(&hist[bin], 1u);
        }
    }
    __syncthreads();
    // exact rank-512 cut bin
    if (tid < 64) {
        u32 ssum = 0;
        int top = NBIN-1 - tid*32;
        for (int k = 0; k < 32; ++k) ssum += hist[top - k];
        gs[tid] = ssum;
    }
    __syncthreads();
    if (tid == 0) {
        u32 cum = 0; int cutbin = -1;
        for (int g = 0; g < 64; ++g) {
            if (cum + gs[g] >= (u32)NSAMP) {
                int t2 = NBIN-1 - g*32;
                for (int k = 0; k < 32; ++k) {
                    u32 c = hist[t2 - k];
                    if (cum + c >= (u32)NSAMP) { cutbin = t2 - k; break; }
                    cum += c;
                }
                break;
            }
            cum += gs[g];
        }
        cutkey_s = (cutbin >= 0) ? (KBASE + ((u32)cutbin << 14)) : 0u;
    }
    __syncthreads();
    u32 cutkey = cutkey_s;
    // pass 2: filter >= cutkey into sort buffer
    for (int t = tid; t < CHUNKS*SLOTS; t += 256) {
        int c = t >> 8, s = t & (SLOTS-1);
        if ((u32)s < ccnt[c]) {
            u64 cv = cd[t];
            if ((u32)(cv >> 32) >= cutkey) {
                u32 p = atomicAdd(&nkeep, 1u);
                if (p < 2048u) buf[p] = cv;
            }
        }
    }
    __syncthreads();
    // bitonic ascending; pads (0) sink to the front; top-512 = buf[2047-r]
    for (int k = 2; k <= 2048; k <<= 1) {
        for (int j = k >> 1; j > 0; j >>= 1) {
            for (int i2 = tid; i2 < 2048; i2 += 256) {
                int ixj = i2 ^ j;
                if (ixj > i2) {
                    bool up = ((i2 & k) == 0);
                    u64 a = buf[i2], c2 = buf[ixj];
                    bool dosw = up ? (a > c2) : (a < c2);
                    if (dosw) { buf[i2] = c2; buf[ixj] = a; }
                }
            }
            __syncthreads();
        }
    }
    if (tid == 0) { inv3(K0 + (size_t)b*9, Ki[0]); inv3(K1 + (size_t)b*9, Ki[1]); }
    __syncthreads();
    for (int r = tid; r < NSAMP; r += 256) {
        u64 c = buf[2047 - r];
        u32 j = (~(u32)(c & 0xFFFFFFFFull)) & (u32)(ROWN - 1);
        int i0 = (int)(j >> 10);
        int i1 = (int)(j & 1023u);
        float uu0 = kps0[(size_t)b*2*NKP + i0];
        float vv0 = kps0[(size_t)b*2*NKP + NKP + i0];
        float dd0 = dep0[(size_t)b*2*NKP + i0];
        float uu1 = kps1[(size_t)b*2*NKP + i1];
        float vv1 = kps1[(size_t)b*2*NKP + NKP + i1];
        float dd1 = dep1[(size_t)b*2*NKP + i1];
        float r0 = Ki[0][0]*uu0 + Ki[0][1]*vv0 + Ki[0][2];
        float r1 = Ki[0][3]*uu0 + Ki[0][4]*vv0 + Ki[0][5];
        float r2 = Ki[0][6]*uu0 + Ki[0][7]*vv0 + Ki[0][8];
        float q0 = Ki[1][0]*uu1 + Ki[1][1]*vv1 + Ki[1][2];
        float q1 = Ki[1][3]*uu1 + Ki[1][4]*vv1 + Ki[1][5];
        float q2 = Ki[1][6]*uu1 + Ki[1][7]*vv1 + Ki[1][8];
        float w = mat[(size_t)b*ROWN + j];
        float* sp = samp + ((size_t)ib*NSAMP + r)*8;
        sp[0] = dd0*r0; sp[1] = dd0*r1; sp[2] = dd0*r2;
        sp[3] = dd1*q0; sp[4] = dd1*q1; sp[5] = dd1*q2;
        sp[6] = logf(w + 1e-12f);
        sp[7] = 0.f;
    }
}

// ---------------- Kernel E: one wave per RANSAC hypothesis ----------------
__global__ __launch_bounds__(64) void kE(const float* __restrict__ samp, const float* __restrict__ Tmat,
                                         Keys keys, float* __restrict__ scoreArr, float* __restrict__ lvArr)
{
    int blk = blockIdx.x;
    int kk = blk & 7;
    int ib = blk >> 3;
    int i = ib / NB;
    int b = ib % NB;
    int lane = threadIdx.x;
    const float* s = samp + (size_t)ib * NSAMP * 8;
    float X[8][3], Y[8][3], lw[8];
    #pragma unroll
    for (int q = 0; q < 8; ++q) {
        const float4* p = reinterpret_cast<const float4*>(s + (size_t)(q*64 + lane)*8);
        float4 a0 = p[0], a1 = p[1];
        X[q][0]=a0.x; X[q][1]=a0.y; X[q][2]=a0.z;
        Y[q][0]=a0.w; Y[q][1]=a1.x; Y[q][2]=a1.y;
        lw[q]=a1.z;
    }
    // inner gumbel + composite keys
    u64 comp[8];
    #pragma unroll
    for (int q = 0; q < 8; ++q) {
        u32 j = (u32)(q*64 + lane);
        u32 o0,o1; tf2x32(keys.kr[i][kk][0], keys.kr[i][kk][1], 0u, (u32)(b*NSAMP) + j, o0,o1);
        float u = u_from_bits(o0^o1);
        float g = -logf(-logf(u));
        float v = lw[q] + g;
        comp[q] = ((u64)fkey(v) << 32) | (u64)(u32)(~j);
    }
    // top-5 (value desc, index asc) via 5 wave arg-max rounds
    int ridx[5];
    #pragma unroll
    for (int r = 0; r < 5; ++r) {
        u64 m = comp[0];
        #pragma unroll
        for (int q=1;q<8;++q) if (comp[q] > m) m = comp[q];
        #pragma unroll
        for (int o=1;o<64;o<<=1) { u64 x = shfl_xor_u64(m,o); if (x > m) m = x; }
        ridx[r] = (int)((~(u32)(m & 0xFFFFFFFFull)) & (u32)(NSAMP-1));
        #pragma unroll
        for (int q=0;q<8;++q) if (comp[q] == m) comp[q] = 0ull;
    }
    // 5-point Procrustes (uniform weights) — all lanes compute identically
    float Xk[5][3], Yk[5][3];
    #pragma unroll
    for (int r=0;r<5;++r) {
        const float* p = s + (size_t)ridx[r]*8;
        Xk[r][0]=p[0]; Xk[r][1]=p[1]; Xk[r][2]=p[2];
        Yk[r][0]=p[3]; Yk[r][1]=p[4]; Yk[r][2]=p[5];
    }
    float S5 = 5.0f + 1e-8f;
    float wn5 = 1.0f / S5;
    float mx[3]={0,0,0}, my[3]={0,0,0};
    #pragma unroll
    for (int r=0;r<5;++r) {
        #pragma unroll
        for (int c=0;c<3;++c) { mx[c] += wn5*Xk[r][c]; my[c] += wn5*Yk[r][c]; }
    }
    float Hf[9] = {0,0,0,0,0,0,0,0,0};
    #pragma unroll
    for (int r=0;r<5;++r)
      #pragma unroll
      for (int ci=0;ci<3;++ci)
        #pragma unroll
        for (int cj=0;cj<3;++cj)
          Hf[ci*3+cj] += wn5*(Xk[r][ci]-mx[ci])*(Yk[r][cj]-my[cj]);
    float Rpre[9], tpre[3];
    kabsch(Hf, Rpre);
    #pragma unroll
    for (int c=0;c<3;++c) tpre[c] = my[c] - (Rpre[c*3+0]*mx[0] + Rpre[c*3+1]*mx[1] + Rpre[c*3+2]*mx[2]);
    // score over all 512 samples
    const float BETAF = (float)(5.0/0.15);
    float partial = 0.f;
    #pragma unroll
    for (int q=0;q<8;++q) {
        float d = dist1(Rpre, tpre, X[q], Y[q]);
        float z = BETAF * (0.15f - d);
        partial += 1.0f / (1.0f + expf(-z));
    }
    float score = wred(partial);
    // refinement (4 steps, exact do-gating)
    float inlref[8];
    #pragma unroll
    for (int q=0;q<8;++q) {
        int j = q*64 + lane;
        inlref[q] = (j==ridx[0] || j==ridx[1] || j==ridx[2] || j==ridx[3] || j==ridx[4]) ? 1.0f : 0.0f;
    }
    float Rd[9], td[3];
    #pragma unroll
    for (int c2=0;c2<9;++c2) Rd[c2]=Rpre[c2];
    td[0]=tpre[0]; td[1]=tpre[1]; td[2]=tpre[2];
    float inl_pre = 0.f;
    for (int step=0; step<4; ++step) {
        float inl[8]; float csum = 0.f;
        #pragma unroll
        for (int q=0;q<8;++q) {
            float d = dist1(Rd, td, X[q], Y[q]);
            inl[q] = (d < 0.15f) ? 1.0f : 0.0f;
            csum += inl[q];
        }
        float cnt = wred(csum);
        bool doit = (cnt >= 5.0f) && (cnt > inl_pre);
        inl_pre = cnt;
        if (doit) {
            #pragma unroll
            for (int q=0;q<8;++q) inlref[q] = inl[q];
            proc512(X, Y, inlref, Rd, td);
        }
    }
    // final Procrustes + pose loss
    float Rfin[9], tfin[3];
    proc512(X, Y, inlref, Rfin, tfin);
    const float* Tb = Tmat + (size_t)b*16;
    float tr = 0.f;
    #pragma unroll
    for (int ci=0;ci<3;++ci)
      #pragma unroll
      for (int cj=0;cj<3;++cj)
        tr += Rfin[ci*3+cj] * Tb[ci*4+cj];
    float cosang = (tr - 1.0f) * 0.5f;
    cosang = fminf(fmaxf(cosang, -0.999999f), 0.999999f);
    float ang = acosf(cosang);
    float d0 = tfin[0]-Tb[3], d1 = tfin[1]-Tb[7], d2 = tfin[2]-Tb[11];
    float terr = sqrtf(d0*d0 + d1*d1 + d2*d2);
    float lr = 0.5f * tanhf(ang / 0.5f);
    float lt = 0.5f * tanhf(terr / 0.5f);
    float lv = 0.5f * (lr + lt);
    if (lane == 0) { scoreArr[blk] = score; lvArr[blk] = lv; }
}

// ---------------- Kernel F: softmax mixing + output ----------------
__global__ void kF(const float* __restrict__ scoreArr, const float* __restrict__ lvArr, float* __restrict__ out)
{
    int b = threadIdx.x;
    if (b >= NB) return;
    const float NULLSC = (float)(0.35 * 512.0);
    float total = 0.f;
    for (int i = 0; i < ITM; ++i) {
        float x[9], lvv[9], ee[9];
        for (int k = 0; k < 8; ++k) {
            x[k] = scoreArr[(i*NB + b)*ITR + k] / 10.0f;
            lvv[k] = lvArr[(i*NB + b)*ITR + k];
        }
        x[8] = NULLSC / 10.0f;
        lvv[8] = 0.5f;
        float m = x[0];
        for (int k = 1; k < 9; ++k) m = fmaxf(m, x[k]);
        float Ssum = 0.f;
        for (int k = 0; k < 9; ++k) { ee[k] = expf(x[k] - m); Ssum += ee[k]; }
        float acc = 0.f;
        for (int k = 0; k < 9; ++k) acc += lvv[k] * (ee[k] / Ssum);
        total += acc;
    }
    out[b] = total / 4.0f;
}

// ---------------- host ----------------
extern "C" void kernel_launch(void* const* d_in, const int* in_sizes, int n_in,
                              void* d_out, int out_size, void* d_ws, size_t ws_size,
                              hipStream_t stream)
{
    (void)in_sizes; (void)n_in; (void)out_size; (void)ws_size;
    const float* mat  = (const float*)d_in[0];
    const float* kps0 = (const float*)d_in[1];
    const float* dep0 = (const float*)d_in[2];
    const float* kps1 = (const float*)d_in[3];
    const float* dep1 = (const float*)d_in[4];
    const float* K0   = (const float*)d_in[5];
    const float* K1   = (const float*)d_in[6];
    const float* Tm   = (const float*)d_in[8];
    float* out = (float*)d_out;

    // JAX key schedule: key(42) -> (0,42); split() in partitionable (fold-like) mode
    Keys keys;
    {
        u32 k0 = 0u, k1 = 42u;
        for (int i = 0; i < ITM; ++i) {
            u32 a0,a1,b0,b1;
            tf2x32(k0,k1, 0u,0u, a0,a1);
            tf2x32(k0,k1, 0u,1u, b0,b1);
            k0=a0; k1=a1; keys.km[i][0]=b0; keys.km[i][1]=b1;
            for (int kk = 0; kk < ITR; ++kk) {
                tf2x32(k0,k1, 0u,0u, a0,a1);
                tf2x32(k0,k1, 0u,1u, b0,b1);
                k0=a0; k1=a1; keys.kr[i][kk][0]=b0; keys.kr[i][kk][1]=b1;
            }
        }
    }
    char* ws = (char*)d_ws;
    u32* cnts       = (u32*)(ws + OFF_CNTS);
    float* scoreArr = (float*)(ws + OFF_SC);
    float* lvArr    = (float*)(ws + OFF_LV);
    float* samp     = (float*)(ws + OFF_SAMP);
    u64* candC      = (u64*)(ws + OFF_CAND);

    kA<<<dim3(CHUNKS, NB), 256, 0, stream>>>(mat, keys, candC, cnts);
    kD<<<ITM*NB, 256, 0, stream>>>(mat, kps0, dep0, kps1, dep1, K0, K1, candC, cnts, samp);
    kE<<<ITM*NB*ITR, 64, 0, stream>>>(samp, Tm, keys, scoreArr, lvArr);
    kF<<<1, 64, 0, stream>>>(scoreArr, lvArr, out);
}

// Round 4
// 406.809 us; speedup vs baseline: 5.8062x; 1.1324x over previous
//
#include <hip/hip_runtime.h>
#include <stdint.h>

typedef unsigned long long u64;
typedef uint32_t u32;

#define NB 32            // batch
#define NKP 1024         // keypoints per image
#define ROWN (NKP*NKP)   // matches row length
#define NSAMP 512        // NUM_SAMPLES
#define ITM 4            // IT_MATCHES
#define ITR 8            // IT_RANSAC
#define NBIN 2048        // fine histogram bins over key range [2.0, 32.0)
#define KBASE 0xC0000000u  // monotone key of +2.0f
#define CHUNKS 64        // blocks per row (blockIdx.x)
#define SLOTS 256        // per-(i,chunk) candidate capacity (mean ~150, +8.6 sigma)
#define QCAP 768         // per-block survivor queue (expected ~82/itc, 76 sigma headroom)

struct Keys { u32 km[ITM][2]; u32 kr[ITM][ITR][2]; };

// ---------------- threefry2x32 (JAX-compatible, 20 rounds) ----------------
// rotl via __builtin_rotateleft32 -> single v_alignbit_b32 on gfx950
__host__ __device__ static inline u32 rotl32(u32 x, int d) { return __builtin_rotateleft32(x, (unsigned)d); }

__host__ __device__ static inline void tf2x32(u32 k0, u32 k1, u32 x0, u32 x1, u32& o0, u32& o1)
{
    u32 ks2 = k0 ^ k1 ^ 0x1BD11BDAu;
    x0 += k0; x1 += k1;
#define TFR(r) { x0 += x1; x1 = rotl32(x1, r); x1 ^= x0; }
    TFR(13) TFR(15) TFR(26) TFR(6)
    x0 += k1; x1 += ks2 + 1u;
    TFR(17) TFR(29) TFR(16) TFR(24)
    x0 += ks2; x1 += k0 + 2u;
    TFR(13) TFR(15) TFR(26) TFR(6)
    x0 += k0; x1 += k1 + 3u;
    TFR(17) TFR(29) TFR(16) TFR(24)
    x0 += k1; x1 += ks2 + 4u;
    TFR(13) TFR(15) TFR(26) TFR(6)
    x0 += ks2; x1 += k0 + 5u;
#undef TFR
    o0 = x0; o1 = x1;
}

// uniform(key, shape, 1e-6, 1-1e-6) bit-faithful to JAX (partitionable mode)
#define G_MINV 1e-6f
#define G_MAXV ((float)(1.0 - 1e-6))
#define G_SPAN (G_MAXV - G_MINV)

__device__ static inline float u_from_bits(u32 bits) {
    float f = __uint_as_float((bits >> 9) | 0x3f800000u) - 1.0f;
    float u = __fadd_rn(__fmul_rn(f, G_SPAN), G_MINV);  // no FMA contraction (match XLA)
    return fmaxf(G_MINV, u);
}

// integer early-out: bits >= 8220000<<9  <=>  (bits>>9) >= 8220000  <=>  u > ~0.97990,
// strict superset of u > 0.981851 needed for gumbel > 4 - log(max m). Exact path decides.
#define EARLY_TH9 (8220000u << 9)   // 4208640000

// monotone float->uint key (order-preserving for all non-NaN)
__device__ static inline u32 fkey(float v) {
    u32 u = __float_as_uint(v);
    return (u & 0x80000000u) ? ~u : (u | 0x80000000u);
}

// 64-lane butterfly sum (uniform result on all lanes)
__device__ static inline float wred(float v) {
    #pragma unroll
    for (int o = 1; o < 64; o <<= 1) v += __shfl_xor(v, o, 64);
    return v;
}

__device__ static inline u64 shfl_xor_u64(u64 v, int mask) {
    u32 lo = (u32)v, hi = (u32)(v >> 32);
    lo = __shfl_xor(lo, mask, 64);
    hi = __shfl_xor(hi, mask, 64);
    return ((u64)hi << 32) | (u64)lo;
}

// ---------------- 3x3 Kabsch via double-precision Jacobi SVD ----------------
__device__ static void kabsch(const float Hf[9], float Rf[9])
{
    double H00=Hf[0],H01=Hf[1],H02=Hf[2];
    double H10=Hf[3],H11=Hf[4],H12=Hf[5];
    double H20=Hf[6],H21=Hf[7],H22=Hf[8];
    double A00 = H00*H00 + H10*H10 + H20*H20;
    double A01 = H00*H01 + H10*H11 + H20*H21;
    double A02 = H00*H02 + H10*H12 + H20*H22;
    double A11 = H01*H01 + H11*H11 + H21*H21;
    double A12 = H01*H02 + H11*H12 + H21*H22;
    double A22 = H02*H02 + H12*H12 + H22*H22;
    double V00=1,V10=0,V20=0;
    double V01=0,V11=1,V21=0;
    double V02=0,V12=0,V22=1;
#define JROT(App,Aqq,Apq,Apr,Aqr, Vp0,Vp1,Vp2, Vq0,Vq1,Vq2) \
    if (fabs(Apq) > 0.0) { \
        double th = (Aqq - App) / (2.0 * Apq); \
        double tt = copysign(1.0, th) / (fabs(th) + sqrt(1.0 + th*th)); \
        double cc = 1.0 / sqrt(1.0 + tt*tt); \
        double ss = tt * cc; \
        double npp = App - tt*Apq, nqq = Aqq + tt*Apq; \
        double npr = cc*Apr - ss*Aqr, nqr = ss*Apr + cc*Aqr; \
        App = npp; Aqq = nqq; Apq = 0.0; Apr = npr; Aqr = nqr; \
        double tv; \
        tv = cc*Vp0 - ss*Vq0; Vq0 = ss*Vp0 + cc*Vq0; Vp0 = tv; \
        tv = cc*Vp1 - ss*Vq1; Vq1 = ss*Vp1 + cc*Vq1; Vp1 = tv; \
        tv = cc*Vp2 - ss*Vq2; Vq2 = ss*Vp2 + cc*Vq2; Vp2 = tv; \
    }
    for (int sw = 0; sw < 10; ++sw) {
        JROT(A00,A11,A01, A02,A12, V00,V10,V20, V01,V11,V21);
        JROT(A00,A22,A02, A01,A12, V00,V10,V20, V02,V12,V22);
        JROT(A11,A22,A12, A01,A02, V01,V11,V21, V02,V12,V22);
    }
#undef JROT
    double l0=A00, l1=A11, l2=A22;
    double e0[3]={V00,V10,V20}, e1[3]={V01,V11,V21}, e2[3]={V02,V12,V22};
    if (l0 < l1) { double t=l0;l0=l1;l1=t; for(int c=0;c<3;++c){double s=e0[c];e0[c]=e1[c];e1[c]=s;} }
    if (l0 < l2) { double t=l0;l0=l2;l2=t; for(int c=0;c<3;++c){double s=e0[c];e0[c]=e2[c];e2[c]=s;} }
    if (l1 < l2) { double t=l1;l1=l2;l2=t; for(int c=0;c<3;++c){double s=e1[c];e1[c]=e2[c];e2[c]=s;} }
    double u0[3], u1[3], u2[3];
#define HMUL(e,u) { u[0]=H00*e[0]+H01*e[1]+H02*e[2]; u[1]=H10*e[0]+H11*e[1]+H12*e[2]; u[2]=H20*e[0]+H21*e[1]+H22*e[2]; }
    HMUL(e0,u0) HMUL(e1,u1) HMUL(e2,u2)
#undef HMUL
    double s0 = sqrt(u0[0]*u0[0]+u0[1]*u0[1]+u0[2]*u0[2]);
    double s1 = sqrt(u1[0]*u1[0]+u1[1]*u1[1]+u1[2]*u1[2]);
    double s2 = sqrt(u2[0]*u2[0]+u2[1]*u2[1]+u2[2]*u2[2]);
    double eps = 1e-12 + 1e-6 * s0;
    if (s0 > 0.0) { u0[0]/=s0; u0[1]/=s0; u0[2]/=s0; } else { u0[0]=1.0; u0[1]=0.0; u0[2]=0.0; }
    if (s1 > eps) { u1[0]/=s1; u1[1]/=s1; u1[2]/=s1; }
    else {
        double ax0 = (fabs(u0[0]) < 0.9) ? 1.0 : 0.0;
        double ax1 = 1.0 - ax0;
        double dd = ax0*u0[0] + ax1*u0[1];
        double w0 = ax0 - dd*u0[0], w1 = ax1 - dd*u0[1], w2 = -dd*u0[2];
        double nn = sqrt(w0*w0+w1*w1+w2*w2);
        u1[0]=w0/nn; u1[1]=w1/nn; u1[2]=w2/nn;
    }
    if (s2 > eps) { u2[0]/=s2; u2[1]/=s2; u2[2]/=s2; }
    else {
        u2[0] = u0[1]*u1[2] - u0[2]*u1[1];
        u2[1] = u0[2]*u1[0] - u0[0]*u1[2];
        u2[2] = u0[0]*u1[1] - u0[1]*u1[0];
    }
    double M[3][3];
    #pragma unroll
    for (int i2=0;i2<3;++i2)
      #pragma unroll
      for (int j2=0;j2<3;++j2)
        M[i2][j2] = e0[i2]*u0[j2] + e1[i2]*u1[j2] + e2[i2]*u2[j2];
    double det = M[0][0]*(M[1][1]*M[2][2]-M[1][2]*M[2][1])
               - M[0][1]*(M[1][0]*M[2][2]-M[1][2]*M[2][0])
               + M[0][2]*(M[1][0]*M[2][1]-M[1][1]*M[2][0]);
    #pragma unroll
    for (int i2=0;i2<3;++i2)
      #pragma unroll
      for (int j2=0;j2<3;++j2)
        Rf[i2*3+j2] = (float)(e0[i2]*u0[j2] + e1[i2]*u1[j2] + det*(e2[i2]*u2[j2]));
}

__device__ static inline float dist1(const float R[9], const float t[3], const float x[3], const float y[3])
{
    float a = R[0]*x[0]+R[1]*x[1]+R[2]*x[2]+t[0]-y[0];
    float b = R[3]*x[0]+R[4]*x[1]+R[5]*x[2]+t[1]-y[1];
    float c = R[6]*x[0]+R[7]*x[1]+R[8]*x[2]+t[2]-y[2];
    return sqrtf(a*a+b*b+c*c);
}

// weighted Procrustes over the wave's 512 samples (8 per lane); uniform result
__device__ static void proc512(const float (&X)[8][3], const float (&Y)[8][3], const float (&w)[8],
                               float R[9], float t[3])
{
    float sw = 0.f;
    #pragma unroll
    for (int q=0;q<8;++q) sw += w[q];
    float S = wred(sw) + 1e-8f;
    float wn[8];
    #pragma unroll
    for (int q=0;q<8;++q) wn[q] = w[q] / S;
    float mx[3], my[3];
    #pragma unroll
    for (int c=0;c<3;++c) {
        float ax=0.f, ay=0.f;
        #pragma unroll
        for (int q=0;q<8;++q) { ax += wn[q]*X[q][c]; ay += wn[q]*Y[q][c]; }
        mx[c] = wred(ax); my[c] = wred(ay);
    }
    float Hf[9];
    #pragma unroll
    for (int ci=0;ci<3;++ci)
      #pragma unroll
      for (int cj=0;cj<3;++cj) {
        float h=0.f;
        #pragma unroll
        for (int q=0;q<8;++q) h += wn[q]*(X[q][ci]-mx[ci])*(Y[q][cj]-my[cj]);
        Hf[ci*3+cj] = wred(h);
      }
    kabsch(Hf, R);
    #pragma unroll
    for (int c=0;c<3;++c) t[c] = my[c] - (R[c*3+0]*mx[0] + R[c*3+1]*mx[1] + R[c*3+2]*mx[2]);
}

// 3x3 inverse, pivoted Gauss-Jordan (mirrors jnp.linalg.inv up to ulps)
__device__ static void inv3(const float* __restrict__ Kin, float* __restrict__ out)
{
    float a[3][6];
    for (int r=0;r<3;++r) for (int c=0;c<3;++c) { a[r][c]=Kin[r*3+c]; a[r][c+3] = (r==c)?1.f:0.f; }
    for (int col=0; col<3; ++col) {
        int piv = col;
        for (int r=col+1;r<3;++r) if (fabsf(a[r][col]) > fabsf(a[piv][col])) piv = r;
        if (piv != col) for (int c=0;c<6;++c) { float tt=a[col][c]; a[col][c]=a[piv][c]; a[piv][c]=tt; }
        float pv = a[col][col];
        for (int c=0;c<6;++c) a[col][c] /= pv;
        for (int r=0;r<3;++r) if (r != col) {
            float f = a[r][col];
            if (f != 0.f) for (int c=0;c<6;++c) a[r][c] -= f * a[col][c];
        }
    }
    for (int r=0;r<3;++r) for (int c=0;c<3;++c) out[r*3+c] = a[r][c+3];
}

// ---------------- workspace layout ----------------
static const size_t OFF_CNTS = 0;                                           // u32[ITM*NB*CHUNKS]
static const size_t OFF_SC   = OFF_CNTS + (size_t)ITM*NB*CHUNKS*4;          // f32[ITM*NB*ITR]
static const size_t OFF_LV   = OFF_SC   + (size_t)ITM*NB*ITR*4;             // f32[ITM*NB*ITR]
static const size_t OFF_SAMP = OFF_LV   + (size_t)ITM*NB*ITR*4;             // f32[ITM*NB*NSAMP*8]
static const size_t OFF_CAND = OFF_SAMP + (size_t)ITM*NB*NSAMP*8*4;         // u64[ITM*NB*CHUNKS*SLOTS]

// ---------------- Kernel A: scan matches -> per-block private candidate lists ----------------
// Hot loop: 4x threefry + 1 u32 compare per element. Survivors (~2%) go to an LDS queue,
// drained densely once per itc (transcendentals at full lane utilization). No global atomics.
__global__ __launch_bounds__(256) void kA(const float* __restrict__ mat, Keys keys,
                                          u64* __restrict__ candC, u32* __restrict__ cnts)
{
    __shared__ u64 lists[ITM][SLOTS];   // 8 KB
    __shared__ u32 lcnt[ITM];
    __shared__ u32 qbits[QCAP];         // 3 KB
    __shared__ float qm[QCAP];          // 3 KB
    __shared__ u32 qji[QCAP];           // 3 KB
    __shared__ u32 qcnt;
    int tid = threadIdx.x;
    int b = blockIdx.y;
    int chunk = blockIdx.x;
    if (tid < ITM) lcnt[tid] = 0;
    if (tid == 0) qcnt = 0;
    __syncthreads();
    const float4* rowp = reinterpret_cast<const float4*>(mat + (size_t)b * ROWN);
    int base = chunk * 4096;     // float4 units
    for (int itc = 0; itc < 16; ++itc) {
        int f4 = base + itc*256 + tid;
        float4 m4 = rowp[f4];
        float mv[4] = {m4.x, m4.y, m4.z, m4.w};
        u32 j0 = (u32)f4 * 4u;
        #pragma unroll
        for (int e = 0; e < 4; ++e) {
            u32 j = j0 + (u32)e;
            u32 flat = ((u32)b << 20) | j;
            #pragma unroll
            for (int i = 0; i < ITM; ++i) {
                u32 o0, o1; tf2x32(keys.km[i][0], keys.km[i][1], 0u, flat, o0, o1);
                u32 bits = o0 ^ o1;
                if (bits >= EARLY_TH9) {       // ~2% of lanes
                    u32 p = atomicAdd(&qcnt, 1u);
                    if (p < (u32)QCAP) {
                        qbits[p] = bits;
                        qm[p]    = mv[e];
                        qji[p]   = ((u32)i << 20) | j;   // j < 2^20
                    }
                }
            }
        }
        // dense drain of survivors (all lanes active on queued work)
        __syncthreads();
        u32 qn = qcnt; if (qn > (u32)QCAP) qn = QCAP;
        for (u32 t = tid; t < qn; t += 256) {
            u32 bits = qbits[t];
            float m  = qm[t];
            u32 ji   = qji[t];
            float u  = u_from_bits(bits);
            float g  = -logf(-logf(u));
            float lg = logf(m + 1e-12f);
            float v  = lg + g;
            if (v > 4.0f) {
                u32 i2 = ji >> 20;
                u32 jj = ji & 0xFFFFFu;
                u32 p = atomicAdd(&lcnt[i2], 1u);
                if (p < (u32)SLOTS)
                    lists[i2][p] = ((u64)fkey(v) << 32) | (u64)(u32)(~jj);
            }
        }
        __syncthreads();
        if (tid == 0) qcnt = 0;
        __syncthreads();
    }
    #pragma unroll
    for (int i = 0; i < ITM; ++i) {
        u32 n = lcnt[i]; if (n > (u32)SLOTS) n = SLOTS;
        for (u32 s = tid; s < n; s += 256)
            candC[(((size_t)(i*NB + b))*CHUNKS + chunk)*SLOTS + s] = lists[i][s];
    }
    if (tid < ITM) cnts[((size_t)(tid*NB + b))*CHUNKS + chunk] = min(lcnt[tid], (u32)SLOTS);
}

// ---------------- Kernel D: hist+cut+select+sort+backproject, one block per (iter,b) ----------------
__global__ __launch_bounds__(256) void kD(const float* __restrict__ mat,
        const float* __restrict__ kps0, const float* __restrict__ dep0,
        const float* __restrict__ kps1, const float* __restrict__ dep1,
        const float* __restrict__ K0, const float* __restrict__ K1,
        const u64* __restrict__ candC, const u32* __restrict__ cnts,
        float* __restrict__ samp)
{
    int ib = blockIdx.x;
    int b = ib % NB;
    int tid = threadIdx.x;
    __shared__ u32 hist[NBIN];     // 8 KB
    __shared__ u64 buf[2048];      // 16 KB
    __shared__ u32 ccnt[CHUNKS];
    __shared__ u32 gs[64];
    __shared__ u32 nkeep, cutkey_s;
    __shared__ float Ki[2][9];
    for (int idx = tid; idx < NBIN; idx += 256) hist[idx] = 0;
    for (int idx = tid; idx < 2048; idx += 256) buf[idx] = 0ull;
    if (tid < CHUNKS) ccnt[tid] = cnts[(size_t)ib*CHUNKS + tid];
    if (tid == 0) nkeep = 0;
    __syncthreads();
    const u64* cd = candC + (size_t)ib * CHUNKS * SLOTS;
    // pass 1: histogram of candidate keys
    for (int t = tid; t < CHUNKS*SLOTS; t += 256) {
        int c = t >> 8, s = t & (SLOTS-1);
        if ((u32)s < ccnt[c]) {
            u32 key = (u32)(cd[t] >> 32);
            u32 bin = (key - KBASE) >> 14;
            if (bin > (u32)(NBIN-1)) bin = NBIN-1;
            atomicAdd(&hist[bin], 1u);
        }
    }
    __syncthreads();
    // exact rank-512 cut bin
    if (tid < 64) {
        u32 ssum = 0;
        int top = NBIN-1 - tid*32;
        for (int k = 0; k < 32; ++k) ssum += hist[top - k];
        gs[tid] = ssum;
    }
    __syncthreads();
    if (tid == 0) {
        u32 cum = 0; int cutbin = -1;
        for (int g = 0; g < 64; ++g) {
            if (cum + gs[g] >= (u32)NSAMP) {
                int t2 = NBIN-1 - g*32;
                for (int k = 0; k < 32; ++k) {
                    u32 c = hist[t2 - k];
                    if (cum + c >= (u32)NSAMP) { cutbin = t2 - k; break; }
                    cum += c;
                }
                break;
            }
            cum += gs[g];
        }
        cutkey_s = (cutbin >= 0) ? (KBASE + ((u32)cutbin << 14)) : 0u;
    }
    __syncthreads();
    u32 cutkey = cutkey_s;
    // pass 2: filter >= cutkey into sort buffer
    for (int t = tid; t < CHUNKS*SLOTS; t += 256) {
        int c = t >> 8, s = t & (SLOTS-1);
        if ((u32)s < ccnt[c]) {
            u64 cv = cd[t];
            if ((u32)(cv >> 32) >= cutkey) {
                u32 p = atomicAdd(&nkeep, 1u);
                if (p < 2048u) buf[p] = cv;
            }
        }
    }
    __syncthreads();
    // bitonic ascending; pads (0) sink to the front; top-512 = buf[2047-r]
    for (int k = 2; k <= 2048; k <<= 1) {
        for (int j = k >> 1; j > 0; j >>= 1) {
            for (int i2 = tid; i2 < 2048; i2 += 256) {
                int ixj = i2 ^ j;
                if (ixj > i2) {
                    bool up = ((i2 & k) == 0);
                    u64 a = buf[i2], c2 = buf[ixj];
                    bool dosw = up ? (a > c2) : (a < c2);
                    if (dosw) { buf[i2] = c2; buf[ixj] = a; }
                }
            }
            __syncthreads();
        }
    }
    if (tid == 0) { inv3(K0 + (size_t)b*9, Ki[0]); inv3(K1 + (size_t)b*9, Ki[1]); }
    __syncthreads();
    for (int r = tid; r < NSAMP; r += 256) {
        u64 c = buf[2047 - r];
        u32 j = (~(u32)(c & 0xFFFFFFFFull)) & (u32)(ROWN - 1);
        int i0 = (int)(j >> 10);
        int i1 = (int)(j & 1023u);
        float uu0 = kps0[(size_t)b*2*NKP + i0];
        float vv0 = kps0[(size_t)b*2*NKP + NKP + i0];
        float dd0 = dep0[(size_t)b*2*NKP + i0];
        float uu1 = kps1[(size_t)b*2*NKP + i1];
        float vv1 = kps1[(size_t)b*2*NKP + NKP + i1];
        float dd1 = dep1[(size_t)b*2*NKP + i1];
        float r0 = Ki[0][0]*uu0 + Ki[0][1]*vv0 + Ki[0][2];
        float r1 = Ki[0][3]*uu0 + Ki[0][4]*vv0 + Ki[0][5];
        float r2 = Ki[0][6]*uu0 + Ki[0][7]*vv0 + Ki[0][8];
        float q0 = Ki[1][0]*uu1 + Ki[1][1]*vv1 + Ki[1][2];
        float q1 = Ki[1][3]*uu1 + Ki[1][4]*vv1 + Ki[1][5];
        float q2 = Ki[1][6]*uu1 + Ki[1][7]*vv1 + Ki[1][8];
        float w = mat[(size_t)b*ROWN + j];
        float* sp = samp + ((size_t)ib*NSAMP + r)*8;
        sp[0] = dd0*r0; sp[1] = dd0*r1; sp[2] = dd0*r2;
        sp[3] = dd1*q0; sp[4] = dd1*q1; sp[5] = dd1*q2;
        sp[6] = logf(w + 1e-12f);
        sp[7] = 0.f;
    }
}

// ---------------- Kernel E: one wave per RANSAC hypothesis ----------------
__global__ __launch_bounds__(64) void kE(const float* __restrict__ samp, const float* __restrict__ Tmat,
                                         Keys keys, float* __restrict__ scoreArr, float* __restrict__ lvArr)
{
    int blk = blockIdx.x;
    int kk = blk & 7;
    int ib = blk >> 3;
    int i = ib / NB;
    int b = ib % NB;
    int lane = threadIdx.x;
    const float* s = samp + (size_t)ib * NSAMP * 8;
    float X[8][3], Y[8][3], lw[8];
    #pragma unroll
    for (int q = 0; q < 8; ++q) {
        const float4* p = reinterpret_cast<const float4*>(s + (size_t)(q*64 + lane)*8);
        float4 a0 = p[0], a1 = p[1];
        X[q][0]=a0.x; X[q][1]=a0.y; X[q][2]=a0.z;
        Y[q][0]=a0.w; Y[q][1]=a1.x; Y[q][2]=a1.y;
        lw[q]=a1.z;
    }
    // inner gumbel + composite keys
    u64 comp[8];
    #pragma unroll
    for (int q = 0; q < 8; ++q) {
        u32 j = (u32)(q*64 + lane);
        u32 o0,o1; tf2x32(keys.kr[i][kk][0], keys.kr[i][kk][1], 0u, (u32)(b*NSAMP) + j, o0,o1);
        float u = u_from_bits(o0^o1);
        float g = -logf(-logf(u));
        float v = lw[q] + g;
        comp[q] = ((u64)fkey(v) << 32) | (u64)(u32)(~j);
    }
    // top-5 (value desc, index asc) via 5 wave arg-max rounds
    int ridx[5];
    #pragma unroll
    for (int r = 0; r < 5; ++r) {
        u64 m = comp[0];
        #pragma unroll
        for (int q=1;q<8;++q) if (comp[q] > m) m = comp[q];
        #pragma unroll
        for (int o=1;o<64;o<<=1) { u64 x = shfl_xor_u64(m,o); if (x > m) m = x; }
        ridx[r] = (int)((~(u32)(m & 0xFFFFFFFFull)) & (u32)(NSAMP-1));
        #pragma unroll
        for (int q=0;q<8;++q) if (comp[q] == m) comp[q] = 0ull;
    }
    // 5-point Procrustes (uniform weights) — all lanes compute identically
    float Xk[5][3], Yk[5][3];
    #pragma unroll
    for (int r=0;r<5;++r) {
        const float* p = s + (size_t)ridx[r]*8;
        Xk[r][0]=p[0]; Xk[r][1]=p[1]; Xk[r][2]=p[2];
        Yk[r][0]=p[3]; Yk[r][1]=p[4]; Yk[r][2]=p[5];
    }
    float S5 = 5.0f + 1e-8f;
    float wn5 = 1.0f / S5;
    float mx[3]={0,0,0}, my[3]={0,0,0};
    #pragma unroll
    for (int r=0;r<5;++r) {
        #pragma unroll
        for (int c=0;c<3;++c) { mx[c] += wn5*Xk[r][c]; my[c] += wn5*Yk[r][c]; }
    }
    float Hf[9] = {0,0,0,0,0,0,0,0,0};
    #pragma unroll
    for (int r=0;r<5;++r)
      #pragma unroll
      for (int ci=0;ci<3;++ci)
        #pragma unroll
        for (int cj=0;cj<3;++cj)
          Hf[ci*3+cj] += wn5*(Xk[r][ci]-mx[ci])*(Yk[r][cj]-my[cj]);
    float Rpre[9], tpre[3];
    kabsch(Hf, Rpre);
    #pragma unroll
    for (int c=0;c<3;++c) tpre[c] = my[c] - (Rpre[c*3+0]*mx[0] + Rpre[c*3+1]*mx[1] + Rpre[c*3+2]*mx[2]);
    // score over all 512 samples
    const float BETAF = (float)(5.0/0.15);
    float partial = 0.f;
    #pragma unroll
    for (int q=0;q<8;++q) {
        float d = dist1(Rpre, tpre, X[q], Y[q]);
        float z = BETAF * (0.15f - d);
        partial += 1.0f / (1.0f + expf(-z));
    }
    float score = wred(partial);
    // refinement (4 steps, exact do-gating)
    float inlref[8];
    #pragma unroll
    for (int q=0;q<8;++q) {
        int j = q*64 + lane;
        inlref[q] = (j==ridx[0] || j==ridx[1] || j==ridx[2] || j==ridx[3] || j==ridx[4]) ? 1.0f : 0.0f;
    }
    float Rd[9], td[3];
    #pragma unroll
    for (int c2=0;c2<9;++c2) Rd[c2]=Rpre[c2];
    td[0]=tpre[0]; td[1]=tpre[1]; td[2]=tpre[2];
    float inl_pre = 0.f;
    for (int step=0; step<4; ++step) {
        float inl[8]; float csum = 0.f;
        #pragma unroll
        for (int q=0;q<8;++q) {
            float d = dist1(Rd, td, X[q], Y[q]);
            inl[q] = (d < 0.15f) ? 1.0f : 0.0f;
            csum += inl[q];
        }
        float cnt = wred(csum);
        bool doit = (cnt >= 5.0f) && (cnt > inl_pre);
        inl_pre = cnt;
        if (doit) {
            #pragma unroll
            for (int q=0;q<8;++q) inlref[q] = inl[q];
            proc512(X, Y, inlref, Rd, td);
        }
    }
    // final Procrustes + pose loss
    float Rfin[9], tfin[3];
    proc512(X, Y, inlref, Rfin, tfin);
    const float* Tb = Tmat + (size_t)b*16;
    float tr = 0.f;
    #pragma unroll
    for (int ci=0;ci<3;++ci)
      #pragma unroll
      for (int cj=0;cj<3;++cj)
        tr += Rfin[ci*3+cj] * Tb[ci*4+cj];
    float cosang = (tr - 1.0f) * 0.5f;
    cosang = fminf(fmaxf(cosang, -0.999999f), 0.999999f);
    float ang = acosf(cosang);
    float d0 = tfin[0]-Tb[3], d1 = tfin[1]-Tb[7], d2 = tfin[2]-Tb[11];
    float terr = sqrtf(d0*d0 + d1*d1 + d2*d2);
    float lr = 0.5f * tanhf(ang / 0.5f);
    float lt = 0.5f * tanhf(terr / 0.5f);
    float lv = 0.5f * (lr + lt);
    if (lane == 0) { scoreArr[blk] = score; lvArr[blk] = lv; }
}

// ---------------- Kernel F: softmax mixing + output ----------------
__global__ void kF(const float* __restrict__ scoreArr, const float* __restrict__ lvArr, float* __restrict__ out)
{
    int b = threadIdx.x;
    if (b >= NB) return;
    const float NULLSC = (float)(0.35 * 512.0);
    float total = 0.f;
    for (int i = 0; i < ITM; ++i) {
        float x[9], lvv[9], ee[9];
        for (int k = 0; k < 8; ++k) {
            x[k] = scoreArr[(i*NB + b)*ITR + k] / 10.0f;
            lvv[k] = lvArr[(i*NB + b)*ITR + k];
        }
        x[8] = NULLSC / 10.0f;
        lvv[8] = 0.5f;
        float m = x[0];
        for (int k = 1; k < 9; ++k) m = fmaxf(m, x[k]);
        float Ssum = 0.f;
        for (int k = 0; k < 9; ++k) { ee[k] = expf(x[k] - m); Ssum += ee[k]; }
        float acc = 0.f;
        for (int k = 0; k < 9; ++k) acc += lvv[k] * (ee[k] / Ssum);
        total += acc;
    }
    out[b] = total / 4.0f;
}

// ---------------- host ----------------
extern "C" void kernel_launch(void* const* d_in, const int* in_sizes, int n_in,
                              void* d_out, int out_size, void* d_ws, size_t ws_size,
                              hipStream_t stream)
{
    (void)in_sizes; (void)n_in; (void)out_size; (void)ws_size;
    const float* mat  = (const float*)d_in[0];
    const float* kps0 = (const float*)d_in[1];
    const float* dep0 = (const float*)d_in[2];
    const float* kps1 = (const float*)d_in[3];
    const float* dep1 = (const float*)d_in[4];
    const float* K0   = (const float*)d_in[5];
    const float* K1   = (const float*)d_in[6];
    const float* Tm   = (const float*)d_in[8];
    float* out = (float*)d_out;

    // JAX key schedule: key(42) -> (0,42); split() in partitionable (fold-like) mode
    Keys keys;
    {
        u32 k0 = 0u, k1 = 42u;
        for (int i = 0; i < ITM; ++i) {
            u32 a0,a1,b0,b1;
            tf2x32(k0,k1, 0u,0u, a0,a1);
            tf2x32(k0,k1, 0u,1u, b0,b1);
            k0=a0; k1=a1; keys.km[i][0]=b0; keys.km[i][1]=b1;
            for (int kk = 0; kk < ITR; ++kk) {
                tf2x32(k0,k1, 0u,0u, a0,a1);
                tf2x32(k0,k1, 0u,1u, b0,b1);
                k0=a0; k1=a1; keys.kr[i][kk][0]=b0; keys.kr[i][kk][1]=b1;
            }
        }
    }
    char* ws = (char*)d_ws;
    u32* cnts       = (u32*)(ws + OFF_CNTS);
    float* scoreArr = (float*)(ws + OFF_SC);
    float* lvArr    = (float*)(ws + OFF_LV);
    float* samp     = (float*)(ws + OFF_SAMP);
    u64* candC      = (u64*)(ws + OFF_CAND);

    kA<<<dim3(CHUNKS, NB), 256, 0, stream>>>(mat, keys, candC, cnts);
    kD<<<ITM*NB, 256, 0, stream>>>(mat, kps0, dep0, kps1, dep1, K0, K1, candC, cnts, samp);
    kE<<<ITM*NB*ITR, 64, 0, stream>>>(samp, Tm, keys, scoreArr, lvArr);
    kF<<<1, 64, 0, stream>>>(scoreArr, lvArr, out);
}

// Round 5
// 400.140 us; speedup vs baseline: 5.9030x; 1.0167x over previous
//
#include <hip/hip_runtime.h>
#include <stdint.h>

typedef unsigned long long u64;
typedef uint32_t u32;

#define NB 32            // batch
#define NKP 1024         // keypoints per image
#define ROWN (NKP*NKP)   // matches row length
#define NSAMP 512        // NUM_SAMPLES
#define ITM 4            // IT_MATCHES
#define ITR 8            // IT_RANSAC
#define NBIN 2048        // fine histogram bins over key range [2.0, 32.0)
#define KBASE 0xC0000000u  // monotone key of +2.0f
#define CHUNKS 64        // blocks per row (blockIdx.x)
#define SLOTS 256        // per-(i,chunk) candidate capacity (mean ~151, +8.6 sigma)
#define QCAP 1024        // survivor queue per drain window (mean ~329, +38 sigma)

struct Keys { u32 km[ITM][2]; u32 kr[ITM][ITR][2]; };

// ---------------- threefry2x32 (JAX-compatible, 20 rounds) ----------------
__host__ __device__ static inline u32 rotl32(u32 x, int d) { return __builtin_rotateleft32(x, (unsigned)d); }

__host__ __device__ static inline void tf2x32(u32 k0, u32 k1, u32 x0, u32 x1, u32& o0, u32& o1)
{
    u32 ks2 = k0 ^ k1 ^ 0x1BD11BDAu;
    x0 += k0; x1 += k1;
#define TFR(r) { x0 += x1; x1 = rotl32(x1, r); x1 ^= x0; }
    TFR(13) TFR(15) TFR(26) TFR(6)
    x0 += k1; x1 += ks2 + 1u;
    TFR(17) TFR(29) TFR(16) TFR(24)
    x0 += ks2; x1 += k0 + 2u;
    TFR(13) TFR(15) TFR(26) TFR(6)
    x0 += k0; x1 += k1 + 3u;
    TFR(17) TFR(29) TFR(16) TFR(24)
    x0 += k1; x1 += ks2 + 4u;
    TFR(13) TFR(15) TFR(26) TFR(6)
    x0 += ks2; x1 += k0 + 5u;
#undef TFR
    o0 = x0; o1 = x1;
}

// uniform(key, shape, 1e-6, 1-1e-6) bit-faithful to JAX (partitionable mode)
#define G_MINV 1e-6f
#define G_MAXV ((float)(1.0 - 1e-6))
#define G_SPAN (G_MAXV - G_MINV)

__device__ static inline float u_from_bits(u32 bits) {
    float f = __uint_as_float((bits >> 9) | 0x3f800000u) - 1.0f;
    float u = __fadd_rn(__fmul_rn(f, G_SPAN), G_MINV);  // no FMA contraction (match XLA)
    return fmaxf(G_MINV, u);
}

// integer early-out: bits >= 8220000<<9  <=>  u > ~0.97990, strict superset of the
// u > 0.981851 needed for gumbel > 4 - log(max m). Exact float path decides.
#define EARLY_TH9 (8220000u << 9)   // 4208640000

// monotone float->uint key (order-preserving for all non-NaN)
__device__ static inline u32 fkey(float v) {
    u32 u = __float_as_uint(v);
    return (u & 0x80000000u) ? ~u : (u | 0x80000000u);
}

// 64-lane butterfly sum (uniform result on all lanes)
__device__ static inline float wred(float v) {
    #pragma unroll
    for (int o = 1; o < 64; o <<= 1) v += __shfl_xor(v, o, 64);
    return v;
}

__device__ static inline u64 shfl_xor_u64(u64 v, int mask) {
    u32 lo = (u32)v, hi = (u32)(v >> 32);
    lo = __shfl_xor(lo, mask, 64);
    hi = __shfl_xor(hi, mask, 64);
    return ((u64)hi << 32) | (u64)lo;
}

// ---------------- 3x3 Kabsch via double-precision Jacobi SVD ----------------
__device__ static void kabsch(const float Hf[9], float Rf[9])
{
    double H00=Hf[0],H01=Hf[1],H02=Hf[2];
    double H10=Hf[3],H11=Hf[4],H12=Hf[5];
    double H20=Hf[6],H21=Hf[7],H22=Hf[8];
    double A00 = H00*H00 + H10*H10 + H20*H20;
    double A01 = H00*H01 + H10*H11 + H20*H21;
    double A02 = H00*H02 + H10*H12 + H20*H22;
    double A11 = H01*H01 + H11*H11 + H21*H21;
    double A12 = H01*H02 + H11*H12 + H21*H22;
    double A22 = H02*H02 + H12*H12 + H22*H22;
    double V00=1,V10=0,V20=0;
    double V01=0,V11=1,V21=0;
    double V02=0,V12=0,V22=1;
#define JROT(App,Aqq,Apq,Apr,Aqr, Vp0,Vp1,Vp2, Vq0,Vq1,Vq2) \
    if (fabs(Apq) > 0.0) { \
        double th = (Aqq - App) / (2.0 * Apq); \
        double tt = copysign(1.0, th) / (fabs(th) + sqrt(1.0 + th*th)); \
        double cc = 1.0 / sqrt(1.0 + tt*tt); \
        double ss = tt * cc; \
        double npp = App - tt*Apq, nqq = Aqq + tt*Apq; \
        double npr = cc*Apr - ss*Aqr, nqr = ss*Apr + cc*Aqr; \
        App = npp; Aqq = nqq; Apq = 0.0; Apr = npr; Aqr = nqr; \
        double tv; \
        tv = cc*Vp0 - ss*Vq0; Vq0 = ss*Vp0 + cc*Vq0; Vp0 = tv; \
        tv = cc*Vp1 - ss*Vq1; Vq1 = ss*Vp1 + cc*Vq1; Vp1 = tv; \
        tv = cc*Vp2 - ss*Vq2; Vq2 = ss*Vp2 + cc*Vq2; Vp2 = tv; \
    }
    for (int sw = 0; sw < 10; ++sw) {
        JROT(A00,A11,A01, A02,A12, V00,V10,V20, V01,V11,V21);
        JROT(A00,A22,A02, A01,A12, V00,V10,V20, V02,V12,V22);
        JROT(A11,A22,A12, A01,A02, V01,V11,V21, V02,V12,V22);
    }
#undef JROT
    double l0=A00, l1=A11, l2=A22;
    double e0[3]={V00,V10,V20}, e1[3]={V01,V11,V21}, e2[3]={V02,V12,V22};
    if (l0 < l1) { double t=l0;l0=l1;l1=t; for(int c=0;c<3;++c){double s=e0[c];e0[c]=e1[c];e1[c]=s;} }
    if (l0 < l2) { double t=l0;l0=l2;l2=t; for(int c=0;c<3;++c){double s=e0[c];e0[c]=e2[c];e2[c]=s;} }
    if (l1 < l2) { double t=l1;l1=l2;l2=t; for(int c=0;c<3;++c){double s=e1[c];e1[c]=e2[c];e2[c]=s;} }
    double u0[3], u1[3], u2[3];
#define HMUL(e,u) { u[0]=H00*e[0]+H01*e[1]+H02*e[2]; u[1]=H10*e[0]+H11*e[1]+H12*e[2]; u[2]=H20*e[0]+H21*e[1]+H22*e[2]; }
    HMUL(e0,u0) HMUL(e1,u1) HMUL(e2,u2)
#undef HMUL
    double s0 = sqrt(u0[0]*u0[0]+u0[1]*u0[1]+u0[2]*u0[2]);
    double s1 = sqrt(u1[0]*u1[0]+u1[1]*u1[1]+u1[2]*u1[2]);
    double s2 = sqrt(u2[0]*u2[0]+u2[1]*u2[1]+u2[2]*u2[2]);
    double eps = 1e-12 + 1e-6 * s0;
    if (s0 > 0.0) { u0[0]/=s0; u0[1]/=s0; u0[2]/=s0; } else { u0[0]=1.0; u0[1]=0.0; u0[2]=0.0; }
    if (s1 > eps) { u1[0]/=s1; u1[1]/=s1; u1[2]/=s1; }
    else {
        double ax0 = (fabs(u0[0]) < 0.9) ? 1.0 : 0.0;
        double ax1 = 1.0 - ax0;
        double dd = ax0*u0[0] + ax1*u0[1];
        double w0 = ax0 - dd*u0[0], w1 = ax1 - dd*u0[1], w2 = -dd*u0[2];
        double nn = sqrt(w0*w0+w1*w1+w2*w2);
        u1[0]=w0/nn; u1[1]=w1/nn; u1[2]=w2/nn;
    }
    if (s2 > eps) { u2[0]/=s2; u2[1]/=s2; u2[2]/=s2; }
    else {
        u2[0] = u0[1]*u1[2] - u0[2]*u1[1];
        u2[1] = u0[2]*u1[0] - u0[0]*u1[2];
        u2[2] = u0[0]*u1[1] - u0[1]*u1[0];
    }
    double M[3][3];
    #pragma unroll
    for (int i2=0;i2<3;++i2)
      #pragma unroll
      for (int j2=0;j2<3;++j2)
        M[i2][j2] = e0[i2]*u0[j2] + e1[i2]*u1[j2] + e2[i2]*u2[j2];
    double det = M[0][0]*(M[1][1]*M[2][2]-M[1][2]*M[2][1])
               - M[0][1]*(M[1][0]*M[2][2]-M[1][2]*M[2][0])
               + M[0][2]*(M[1][0]*M[2][1]-M[1][1]*M[2][0]);
    #pragma unroll
    for (int i2=0;i2<3;++i2)
      #pragma unroll
      for (int j2=0;j2<3;++j2)
        Rf[i2*3+j2] = (float)(e0[i2]*u0[j2] + e1[i2]*u1[j2] + det*(e2[i2]*u2[j2]));
}

__device__ static inline float dist1(const float R[9], const float t[3], const float x[3], const float y[3])
{
    float a = R[0]*x[0]+R[1]*x[1]+R[2]*x[2]+t[0]-y[0];
    float b = R[3]*x[0]+R[4]*x[1]+R[5]*x[2]+t[1]-y[1];
    float c = R[6]*x[0]+R[7]*x[1]+R[8]*x[2]+t[2]-y[2];
    return sqrtf(a*a+b*b+c*c);
}

// weighted Procrustes over the wave's 512 samples (8 per lane); uniform result
__device__ static void proc512(const float (&X)[8][3], const float (&Y)[8][3], const float (&w)[8],
                               float R[9], float t[3])
{
    float sw = 0.f;
    #pragma unroll
    for (int q=0;q<8;++q) sw += w[q];
    float S = wred(sw) + 1e-8f;
    float wn[8];
    #pragma unroll
    for (int q=0;q<8;++q) wn[q] = w[q] / S;
    float mx[3], my[3];
    #pragma unroll
    for (int c=0;c<3;++c) {
        float ax=0.f, ay=0.f;
        #pragma unroll
        for (int q=0;q<8;++q) { ax += wn[q]*X[q][c]; ay += wn[q]*Y[q][c]; }
        mx[c] = wred(ax); my[c] = wred(ay);
    }
    float Hf[9];
    #pragma unroll
    for (int ci=0;ci<3;++ci)
      #pragma unroll
      for (int cj=0;cj<3;++cj) {
        float h=0.f;
        #pragma unroll
        for (int q=0;q<8;++q) h += wn[q]*(X[q][ci]-mx[ci])*(Y[q][cj]-my[cj]);
        Hf[ci*3+cj] = wred(h);
      }
    kabsch(Hf, R);
    #pragma unroll
    for (int c=0;c<3;++c) t[c] = my[c] - (R[c*3+0]*mx[0] + R[c*3+1]*mx[1] + R[c*3+2]*mx[2]);
}

// 3x3 inverse, pivoted Gauss-Jordan (mirrors jnp.linalg.inv up to ulps)
__device__ static void inv3(const float* __restrict__ Kin, float* __restrict__ out)
{
    float a[3][6];
    for (int r=0;r<3;++r) for (int c=0;c<3;++c) { a[r][c]=Kin[r*3+c]; a[r][c+3] = (r==c)?1.f:0.f; }
    for (int col=0; col<3; ++col) {
        int piv = col;
        for (int r=col+1;r<3;++r) if (fabsf(a[r][col]) > fabsf(a[piv][col])) piv = r;
        if (piv != col) for (int c=0;c<6;++c) { float tt=a[col][c]; a[col][c]=a[piv][c]; a[piv][c]=tt; }
        float pv = a[col][col];
        for (int c=0;c<6;++c) a[col][c] /= pv;
        for (int r=0;r<3;++r) if (r != col) {
            float f = a[r][col];
            if (f != 0.f) for (int c=0;c<6;++c) a[r][c] -= f * a[col][c];
        }
    }
    for (int r=0;r<3;++r) for (int c=0;c<3;++c) out[r*3+c] = a[r][c+3];
}

// ---------------- workspace layout ----------------
static const size_t OFF_CNTS = 0;                                           // u32[ITM*NB*CHUNKS]
static const size_t OFF_SC   = OFF_CNTS + (size_t)ITM*NB*CHUNKS*4;          // f32[ITM*NB*ITR]
static const size_t OFF_LV   = OFF_SC   + (size_t)ITM*NB*ITR*4;             // f32[ITM*NB*ITR]
static const size_t OFF_SAMP = OFF_LV   + (size_t)ITM*NB*ITR*4;             // f32[ITM*NB*NSAMP*8]
static const size_t OFF_CAND = OFF_SAMP + (size_t)ITM*NB*NSAMP*8*4;         // u64[ITM*NB*CHUNKS*SLOTS]

// ---------------- Kernel A: pure-threefry hot loop + deferred survivor drain ----------------
// Hot loop: 4x threefry + 1 compare per element — NO matrix load, NO transcendentals.
// Survivors (~2%) queue one u64 (bits|i|j) in LDS; drained densely 4x per block, reading
// mat[j] on demand (scattered, latency-hidden). No global atomics anywhere.
__global__ __launch_bounds__(256) void kA(const float* __restrict__ mat, Keys keys,
                                          u64* __restrict__ candC, u32* __restrict__ cnts)
{
    __shared__ u64 lists[ITM][SLOTS];   // 8 KB
    __shared__ u32 lcnt[ITM];
    __shared__ u64 q[QCAP];             // 8 KB
    __shared__ u32 qcnt;
    int tid = threadIdx.x;
    int b = blockIdx.y;
    int chunk = blockIdx.x;
    if (tid < ITM) lcnt[tid] = 0;
    if (tid == 0) qcnt = 0;
    __syncthreads();
    const float* rowb = mat + (size_t)b * ROWN;
    u32 jbase = (u32)chunk * 16384u + (u32)tid;
    for (int seg = 0; seg < 4; ++seg) {
        for (int lp = 0; lp < 16; ++lp) {
            u32 j = jbase + (u32)((seg*16 + lp) << 8);
            u32 flat = ((u32)b << 20) | j;
            #pragma unroll
            for (int i = 0; i < ITM; ++i) {
                u32 o0, o1; tf2x32(keys.km[i][0], keys.km[i][1], 0u, flat, o0, o1);
                u32 bits = o0 ^ o1;
                if (bits >= EARLY_TH9) {       // ~2% of lanes
                    u32 p = atomicAdd(&qcnt, 1u);
                    if (p < (u32)QCAP)
                        q[p] = ((u64)bits << 32) | ((u64)(u32)i << 20) | (u64)j;
                }
            }
        }
        // dense drain (all lanes active on queued work)
        __syncthreads();
        u32 qn = qcnt; if (qn > (u32)QCAP) qn = QCAP;
        for (u32 t = tid; t < qn; t += 256) {
            u64 e  = q[t];
            u32 bits = (u32)(e >> 32);
            u32 i2 = ((u32)e >> 20) & 3u;
            u32 jj = (u32)e & 0xFFFFFu;
            float m  = rowb[jj];               // demand fetch (L2/HBM), latency-hidden
            float u  = u_from_bits(bits);
            float g  = -logf(-logf(u));
            float v  = logf(m + 1e-12f) + g;
            if (v > 4.0f) {
                u32 p = atomicAdd(&lcnt[i2], 1u);
                if (p < (u32)SLOTS)
                    lists[i2][p] = ((u64)fkey(v) << 32) | (u64)(u32)(~jj);
            }
        }
        __syncthreads();
        if (tid == 0) qcnt = 0;
        __syncthreads();
    }
    #pragma unroll
    for (int i = 0; i < ITM; ++i) {
        u32 n = lcnt[i]; if (n > (u32)SLOTS) n = SLOTS;
        for (u32 s = tid; s < n; s += 256)
            candC[(((size_t)(i*NB + b))*CHUNKS + chunk)*SLOTS + s] = lists[i][s];
    }
    if (tid < ITM) cnts[((size_t)(tid*NB + b))*CHUNKS + chunk] = min(lcnt[tid], (u32)SLOTS);
}

// ---------------- Kernel D: hist+cut+select+sort+backproject, one block per (iter,b) ----------------
__global__ __launch_bounds__(256) void kD(const float* __restrict__ mat,
        const float* __restrict__ kps0, const float* __restrict__ dep0,
        const float* __restrict__ kps1, const float* __restrict__ dep1,
        const float* __restrict__ K0, const float* __restrict__ K1,
        const u64* __restrict__ candC, const u32* __restrict__ cnts,
        float* __restrict__ samp)
{
    int ib = blockIdx.x;
    int b = ib % NB;
    int tid = threadIdx.x;
    __shared__ u32 hist[NBIN];     // 8 KB
    __shared__ u64 buf[2048];      // 16 KB
    __shared__ u32 ccnt[CHUNKS];
    __shared__ u32 gs[64];
    __shared__ u32 nkeep, cutkey_s;
    __shared__ float Ki[2][9];
    for (int idx = tid; idx < NBIN; idx += 256) hist[idx] = 0;
    for (int idx = tid; idx < 2048; idx += 256) buf[idx] = 0ull;
    if (tid < CHUNKS) ccnt[tid] = cnts[(size_t)ib*CHUNKS + tid];
    if (tid == 0) nkeep = 0;
    __syncthreads();
    const u64* cd = candC + (size_t)ib * CHUNKS * SLOTS;
    // pass 1: histogram of candidate keys
    for (int t = tid; t < CHUNKS*SLOTS; t += 256) {
        int c = t >> 8, s = t & (SLOTS-1);
        if ((u32)s < ccnt[c]) {
            u32 key = (u32)(cd[t] >> 32);
            u32 bin = (key - KBASE) >> 14;
            if (bin > (u32)(NBIN-1)) bin = NBIN-1;
            atomicAdd(&hist[bin], 1u);
        }
    }
    __syncthreads();
    // exact rank-512 cut bin
    if (tid < 64) {
        u32 ssum = 0;
        int top = NBIN-1 - tid*32;
        for (int k = 0; k < 32; ++k) ssum += hist[top - k];
        gs[tid] = ssum;
    }
    __syncthreads();
    if (tid == 0) {
        u32 cum = 0; int cutbin = -1;
        for (int g = 0; g < 64; ++g) {
            if (cum + gs[g] >= (u32)NSAMP) {
                int t2 = NBIN-1 - g*32;
                for (int k = 0; k < 32; ++k) {
                    u32 c = hist[t2 - k];
                    if (cum + c >= (u32)NSAMP) { cutbin = t2 - k; break; }
                    cum += c;
                }
                break;
            }
            cum += gs[g];
        }
        cutkey_s = (cutbin >= 0) ? (KBASE + ((u32)cutbin << 14)) : 0u;
    }
    __syncthreads();
    u32 cutkey = cutkey_s;
    // pass 2: filter >= cutkey into sort buffer
    for (int t = tid; t < CHUNKS*SLOTS; t += 256) {
        int c = t >> 8, s = t & (SLOTS-1);
        if ((u32)s < ccnt[c]) {
            u64 cv = cd[t];
            if ((u32)(cv >> 32) >= cutkey) {
                u32 p = atomicAdd(&nkeep, 1u);
                if (p < 2048u) buf[p] = cv;
            }
        }
    }
    __syncthreads();
    // bitonic ascending; pads (0) sink to the front; top-512 = buf[2047-r]
    for (int k = 2; k <= 2048; k <<= 1) {
        for (int j = k >> 1; j > 0; j >>= 1) {
            for (int i2 = tid; i2 < 2048; i2 += 256) {
                int ixj = i2 ^ j;
                if (ixj > i2) {
                    bool up = ((i2 & k) == 0);
                    u64 a = buf[i2], c2 = buf[ixj];
                    bool dosw = up ? (a > c2) : (a < c2);
                    if (dosw) { buf[i2] = c2; buf[ixj] = a; }
                }
            }
            __syncthreads();
        }
    }
    if (tid == 0) { inv3(K0 + (size_t)b*9, Ki[0]); inv3(K1 + (size_t)b*9, Ki[1]); }
    __syncthreads();
    for (int r = tid; r < NSAMP; r += 256) {
        u64 c = buf[2047 - r];
        u32 j = (~(u32)(c & 0xFFFFFFFFull)) & (u32)(ROWN - 1);
        int i0 = (int)(j >> 10);
        int i1 = (int)(j & 1023u);
        float uu0 = kps0[(size_t)b*2*NKP + i0];
        float vv0 = kps0[(size_t)b*2*NKP + NKP + i0];
        float dd0 = dep0[(size_t)b*2*NKP + i0];
        float uu1 = kps1[(size_t)b*2*NKP + i1];
        float vv1 = kps1[(size_t)b*2*NKP + NKP + i1];
        float dd1 = dep1[(size_t)b*2*NKP + i1];
        float r0 = Ki[0][0]*uu0 + Ki[0][1]*vv0 + Ki[0][2];
        float r1 = Ki[0][3]*uu0 + Ki[0][4]*vv0 + Ki[0][5];
        float r2 = Ki[0][6]*uu0 + Ki[0][7]*vv0 + Ki[0][8];
        float q0 = Ki[1][0]*uu1 + Ki[1][1]*vv1 + Ki[1][2];
        float q1 = Ki[1][3]*uu1 + Ki[1][4]*vv1 + Ki[1][5];
        float q2 = Ki[1][6]*uu1 + Ki[1][7]*vv1 + Ki[1][8];
        float w = mat[(size_t)b*ROWN + j];
        float* sp = samp + ((size_t)ib*NSAMP + r)*8;
        sp[0] = dd0*r0; sp[1] = dd0*r1; sp[2] = dd0*r2;
        sp[3] = dd1*q0; sp[4] = dd1*q1; sp[5] = dd1*q2;
        sp[6] = logf(w + 1e-12f);
        sp[7] = 0.f;
    }
}

// ---------------- Kernel E: one wave per RANSAC hypothesis ----------------
__global__ __launch_bounds__(64) void kE(const float* __restrict__ samp, const float* __restrict__ Tmat,
                                         Keys keys, float* __restrict__ scoreArr, float* __restrict__ lvArr)
{
    int blk = blockIdx.x;
    int kk = blk & 7;
    int ib = blk >> 3;
    int i = ib / NB;
    int b = ib % NB;
    int lane = threadIdx.x;
    const float* s = samp + (size_t)ib * NSAMP * 8;
    float X[8][3], Y[8][3], lw[8];
    #pragma unroll
    for (int q = 0; q < 8; ++q) {
        const float4* p = reinterpret_cast<const float4*>(s + (size_t)(q*64 + lane)*8);
        float4 a0 = p[0], a1 = p[1];
        X[q][0]=a0.x; X[q][1]=a0.y; X[q][2]=a0.z;
        Y[q][0]=a0.w; Y[q][1]=a1.x; Y[q][2]=a1.y;
        lw[q]=a1.z;
    }
    // inner gumbel + composite keys
    u64 comp[8];
    #pragma unroll
    for (int q = 0; q < 8; ++q) {
        u32 j = (u32)(q*64 + lane);
        u32 o0,o1; tf2x32(keys.kr[i][kk][0], keys.kr[i][kk][1], 0u, (u32)(b*NSAMP) + j, o0,o1);
        float u = u_from_bits(o0^o1);
        float g = -logf(-logf(u));
        float v = lw[q] + g;
        comp[q] = ((u64)fkey(v) << 32) | (u64)(u32)(~j);
    }
    // top-5 (value desc, index asc) via 5 wave arg-max rounds
    int ridx[5];
    #pragma unroll
    for (int r = 0; r < 5; ++r) {
        u64 m = comp[0];
        #pragma unroll
        for (int q=1;q<8;++q) if (comp[q] > m) m = comp[q];
        #pragma unroll
        for (int o=1;o<64;o<<=1) { u64 x = shfl_xor_u64(m,o); if (x > m) m = x; }
        ridx[r] = (int)((~(u32)(m & 0xFFFFFFFFull)) & (u32)(NSAMP-1));
        #pragma unroll
        for (int q=0;q<8;++q) if (comp[q] == m) comp[q] = 0ull;
    }
    // 5-point Procrustes (uniform weights) — all lanes compute identically
    float Xk[5][3], Yk[5][3];
    #pragma unroll
    for (int r=0;r<5;++r) {
        const float* p = s + (size_t)ridx[r]*8;
        Xk[r][0]=p[0]; Xk[r][1]=p[1]; Xk[r][2]=p[2];
        Yk[r][0]=p[3]; Yk[r][1]=p[4]; Yk[r][2]=p[5];
    }
    float S5 = 5.0f + 1e-8f;
    float wn5 = 1.0f / S5;
    float mx[3]={0,0,0}, my[3]={0,0,0};
    #pragma unroll
    for (int r=0;r<5;++r) {
        #pragma unroll
        for (int c=0;c<3;++c) { mx[c] += wn5*Xk[r][c]; my[c] += wn5*Yk[r][c]; }
    }
    float Hf[9] = {0,0,0,0,0,0,0,0,0};
    #pragma unroll
    for (int r=0;r<5;++r)
      #pragma unroll
      for (int ci=0;ci<3;++ci)
        #pragma unroll
        for (int cj=0;cj<3;++cj)
          Hf[ci*3+cj] += wn5*(Xk[r][ci]-mx[ci])*(Yk[r][cj]-my[cj]);
    float Rpre[9], tpre[3];
    kabsch(Hf, Rpre);
    #pragma unroll
    for (int c=0;c<3;++c) tpre[c] = my[c] - (Rpre[c*3+0]*mx[0] + Rpre[c*3+1]*mx[1] + Rpre[c*3+2]*mx[2]);
    // score over all 512 samples
    const float BETAF = (float)(5.0/0.15);
    float partial = 0.f;
    #pragma unroll
    for (int q=0;q<8;++q) {
        float d = dist1(Rpre, tpre, X[q], Y[q]);
        float z = BETAF * (0.15f - d);
        partial += 1.0f / (1.0f + expf(-z));
    }
    float score = wred(partial);
    // refinement (4 steps, exact do-gating)
    float inlref[8];
    #pragma unroll
    for (int q=0;q<8;++q) {
        int j = q*64 + lane;
        inlref[q] = (j==ridx[0] || j==ridx[1] || j==ridx[2] || j==ridx[3] || j==ridx[4]) ? 1.0f : 0.0f;
    }
    float Rd[9], td[3];
    #pragma unroll
    for (int c2=0;c2<9;++c2) Rd[c2]=Rpre[c2];
    td[0]=tpre[0]; td[1]=tpre[1]; td[2]=tpre[2];
    float inl_pre = 0.f;
    for (int step=0; step<4; ++step) {
        float inl[8]; float csum = 0.f;
        #pragma unroll
        for (int q=0;q<8;++q) {
            float d = dist1(Rd, td, X[q], Y[q]);
            inl[q] = (d < 0.15f) ? 1.0f : 0.0f;
            csum += inl[q];
        }
        float cnt = wred(csum);
        bool doit = (cnt >= 5.0f) && (cnt > inl_pre);
        inl_pre = cnt;
        if (doit) {
            #pragma unroll
            for (int q=0;q<8;++q) inlref[q] = inl[q];
            proc512(X, Y, inlref, Rd, td);
        }
    }
    // final Procrustes + pose loss
    float Rfin[9], tfin[3];
    proc512(X, Y, inlref, Rfin, tfin);
    const float* Tb = Tmat + (size_t)b*16;
    float tr = 0.f;
    #pragma unroll
    for (int ci=0;ci<3;++ci)
      #pragma unroll
      for (int cj=0;cj<3;++cj)
        tr += Rfin[ci*3+cj] * Tb[ci*4+cj];
    float cosang = (tr - 1.0f) * 0.5f;
    cosang = fminf(fmaxf(cosang, -0.999999f), 0.999999f);
    float ang = acosf(cosang);
    float d0 = tfin[0]-Tb[3], d1 = tfin[1]-Tb[7], d2 = tfin[2]-Tb[11];
    float terr = sqrtf(d0*d0 + d1*d1 + d2*d2);
    float lr = 0.5f * tanhf(ang / 0.5f);
    float lt = 0.5f * tanhf(terr / 0.5f);
    float lv = 0.5f * (lr + lt);
    if (lane == 0) { scoreArr[blk] = score; lvArr[blk] = lv; }
}

// ---------------- Kernel F: softmax mixing + output ----------------
__global__ void kF(const float* __restrict__ scoreArr, const float* __restrict__ lvArr, float* __restrict__ out)
{
    int b = threadIdx.x;
    if (b >= NB) return;
    const float NULLSC = (float)(0.35 * 512.0);
    float total = 0.f;
    for (int i = 0; i < ITM; ++i) {
        float x[9], lvv[9], ee[9];
        for (int k = 0; k < 8; ++k) {
            x[k] = scoreArr[(i*NB + b)*ITR + k] / 10.0f;
            lvv[k] = lvArr[(i*NB + b)*ITR + k];
        }
        x[8] = NULLSC / 10.0f;
        lvv[8] = 0.5f;
        float m = x[0];
        for (int k = 1; k < 9; ++k) m = fmaxf(m, x[k]);
        float Ssum = 0.f;
        for (int k = 0; k < 9; ++k) { ee[k] = expf(x[k] - m); Ssum += ee[k]; }
        float acc = 0.f;
        for (int k = 0; k < 9; ++k) acc += lvv[k] * (ee[k] / Ssum);
        total += acc;
    }
    out[b] = total / 4.0f;
}

// ---------------- host ----------------
extern "C" void kernel_launch(void* const* d_in, const int* in_sizes, int n_in,
                              void* d_out, int out_size, void* d_ws, size_t ws_size,
                              hipStream_t stream)
{
    (void)in_sizes; (void)n_in; (void)out_size; (void)ws_size;
    const float* mat  = (const float*)d_in[0];
    const float* kps0 = (const float*)d_in[1];
    const float* dep0 = (const float*)d_in[2];
    const float* kps1 = (const float*)d_in[3];
    const float* dep1 = (const float*)d_in[4];
    const float* K0   = (const float*)d_in[5];
    const float* K1   = (const float*)d_in[6];
    const float* Tm   = (const float*)d_in[8];
    float* out = (float*)d_out;

    // JAX key schedule: key(42) -> (0,42); split() in partitionable (fold-like) mode
    Keys keys;
    {
        u32 k0 = 0u, k1 = 42u;
        for (int i = 0; i < ITM; ++i) {
            u32 a0,a1,b0,b1;
            tf2x32(k0,k1, 0u,0u, a0,a1);
            tf2x32(k0,k1, 0u,1u, b0,b1);
            k0=a0; k1=a1; keys.km[i][0]=b0; keys.km[i][1]=b1;
            for (int kk = 0; kk < ITR; ++kk) {
                tf2x32(k0,k1, 0u,0u, a0,a1);
                tf2x32(k0,k1, 0u,1u, b0,b1);
                k0=a0; k1=a1; keys.kr[i][kk][0]=b0; keys.kr[i][kk][1]=b1;
            }
        }
    }
    char* ws = (char*)d_ws;
    u32* cnts       = (u32*)(ws + OFF_CNTS);
    float* scoreArr = (float*)(ws + OFF_SC);
    float* lvArr    = (float*)(ws + OFF_LV);
    float* samp     = (float*)(ws + OFF_SAMP);
    u64* candC      = (u64*)(ws + OFF_CAND);

    kA<<<dim3(CHUNKS, NB), 256, 0, stream>>>(mat, keys, candC, cnts);
    kD<<<ITM*NB, 256, 0, stream>>>(mat, kps0, dep0, kps1, dep1, K0, K1, candC, cnts, samp);
    kE<<<ITM*NB*ITR, 64, 0, stream>>>(samp, Tm, keys, scoreArr, lvArr);
    kF<<<1, 64, 0, stream>>>(scoreArr, lvArr, out);
}

// Round 6
// 397.401 us; speedup vs baseline: 5.9437x; 1.0069x over previous
//
#include <hip/hip_runtime.h>
#include <stdint.h>

typedef unsigned long long u64;
typedef uint32_t u32;

#define NB 32            // batch
#define NKP 1024         // keypoints per image
#define ROWN (NKP*NKP)   // matches row length
#define NSAMP 512        // NUM_SAMPLES
#define ITM 4            // IT_MATCHES
#define ITR 8            // IT_RANSAC
#define NBIN 2048        // fine histogram bins over key range [2.0, 32.0)
#define KBASE 0xC0000000u  // monotone key of +2.0f
#define CHUNKS 64        // blocks per row (blockIdx.x)
#define SLOTS 256        // per-(i,chunk) candidate capacity (mean ~151, +8.6 sigma)
#define QCAP 1024        // survivor queue per drain window (mean ~669, +13.7 sigma)

struct Keys { u32 km[ITM][2]; u32 kr[ITM][ITR][2]; };

// ---------------- threefry2x32 (JAX-compatible, 20 rounds) ----------------
__host__ __device__ static inline u32 rotl32(u32 x, int d) { return __builtin_rotateleft32(x, (unsigned)d); }

__host__ __device__ static inline void tf2x32(u32 k0, u32 k1, u32 x0, u32 x1, u32& o0, u32& o1)
{
    u32 ks2 = k0 ^ k1 ^ 0x1BD11BDAu;
    x0 += k0; x1 += k1;
#define TFR(r) { x0 += x1; x1 = rotl32(x1, r); x1 ^= x0; }
    TFR(13) TFR(15) TFR(26) TFR(6)
    x0 += k1; x1 += ks2 + 1u;
    TFR(17) TFR(29) TFR(16) TFR(24)
    x0 += ks2; x1 += k0 + 2u;
    TFR(13) TFR(15) TFR(26) TFR(6)
    x0 += k0; x1 += k1 + 3u;
    TFR(17) TFR(29) TFR(16) TFR(24)
    x0 += k1; x1 += ks2 + 4u;
    TFR(13) TFR(15) TFR(26) TFR(6)
    x0 += ks2; x1 += k0 + 5u;
#undef TFR
    o0 = x0; o1 = x1;
}

// 4 keyed threefry chains advanced round-major in lockstep: ILP=4 inside one wave.
// Returns bits[i] = o0^o1 for key km[i], counter (0, flat). Value-identical to tf2x32.
__device__ static inline void tf4(const Keys& K, u32 flat, u32 bits[ITM])
{
    u32 x0[ITM], x1[ITM];
    #pragma unroll
    for (int i = 0; i < ITM; ++i) {
        x0[i] = K.km[i][0];                 // 0 + k0 (SGPR, folded)
        x1[i] = flat + K.km[i][1];
    }
#define R4(rot) { _Pragma("unroll") \
    for (int i = 0; i < ITM; ++i) { x0[i] += x1[i]; x1[i] = rotl32(x1[i], rot); x1[i] ^= x0[i]; } }
#define INJ(a_expr, b_expr) { _Pragma("unroll") \
    for (int i = 0; i < ITM; ++i) { u32 k0 = K.km[i][0], k1 = K.km[i][1]; \
        u32 ks2 = k0 ^ k1 ^ 0x1BD11BDAu; (void)k0; (void)k1; (void)ks2; \
        x0[i] += (a_expr); x1[i] += (b_expr); } }
    R4(13) R4(15) R4(26) R4(6)
    INJ(k1,      ks2 + 1u)
    R4(17) R4(29) R4(16) R4(24)
    INJ(ks2,     k0 + 2u)
    R4(13) R4(15) R4(26) R4(6)
    INJ(k0,      k1 + 3u)
    R4(17) R4(29) R4(16) R4(24)
    INJ(k1,      ks2 + 4u)
    R4(13) R4(15) R4(26) R4(6)
    INJ(ks2,     k0 + 5u)
#undef R4
#undef INJ
    #pragma unroll
    for (int i = 0; i < ITM; ++i) bits[i] = x0[i] ^ x1[i];
}

// uniform(key, shape, 1e-6, 1-1e-6) bit-faithful to JAX (partitionable mode)
#define G_MINV 1e-6f
#define G_MAXV ((float)(1.0 - 1e-6))
#define G_SPAN (G_MAXV - G_MINV)

__device__ static inline float u_from_bits(u32 bits) {
    float f = __uint_as_float((bits >> 9) | 0x3f800000u) - 1.0f;
    float u = __fadd_rn(__fmul_rn(f, G_SPAN), G_MINV);  // no FMA contraction (match XLA)
    return fmaxf(G_MINV, u);
}

// integer early-out: bits >= 8220000<<9  <=>  u > ~0.97990, strict superset of the
// u > 0.981851 needed for gumbel > 4 - log(max m). Exact float path decides.
#define EARLY_TH9 (8220000u << 9)   // 4208640000

// monotone float->uint key (order-preserving for all non-NaN)
__device__ static inline u32 fkey(float v) {
    u32 u = __float_as_uint(v);
    return (u & 0x80000000u) ? ~u : (u | 0x80000000u);
}

// 64-lane butterfly sum (uniform result on all lanes)
__device__ static inline float wred(float v) {
    #pragma unroll
    for (int o = 1; o < 64; o <<= 1) v += __shfl_xor(v, o, 64);
    return v;
}

__device__ static inline u64 shfl_xor_u64(u64 v, int mask) {
    u32 lo = (u32)v, hi = (u32)(v >> 32);
    lo = __shfl_xor(lo, mask, 64);
    hi = __shfl_xor(hi, mask, 64);
    return ((u64)hi << 32) | (u64)lo;
}

// ---------------- 3x3 Kabsch via double-precision Jacobi SVD ----------------
// 5 sweeps: 3x3 cyclic Jacobi is quadratically convergent; off-diag < 1e-14 by sweep 5.
__device__ static void kabsch(const float Hf[9], float Rf[9])
{
    double H00=Hf[0],H01=Hf[1],H02=Hf[2];
    double H10=Hf[3],H11=Hf[4],H12=Hf[5];
    double H20=Hf[6],H21=Hf[7],H22=Hf[8];
    double A00 = H00*H00 + H10*H10 + H20*H20;
    double A01 = H00*H01 + H10*H11 + H20*H21;
    double A02 = H00*H02 + H10*H12 + H20*H22;
    double A11 = H01*H01 + H11*H11 + H21*H21;
    double A12 = H01*H02 + H11*H12 + H21*H22;
    double A22 = H02*H02 + H12*H12 + H22*H22;
    double V00=1,V10=0,V20=0;
    double V01=0,V11=1,V21=0;
    double V02=0,V12=0,V22=1;
#define JROT(App,Aqq,Apq,Apr,Aqr, Vp0,Vp1,Vp2, Vq0,Vq1,Vq2) \
    if (fabs(Apq) > 0.0) { \
        double th = (Aqq - App) / (2.0 * Apq); \
        double tt = copysign(1.0, th) / (fabs(th) + sqrt(1.0 + th*th)); \
        double cc = 1.0 / sqrt(1.0 + tt*tt); \
        double ss = tt * cc; \
        double npp = App - tt*Apq, nqq = Aqq + tt*Apq; \
        double npr = cc*Apr - ss*Aqr, nqr = ss*Apr + cc*Aqr; \
        App = npp; Aqq = nqq; Apq = 0.0; Apr = npr; Aqr = nqr; \
        double tv; \
        tv = cc*Vp0 - ss*Vq0; Vq0 = ss*Vp0 + cc*Vq0; Vp0 = tv; \
        tv = cc*Vp1 - ss*Vq1; Vq1 = ss*Vp1 + cc*Vq1; Vp1 = tv; \
        tv = cc*Vp2 - ss*Vq2; Vq2 = ss*Vp2 + cc*Vq2; Vp2 = tv; \
    }
    for (int sw = 0; sw < 5; ++sw) {
        JROT(A00,A11,A01, A02,A12, V00,V10,V20, V01,V11,V21);
        JROT(A00,A22,A02, A01,A12, V00,V10,V20, V02,V12,V22);
        JROT(A11,A22,A12, A01,A02, V01,V11,V21, V02,V12,V22);
    }
#undef JROT
    double l0=A00, l1=A11, l2=A22;
    double e0[3]={V00,V10,V20}, e1[3]={V01,V11,V21}, e2[3]={V02,V12,V22};
    if (l0 < l1) { double t=l0;l0=l1;l1=t; for(int c=0;c<3;++c){double s=e0[c];e0[c]=e1[c];e1[c]=s;} }
    if (l0 < l2) { double t=l0;l0=l2;l2=t; for(int c=0;c<3;++c){double s=e0[c];e0[c]=e2[c];e2[c]=s;} }
    if (l1 < l2) { double t=l1;l1=l2;l2=t; for(int c=0;c<3;++c){double s=e1[c];e1[c]=e2[c];e2[c]=s;} }
    double u0[3], u1[3], u2[3];
#define HMUL(e,u) { u[0]=H00*e[0]+H01*e[1]+H02*e[2]; u[1]=H10*e[0]+H11*e[1]+H12*e[2]; u[2]=H20*e[0]+H21*e[1]+H22*e[2]; }
    HMUL(e0,u0) HMUL(e1,u1) HMUL(e2,u2)
#undef HMUL
    double s0 = sqrt(u0[0]*u0[0]+u0[1]*u0[1]+u0[2]*u0[2]);
    double s1 = sqrt(u1[0]*u1[0]+u1[1]*u1[1]+u1[2]*u1[2]);
    double s2 = sqrt(u2[0]*u2[0]+u2[1]*u2[1]+u2[2]*u2[2]);
    double eps = 1e-12 + 1e-6 * s0;
    if (s0 > 0.0) { u0[0]/=s0; u0[1]/=s0; u0[2]/=s0; } else { u0[0]=1.0; u0[1]=0.0; u0[2]=0.0; }
    if (s1 > eps) { u1[0]/=s1; u1[1]/=s1; u1[2]/=s1; }
    else {
        double ax0 = (fabs(u0[0]) < 0.9) ? 1.0 : 0.0;
        double ax1 = 1.0 - ax0;
        double dd = ax0*u0[0] + ax1*u0[1];
        double w0 = ax0 - dd*u0[0], w1 = ax1 - dd*u0[1], w2 = -dd*u0[2];
        double nn = sqrt(w0*w0+w1*w1+w2*w2);
        u1[0]=w0/nn; u1[1]=w1/nn; u1[2]=w2/nn;
    }
    if (s2 > eps) { u2[0]/=s2; u2[1]/=s2; u2[2]/=s2; }
    else {
        u2[0] = u0[1]*u1[2] - u0[2]*u1[1];
        u2[1] = u0[2]*u1[0] - u0[0]*u1[2];
        u2[2] = u0[0]*u1[1] - u0[1]*u1[0];
    }
    double M[3][3];
    #pragma unroll
    for (int i2=0;i2<3;++i2)
      #pragma unroll
      for (int j2=0;j2<3;++j2)
        M[i2][j2] = e0[i2]*u0[j2] + e1[i2]*u1[j2] + e2[i2]*u2[j2];
    double det = M[0][0]*(M[1][1]*M[2][2]-M[1][2]*M[2][1])
               - M[0][1]*(M[1][0]*M[2][2]-M[1][2]*M[2][0])
               + M[0][2]*(M[1][0]*M[2][1]-M[1][1]*M[2][0]);
    #pragma unroll
    for (int i2=0;i2<3;++i2)
      #pragma unroll
      for (int j2=0;j2<3;++j2)
        Rf[i2*3+j2] = (float)(e0[i2]*u0[j2] + e1[i2]*u1[j2] + det*(e2[i2]*u2[j2]));
}

__device__ static inline float dist1(const float R[9], const float t[3], const float x[3], const float y[3])
{
    float a = R[0]*x[0]+R[1]*x[1]+R[2]*x[2]+t[0]-y[0];
    float b = R[3]*x[0]+R[4]*x[1]+R[5]*x[2]+t[1]-y[1];
    float c = R[6]*x[0]+R[7]*x[1]+R[8]*x[2]+t[2]-y[2];
    return sqrtf(a*a+b*b+c*c);
}

// weighted Procrustes over the wave's 512 samples (8 per lane); uniform result
__device__ static void proc512(const float (&X)[8][3], const float (&Y)[8][3], const float (&w)[8],
                               float R[9], float t[3])
{
    float sw = 0.f;
    #pragma unroll
    for (int q=0;q<8;++q) sw += w[q];
    float S = wred(sw) + 1e-8f;
    float wn[8];
    #pragma unroll
    for (int q=0;q<8;++q) wn[q] = w[q] / S;
    float mx[3], my[3];
    #pragma unroll
    for (int c=0;c<3;++c) {
        float ax=0.f, ay=0.f;
        #pragma unroll
        for (int q=0;q<8;++q) { ax += wn[q]*X[q][c]; ay += wn[q]*Y[q][c]; }
        mx[c] = wred(ax); my[c] = wred(ay);
    }
    float Hf[9];
    #pragma unroll
    for (int ci=0;ci<3;++ci)
      #pragma unroll
      for (int cj=0;cj<3;++cj) {
        float h=0.f;
        #pragma unroll
        for (int q=0;q<8;++q) h += wn[q]*(X[q][ci]-mx[ci])*(Y[q][cj]-my[cj]);
        Hf[ci*3+cj] = wred(h);
      }
    kabsch(Hf, R);
    #pragma unroll
    for (int c=0;c<3;++c) t[c] = my[c] - (R[c*3+0]*mx[0] + R[c*3+1]*mx[1] + R[c*3+2]*mx[2]);
}

// 3x3 inverse, pivoted Gauss-Jordan (mirrors jnp.linalg.inv up to ulps)
__device__ static void inv3(const float* __restrict__ Kin, float* __restrict__ out)
{
    float a[3][6];
    for (int r=0;r<3;++r) for (int c=0;c<3;++c) { a[r][c]=Kin[r*3+c]; a[r][c+3] = (r==c)?1.f:0.f; }
    for (int col=0; col<3; ++col) {
        int piv = col;
        for (int r=col+1;r<3;++r) if (fabsf(a[r][col]) > fabsf(a[piv][col])) piv = r;
        if (piv != col) for (int c=0;c<6;++c) { float tt=a[col][c]; a[col][c]=a[piv][c]; a[piv][c]=tt; }
        float pv = a[col][col];
        for (int c=0;c<6;++c) a[col][c] /= pv;
        for (int r=0;r<3;++r) if (r != col) {
            float f = a[r][col];
            if (f != 0.f) for (int c=0;c<6;++c) a[r][c] -= f * a[col][c];
        }
    }
    for (int r=0;r<3;++r) for (int c=0;c<3;++c) out[r*3+c] = a[r][c+3];
}

// ---------------- workspace layout ----------------
static const size_t OFF_CNTS = 0;                                           // u32[ITM*NB*CHUNKS]
static const size_t OFF_SC   = OFF_CNTS + (size_t)ITM*NB*CHUNKS*4;          // f32[ITM*NB*ITR]
static const size_t OFF_LV   = OFF_SC   + (size_t)ITM*NB*ITR*4;             // f32[ITM*NB*ITR]
static const size_t OFF_SAMP = OFF_LV   + (size_t)ITM*NB*ITR*4;             // f32[ITM*NB*NSAMP*8]
static const size_t OFF_CAND = OFF_SAMP + (size_t)ITM*NB*NSAMP*8*4;         // u64[ITM*NB*CHUNKS*SLOTS]

// ---------------- Kernel A: ILP-4 threefry hot loop + deferred survivor drain ----------------
__global__ __launch_bounds__(256) void kA(const float* __restrict__ mat, Keys keys,
                                          u64* __restrict__ candC, u32* __restrict__ cnts)
{
    __shared__ u64 lists[ITM][SLOTS];   // 8 KB
    __shared__ u32 lcnt[ITM];
    __shared__ u64 q[QCAP];             // 8 KB
    __shared__ u32 qcnt;
    int tid = threadIdx.x;
    int b = blockIdx.y;
    int chunk = blockIdx.x;
    if (tid < ITM) lcnt[tid] = 0;
    if (tid == 0) qcnt = 0;
    __syncthreads();
    const float* rowb = mat + (size_t)b * ROWN;
    u32 jbase = (u32)chunk * 16384u + (u32)tid;
    for (int seg = 0; seg < 2; ++seg) {
        for (int lp = 0; lp < 32; ++lp) {
            u32 j = jbase + (u32)((seg*32 + lp) << 8);
            u32 flat = ((u32)b << 20) | j;
            u32 bits[ITM];
            tf4(keys, flat, bits);
            #pragma unroll
            for (int i = 0; i < ITM; ++i) {
                if (bits[i] >= EARLY_TH9) {       // ~2% of lanes
                    u32 p = atomicAdd(&qcnt, 1u);
                    if (p < (u32)QCAP)
                        q[p] = ((u64)bits[i] << 32) | ((u64)(u32)i << 20) | (u64)j;
                }
            }
        }
        // dense drain (all lanes active on queued work)
        __syncthreads();
        u32 qn = qcnt; if (qn > (u32)QCAP) qn = QCAP;
        for (u32 t = tid; t < qn; t += 256) {
            u64 e  = q[t];
            u32 bits = (u32)(e >> 32);
            u32 i2 = ((u32)e >> 20) & 3u;
            u32 jj = (u32)e & 0xFFFFFu;
            float m  = rowb[jj];               // demand fetch (L2/L3), latency-hidden
            float u  = u_from_bits(bits);
            float g  = -logf(-logf(u));
            float v  = logf(m + 1e-12f) + g;
            if (v > 4.0f) {
                u32 p = atomicAdd(&lcnt[i2], 1u);
                if (p < (u32)SLOTS)
                    lists[i2][p] = ((u64)fkey(v) << 32) | (u64)(u32)(~jj);
            }
        }
        __syncthreads();
        if (tid == 0) qcnt = 0;
        __syncthreads();
    }
    #pragma unroll
    for (int i = 0; i < ITM; ++i) {
        u32 n = lcnt[i]; if (n > (u32)SLOTS) n = SLOTS;
        for (u32 s = tid; s < n; s += 256)
            candC[(((size_t)(i*NB + b))*CHUNKS + chunk)*SLOTS + s] = lists[i][s];
    }
    if (tid < ITM) cnts[((size_t)(tid*NB + b))*CHUNKS + chunk] = min(lcnt[tid], (u32)SLOTS);
}

// ---------------- Kernel D: hist+cut+select+sort+backproject, one block per (iter,b) ----------------
__global__ __launch_bounds__(256) void kD(const float* __restrict__ mat,
        const float* __restrict__ kps0, const float* __restrict__ dep0,
        const float* __restrict__ kps1, const float* __restrict__ dep1,
        const float* __restrict__ K0, const float* __restrict__ K1,
        const u64* __restrict__ candC, const u32* __restrict__ cnts,
        float* __restrict__ samp)
{
    int ib = blockIdx.x;
    int b = ib % NB;
    int tid = threadIdx.x;
    __shared__ u32 hist[NBIN];     // 8 KB
    __shared__ u64 buf[2048];      // 16 KB
    __shared__ u32 ccnt[CHUNKS];
    __shared__ u32 gs[64];
    __shared__ u32 nkeep, cutkey_s;
    __shared__ float Ki[2][9];
    for (int idx = tid; idx < NBIN; idx += 256) hist[idx] = 0;
    for (int idx = tid; idx < 2048; idx += 256) buf[idx] = 0ull;
    if (tid < CHUNKS) ccnt[tid] = cnts[(size_t)ib*CHUNKS + tid];
    if (tid == 0) nkeep = 0;
    __syncthreads();
    const u64* cd = candC + (size_t)ib * CHUNKS * SLOTS;
    // pass 1: histogram of candidate keys
    for (int t = tid; t < CHUNKS*SLOTS; t += 256) {
        int c = t >> 8, s = t & (SLOTS-1);
        if ((u32)s < ccnt[c]) {
            u32 key = (u32)(cd[t] >> 32);
            u32 bin = (key - KBASE) >> 14;
            if (bin > (u32)(NBIN-1)) bin = NBIN-1;
            atomicAdd(&hist[bin], 1u);
        }
    }
    __syncthreads();
    // exact rank-512 cut bin
    if (tid < 64) {
        u32 ssum = 0;
        int top = NBIN-1 - tid*32;
        for (int k = 0; k < 32; ++k) ssum += hist[top - k];
        gs[tid] = ssum;
    }
    __syncthreads();
    if (tid == 0) {
        u32 cum = 0; int cutbin = -1;
        for (int g = 0; g < 64; ++g) {
            if (cum + gs[g] >= (u32)NSAMP) {
                int t2 = NBIN-1 - g*32;
                for (int k = 0; k < 32; ++k) {
                    u32 c = hist[t2 - k];
                    if (cum + c >= (u32)NSAMP) { cutbin = t2 - k; break; }
                    cum += c;
                }
                break;
            }
            cum += gs[g];
        }
        cutkey_s = (cutbin >= 0) ? (KBASE + ((u32)cutbin << 14)) : 0u;
    }
    __syncthreads();
    u32 cutkey = cutkey_s;
    // pass 2: filter >= cutkey into sort buffer
    for (int t = tid; t < CHUNKS*SLOTS; t += 256) {
        int c = t >> 8, s = t & (SLOTS-1);
        if ((u32)s < ccnt[c]) {
            u64 cv = cd[t];
            if ((u32)(cv >> 32) >= cutkey) {
                u32 p = atomicAdd(&nkeep, 1u);
                if (p < 2048u) buf[p] = cv;
            }
        }
    }
    __syncthreads();
    // bitonic ascending; pads (0) sink to the front; top-512 = buf[2047-r]
    for (int k = 2; k <= 2048; k <<= 1) {
        for (int j = k >> 1; j > 0; j >>= 1) {
            for (int i2 = tid; i2 < 2048; i2 += 256) {
                int ixj = i2 ^ j;
                if (ixj > i2) {
                    bool up = ((i2 & k) == 0);
                    u64 a = buf[i2], c2 = buf[ixj];
                    bool dosw = up ? (a > c2) : (a < c2);
                    if (dosw) { buf[i2] = c2; buf[ixj] = a; }
                }
            }
            __syncthreads();
        }
    }
    if (tid == 0) { inv3(K0 + (size_t)b*9, Ki[0]); inv3(K1 + (size_t)b*9, Ki[1]); }
    __syncthreads();
    for (int r = tid; r < NSAMP; r += 256) {
        u64 c = buf[2047 - r];
        u32 j = (~(u32)(c & 0xFFFFFFFFull)) & (u32)(ROWN - 1);
        int i0 = (int)(j >> 10);
        int i1 = (int)(j & 1023u);
        float uu0 = kps0[(size_t)b*2*NKP + i0];
        float vv0 = kps0[(size_t)b*2*NKP + NKP + i0];
        float dd0 = dep0[(size_t)b*2*NKP + i0];
        float uu1 = kps1[(size_t)b*2*NKP + i1];
        float vv1 = kps1[(size_t)b*2*NKP + NKP + i1];
        float dd1 = dep1[(size_t)b*2*NKP + i1];
        float r0 = Ki[0][0]*uu0 + Ki[0][1]*vv0 + Ki[0][2];
        float r1 = Ki[0][3]*uu0 + Ki[0][4]*vv0 + Ki[0][5];
        float r2 = Ki[0][6]*uu0 + Ki[0][7]*vv0 + Ki[0][8];
        float q0 = Ki[1][0]*uu1 + Ki[1][1]*vv1 + Ki[1][2];
        float q1 = Ki[1][3]*uu1 + Ki[1][4]*vv1 + Ki[1][5];
        float q2 = Ki[1][6]*uu1 + Ki[1][7]*vv1 + Ki[1][8];
        float w = mat[(size_t)b*ROWN + j];
        float* sp = samp + ((size_t)ib*NSAMP + r)*8;
        sp[0] = dd0*r0; sp[1] = dd0*r1; sp[2] = dd0*r2;
        sp[3] = dd1*q0; sp[4] = dd1*q1; sp[5] = dd1*q2;
        sp[6] = logf(w + 1e-12f);
        sp[7] = 0.f;
    }
}

// ---------------- Kernel E: one wave per RANSAC hypothesis ----------------
__global__ __launch_bounds__(64) void kE(const float* __restrict__ samp, const float* __restrict__ Tmat,
                                         Keys keys, float* __restrict__ scoreArr, float* __restrict__ lvArr)
{
    int blk = blockIdx.x;
    int kk = blk & 7;
    int ib = blk >> 3;
    int i = ib / NB;
    int b = ib % NB;
    int lane = threadIdx.x;
    const float* s = samp + (size_t)ib * NSAMP * 8;
    float X[8][3], Y[8][3], lw[8];
    #pragma unroll
    for (int q = 0; q < 8; ++q) {
        const float4* p = reinterpret_cast<const float4*>(s + (size_t)(q*64 + lane)*8);
        float4 a0 = p[0], a1 = p[1];
        X[q][0]=a0.x; X[q][1]=a0.y; X[q][2]=a0.z;
        Y[q][0]=a0.w; Y[q][1]=a1.x; Y[q][2]=a1.y;
        lw[q]=a1.z;
    }
    // inner gumbel + composite keys
    u64 comp[8];
    #pragma unroll
    for (int q = 0; q < 8; ++q) {
        u32 j = (u32)(q*64 + lane);
        u32 o0,o1; tf2x32(keys.kr[i][kk][0], keys.kr[i][kk][1], 0u, (u32)(b*NSAMP) + j, o0,o1);
        float u = u_from_bits(o0^o1);
        float g = -logf(-logf(u));
        float v = lw[q] + g;
        comp[q] = ((u64)fkey(v) << 32) | (u64)(u32)(~j);
    }
    // top-5 (value desc, index asc) via 5 wave arg-max rounds
    int ridx[5];
    #pragma unroll
    for (int r = 0; r < 5; ++r) {
        u64 m = comp[0];
        #pragma unroll
        for (int q=1;q<8;++q) if (comp[q] > m) m = comp[q];
        #pragma unroll
        for (int o=1;o<64;o<<=1) { u64 x = shfl_xor_u64(m,o); if (x > m) m = x; }
        ridx[r] = (int)((~(u32)(m & 0xFFFFFFFFull)) & (u32)(NSAMP-1));
        #pragma unroll
        for (int q=0;q<8;++q) if (comp[q] == m) comp[q] = 0ull;
    }
    // 5-point Procrustes (uniform weights) — all lanes compute identically
    float Xk[5][3], Yk[5][3];
    #pragma unroll
    for (int r=0;r<5;++r) {
        const float* p = s + (size_t)ridx[r]*8;
        Xk[r][0]=p[0]; Xk[r][1]=p[1]; Xk[r][2]=p[2];
        Yk[r][0]=p[3]; Yk[r][1]=p[4]; Yk[r][2]=p[5];
    }
    float S5 = 5.0f + 1e-8f;
    float wn5 = 1.0f / S5;
    float mx[3]={0,0,0}, my[3]={0,0,0};
    #pragma unroll
    for (int r=0;r<5;++r) {
        #pragma unroll
        for (int c=0;c<3;++c) { mx[c] += wn5*Xk[r][c]; my[c] += wn5*Yk[r][c]; }
    }
    float Hf[9] = {0,0,0,0,0,0,0,0,0};
    #pragma unroll
    for (int r=0;r<5;++r)
      #pragma unroll
      for (int ci=0;ci<3;++ci)
        #pragma unroll
        for (int cj=0;cj<3;++cj)
          Hf[ci*3+cj] += wn5*(Xk[r][ci]-mx[ci])*(Yk[r][cj]-my[cj]);
    float Rpre[9], tpre[3];
    kabsch(Hf, Rpre);
    #pragma unroll
    for (int c=0;c<3;++c) tpre[c] = my[c] - (Rpre[c*3+0]*mx[0] + Rpre[c*3+1]*mx[1] + Rpre[c*3+2]*mx[2]);
    // score over all 512 samples
    const float BETAF = (float)(5.0/0.15);
    float partial = 0.f;
    #pragma unroll
    for (int q=0;q<8;++q) {
        float d = dist1(Rpre, tpre, X[q], Y[q]);
        float z = BETAF * (0.15f - d);
        partial += 1.0f / (1.0f + expf(-z));
    }
    float score = wred(partial);
    // refinement (4 steps, exact do-gating)
    float inlref[8];
    #pragma unroll
    for (int q=0;q<8;++q) {
        int j = q*64 + lane;
        inlref[q] = (j==ridx[0] || j==ridx[1] || j==ridx[2] || j==ridx[3] || j==ridx[4]) ? 1.0f : 0.0f;
    }
    float Rd[9], td[3];
    #pragma unroll
    for (int c2=0;c2<9;++c2) Rd[c2]=Rpre[c2];
    td[0]=tpre[0]; td[1]=tpre[1]; td[2]=tpre[2];
    float inl_pre = 0.f;
    for (int step=0; step<4; ++step) {
        float inl[8]; float csum = 0.f;
        #pragma unroll
        for (int q=0;q<8;++q) {
            float d = dist1(Rd, td, X[q], Y[q]);
            inl[q] = (d < 0.15f) ? 1.0f : 0.0f;
            csum += inl[q];
        }
        float cnt = wred(csum);
        bool doit = (cnt >= 5.0f) && (cnt > inl_pre);
        inl_pre = cnt;
        if (doit) {
            #pragma unroll
            for (int q=0;q<8;++q) inlref[q] = inl[q];
            proc512(X, Y, inlref, Rd, td);
        }
    }
    // final Procrustes + pose loss
    float Rfin[9], tfin[3];
    proc512(X, Y, inlref, Rfin, tfin);
    const float* Tb = Tmat + (size_t)b*16;
    float tr = 0.f;
    #pragma unroll
    for (int ci=0;ci<3;++ci)
      #pragma unroll
      for (int cj=0;cj<3;++cj)
        tr += Rfin[ci*3+cj] * Tb[ci*4+cj];
    float cosang = (tr - 1.0f) * 0.5f;
    cosang = fminf(fmaxf(cosang, -0.999999f), 0.999999f);
    float ang = acosf(cosang);
    float d0 = tfin[0]-Tb[3], d1 = tfin[1]-Tb[7], d2 = tfin[2]-Tb[11];
    float terr = sqrtf(d0*d0 + d1*d1 + d2*d2);
    float lr = 0.5f * tanhf(ang / 0.5f);
    float lt = 0.5f * tanhf(terr / 0.5f);
    float lv = 0.5f * (lr + lt);
    if (lane == 0) { scoreArr[blk] = score; lvArr[blk] = lv; }
}

// ---------------- Kernel F: softmax mixing + output ----------------
__global__ void kF(const float* __restrict__ scoreArr, const float* __restrict__ lvArr, float* __restrict__ out)
{
    int b = threadIdx.x;
    if (b >= NB) return;
    const float NULLSC = (float)(0.35 * 512.0);
    float total = 0.f;
    for (int i = 0; i < ITM; ++i) {
        float x[9], lvv[9], ee[9];
        for (int k = 0; k < 8; ++k) {
            x[k] = scoreArr[(i*NB + b)*ITR + k] / 10.0f;
            lvv[k] = lvArr[(i*NB + b)*ITR + k];
        }
        x[8] = NULLSC / 10.0f;
        lvv[8] = 0.5f;
        float m = x[0];
        for (int k = 1; k < 9; ++k) m = fmaxf(m, x[k]);
        float Ssum = 0.f;
        for (int k = 0; k < 9; ++k) { ee[k] = expf(x[k] - m); Ssum += ee[k]; }
        float acc = 0.f;
        for (int k = 0; k < 9; ++k) acc += lvv[k] * (ee[k] / Ssum);
        total += acc;
    }
    out[b] = total / 4.0f;
}

// ---------------- host ----------------
extern "C" void kernel_launch(void* const* d_in, const int* in_sizes, int n_in,
                              void* d_out, int out_size, void* d_ws, size_t ws_size,
                              hipStream_t stream)
{
    (void)in_sizes; (void)n_in; (void)out_size; (void)ws_size;
    const float* mat  = (const float*)d_in[0];
    const float* kps0 = (const float*)d_in[1];
    const float* dep0 = (const float*)d_in[2];
    const float* kps1 = (const float*)d_in[3];
    const float* dep1 = (const float*)d_in[4];
    const float* K0   = (const float*)d_in[5];
    const float* K1   = (const float*)d_in[6];
    const float* Tm   = (const float*)d_in[8];
    float* out = (float*)d_out;

    // JAX key schedule: key(42) -> (0,42); split() in partitionable (fold-like) mode
    Keys keys;
    {
        u32 k0 = 0u, k1 = 42u;
        for (int i = 0; i < ITM; ++i) {
            u32 a0,a1,b0,b1;
            tf2x32(k0,k1, 0u,0u, a0,a1);
            tf2x32(k0,k1, 0u,1u, b0,b1);
            k0=a0; k1=a1; keys.km[i][0]=b0; keys.km[i][1]=b1;
            for (int kk = 0; kk < ITR; ++kk) {
                tf2x32(k0,k1, 0u,0u, a0,a1);
                tf2x32(k0,k1, 0u,1u, b0,b1);
                k0=a0; k1=a1; keys.kr[i][kk][0]=b0; keys.kr[i][kk][1]=b1;
            }
        }
    }
    char* ws = (char*)d_ws;
    u32* cnts       = (u32*)(ws + OFF_CNTS);
    float* scoreArr = (float*)(ws + OFF_SC);
    float* lvArr    = (float*)(ws + OFF_LV);
    float* samp     = (float*)(ws + OFF_SAMP);
    u64* candC      = (u64*)(ws + OFF_CAND);

    kA<<<dim3(CHUNKS, NB), 256, 0, stream>>>(mat, keys, candC, cnts);
    kD<<<ITM*NB, 256, 0, stream>>>(mat, kps0, dep0, kps1, dep1, K0, K1, candC, cnts, samp);
    kE<<<ITM*NB*ITR, 64, 0, stream>>>(samp, Tm, keys, scoreArr, lvArr);
    kF<<<1, 64, 0, stream>>>(scoreArr, lvArr, out);
}

// Round 7
// 394.483 us; speedup vs baseline: 5.9876x; 1.0074x over previous
//
#include <hip/hip_runtime.h>
#include <stdint.h>

typedef unsigned long long u64;
typedef uint32_t u32;

#define NB 32            // batch
#define NKP 1024         // keypoints per image
#define ROWN (NKP*NKP)   // matches row length
#define NSAMP 512        // NUM_SAMPLES
#define ITM 4            // IT_MATCHES
#define ITR 8            // IT_RANSAC
#define NBIN 2048        // fine histogram bins over key range [2.0, 32.0)
#define KBASE 0xC0000000u  // monotone key of +2.0f
#define CHUNKS 64        // blocks per row (blockIdx.x)
#define SLOTS 256        // per-(i,chunk) candidate capacity (mean ~151, +8.6 sigma)
#define WQ 352           // per-wave queue capacity per window (mean ~165, +14.7 sigma)

struct Keys { u32 km[ITM][2]; u32 kr[ITM][ITR][2]; };

// ---------------- threefry2x32 (JAX-compatible, 20 rounds) ----------------
__host__ __device__ static inline u32 rotl32(u32 x, int d) { return __builtin_rotateleft32(x, (unsigned)d); }

__host__ __device__ static inline void tf2x32(u32 k0, u32 k1, u32 x0, u32 x1, u32& o0, u32& o1)
{
    u32 ks2 = k0 ^ k1 ^ 0x1BD11BDAu;
    x0 += k0; x1 += k1;
#define TFR(r) { x0 += x1; x1 = rotl32(x1, r); x1 ^= x0; }
    TFR(13) TFR(15) TFR(26) TFR(6)
    x0 += k1; x1 += ks2 + 1u;
    TFR(17) TFR(29) TFR(16) TFR(24)
    x0 += ks2; x1 += k0 + 2u;
    TFR(13) TFR(15) TFR(26) TFR(6)
    x0 += k0; x1 += k1 + 3u;
    TFR(17) TFR(29) TFR(16) TFR(24)
    x0 += k1; x1 += ks2 + 4u;
    TFR(13) TFR(15) TFR(26) TFR(6)
    x0 += ks2; x1 += k0 + 5u;
#undef TFR
    o0 = x0; o1 = x1;
}

// 4 keyed threefry chains advanced round-major in lockstep (ILP=4); value-identical to tf2x32.
__device__ static inline void tf4(const Keys& K, u32 flat, u32 bits[ITM])
{
    u32 x0[ITM], x1[ITM];
    #pragma unroll
    for (int i = 0; i < ITM; ++i) {
        x0[i] = K.km[i][0];
        x1[i] = flat + K.km[i][1];
    }
#define R4(rot) { _Pragma("unroll") \
    for (int i = 0; i < ITM; ++i) { x0[i] += x1[i]; x1[i] = rotl32(x1[i], rot); x1[i] ^= x0[i]; } }
#define INJ(a_expr, b_expr) { _Pragma("unroll") \
    for (int i = 0; i < ITM; ++i) { u32 k0 = K.km[i][0], k1 = K.km[i][1]; \
        u32 ks2 = k0 ^ k1 ^ 0x1BD11BDAu; (void)k0; (void)k1; (void)ks2; \
        x0[i] += (a_expr); x1[i] += (b_expr); } }
    R4(13) R4(15) R4(26) R4(6)
    INJ(k1,      ks2 + 1u)
    R4(17) R4(29) R4(16) R4(24)
    INJ(ks2,     k0 + 2u)
    R4(13) R4(15) R4(26) R4(6)
    INJ(k0,      k1 + 3u)
    R4(17) R4(29) R4(16) R4(24)
    INJ(k1,      ks2 + 4u)
    R4(13) R4(15) R4(26) R4(6)
    INJ(ks2,     k0 + 5u)
#undef R4
#undef INJ
    #pragma unroll
    for (int i = 0; i < ITM; ++i) bits[i] = x0[i] ^ x1[i];
}

// uniform(key, shape, 1e-6, 1-1e-6) bit-faithful to JAX (partitionable mode)
#define G_MINV 1e-6f
#define G_MAXV ((float)(1.0 - 1e-6))
#define G_SPAN (G_MAXV - G_MINV)

__device__ static inline float u_from_bits(u32 bits) {
    float f = __uint_as_float((bits >> 9) | 0x3f800000u) - 1.0f;
    float u = __fadd_rn(__fmul_rn(f, G_SPAN), G_MINV);  // no FMA contraction (match XLA)
    return fmaxf(G_MINV, u);
}

// integer early-out: bits >= 8220000<<9  <=>  u > ~0.97990, strict superset of the
// u > 0.981851 needed for gumbel > 4 - log(max m). Exact float path decides.
#define EARLY_TH9 (8220000u << 9)   // 4208640000

// monotone float->uint key (order-preserving for all non-NaN)
__device__ static inline u32 fkey(float v) {
    u32 u = __float_as_uint(v);
    return (u & 0x80000000u) ? ~u : (u | 0x80000000u);
}

// 64-lane butterfly sum (uniform result on all lanes)
__device__ static inline float wred(float v) {
    #pragma unroll
    for (int o = 1; o < 64; o <<= 1) v += __shfl_xor(v, o, 64);
    return v;
}

__device__ static inline u64 shfl_xor_u64(u64 v, int mask) {
    u32 lo = (u32)v, hi = (u32)(v >> 32);
    lo = __shfl_xor(lo, mask, 64);
    hi = __shfl_xor(hi, mask, 64);
    return ((u64)hi << 32) | (u64)lo;
}

// ---------------- 3x3 Kabsch via double-precision Jacobi SVD (5 sweeps) ----------------
__device__ static void kabsch(const float Hf[9], float Rf[9])
{
    double H00=Hf[0],H01=Hf[1],H02=Hf[2];
    double H10=Hf[3],H11=Hf[4],H12=Hf[5];
    double H20=Hf[6],H21=Hf[7],H22=Hf[8];
    double A00 = H00*H00 + H10*H10 + H20*H20;
    double A01 = H00*H01 + H10*H11 + H20*H21;
    double A02 = H00*H02 + H10*H12 + H20*H22;
    double A11 = H01*H01 + H11*H11 + H21*H21;
    double A12 = H01*H02 + H11*H12 + H21*H22;
    double A22 = H02*H02 + H12*H12 + H22*H22;
    double V00=1,V10=0,V20=0;
    double V01=0,V11=1,V21=0;
    double V02=0,V12=0,V22=1;
#define JROT(App,Aqq,Apq,Apr,Aqr, Vp0,Vp1,Vp2, Vq0,Vq1,Vq2) \
    if (fabs(Apq) > 0.0) { \
        double th = (Aqq - App) / (2.0 * Apq); \
        double tt = copysign(1.0, th) / (fabs(th) + sqrt(1.0 + th*th)); \
        double cc = 1.0 / sqrt(1.0 + tt*tt); \
        double ss = tt * cc; \
        double npp = App - tt*Apq, nqq = Aqq + tt*Apq; \
        double npr = cc*Apr - ss*Aqr, nqr = ss*Apr + cc*Aqr; \
        App = npp; Aqq = nqq; Apq = 0.0; Apr = npr; Aqr = nqr; \
        double tv; \
        tv = cc*Vp0 - ss*Vq0; Vq0 = ss*Vp0 + cc*Vq0; Vp0 = tv; \
        tv = cc*Vp1 - ss*Vq1; Vq1 = ss*Vp1 + cc*Vq1; Vp1 = tv; \
        tv = cc*Vp2 - ss*Vq2; Vq2 = ss*Vp2 + cc*Vq2; Vp2 = tv; \
    }
    for (int sw = 0; sw < 5; ++sw) {
        JROT(A00,A11,A01, A02,A12, V00,V10,V20, V01,V11,V21);
        JROT(A00,A22,A02, A01,A12, V00,V10,V20, V02,V12,V22);
        JROT(A11,A22,A12, A01,A02, V01,V11,V21, V02,V12,V22);
    }
#undef JROT
    double l0=A00, l1=A11, l2=A22;
    double e0[3]={V00,V10,V20}, e1[3]={V01,V11,V21}, e2[3]={V02,V12,V22};
    if (l0 < l1) { double t=l0;l0=l1;l1=t; for(int c=0;c<3;++c){double s=e0[c];e0[c]=e1[c];e1[c]=s;} }
    if (l0 < l2) { double t=l0;l0=l2;l2=t; for(int c=0;c<3;++c){double s=e0[c];e0[c]=e2[c];e2[c]=s;} }
    if (l1 < l2) { double t=l1;l1=l2;l2=t; for(int c=0;c<3;++c){double s=e1[c];e1[c]=e2[c];e2[c]=s;} }
    double u0[3], u1[3], u2[3];
#define HMUL(e,u) { u[0]=H00*e[0]+H01*e[1]+H02*e[2]; u[1]=H10*e[0]+H11*e[1]+H12*e[2]; u[2]=H20*e[0]+H21*e[1]+H22*e[2]; }
    HMUL(e0,u0) HMUL(e1,u1) HMUL(e2,u2)
#undef HMUL
    double s0 = sqrt(u0[0]*u0[0]+u0[1]*u0[1]+u0[2]*u0[2]);
    double s1 = sqrt(u1[0]*u1[0]+u1[1]*u1[1]+u1[2]*u1[2]);
    double s2 = sqrt(u2[0]*u2[0]+u2[1]*u2[1]+u2[2]*u2[2]);
    double eps = 1e-12 + 1e-6 * s0;
    if (s0 > 0.0) { u0[0]/=s0; u0[1]/=s0; u0[2]/=s0; } else { u0[0]=1.0; u0[1]=0.0; u0[2]=0.0; }
    if (s1 > eps) { u1[0]/=s1; u1[1]/=s1; u1[2]/=s1; }
    else {
        double ax0 = (fabs(u0[0]) < 0.9) ? 1.0 : 0.0;
        double ax1 = 1.0 - ax0;
        double dd = ax0*u0[0] + ax1*u0[1];
        double w0 = ax0 - dd*u0[0], w1 = ax1 - dd*u0[1], w2 = -dd*u0[2];
        double nn = sqrt(w0*w0+w1*w1+w2*w2);
        u1[0]=w0/nn; u1[1]=w1/nn; u1[2]=w2/nn;
    }
    if (s2 > eps) { u2[0]/=s2; u2[1]/=s2; u2[2]/=s2; }
    else {
        u2[0] = u0[1]*u1[2] - u0[2]*u1[1];
        u2[1] = u0[2]*u1[0] - u0[0]*u1[2];
        u2[2] = u0[0]*u1[1] - u0[1]*u1[0];
    }
    double M[3][3];
    #pragma unroll
    for (int i2=0;i2<3;++i2)
      #pragma unroll
      for (int j2=0;j2<3;++j2)
        M[i2][j2] = e0[i2]*u0[j2] + e1[i2]*u1[j2] + e2[i2]*u2[j2];
    double det = M[0][0]*(M[1][1]*M[2][2]-M[1][2]*M[2][1])
               - M[0][1]*(M[1][0]*M[2][2]-M[1][2]*M[2][0])
               + M[0][2]*(M[1][0]*M[2][1]-M[1][1]*M[2][0]);
    #pragma unroll
    for (int i2=0;i2<3;++i2)
      #pragma unroll
      for (int j2=0;j2<3;++j2)
        Rf[i2*3+j2] = (float)(e0[i2]*u0[j2] + e1[i2]*u1[j2] + det*(e2[i2]*u2[j2]));
}

__device__ static inline float dist1(const float R[9], const float t[3], const float x[3], const float y[3])
{
    float a = R[0]*x[0]+R[1]*x[1]+R[2]*x[2]+t[0]-y[0];
    float b = R[3]*x[0]+R[4]*x[1]+R[5]*x[2]+t[1]-y[1];
    float c = R[6]*x[0]+R[7]*x[1]+R[8]*x[2]+t[2]-y[2];
    return sqrtf(a*a+b*b+c*c);
}

// weighted Procrustes over the wave's 512 samples (8 per lane); uniform result
__device__ static void proc512(const float (&X)[8][3], const float (&Y)[8][3], const float (&w)[8],
                               float R[9], float t[3])
{
    float sw = 0.f;
    #pragma unroll
    for (int q=0;q<8;++q) sw += w[q];
    float S = wred(sw) + 1e-8f;
    float wn[8];
    #pragma unroll
    for (int q=0;q<8;++q) wn[q] = w[q] / S;
    float mx[3], my[3];
    #pragma unroll
    for (int c=0;c<3;++c) {
        float ax=0.f, ay=0.f;
        #pragma unroll
        for (int q=0;q<8;++q) { ax += wn[q]*X[q][c]; ay += wn[q]*Y[q][c]; }
        mx[c] = wred(ax); my[c] = wred(ay);
    }
    float Hf[9];
    #pragma unroll
    for (int ci=0;ci<3;++ci)
      #pragma unroll
      for (int cj=0;cj<3;++cj) {
        float h=0.f;
        #pragma unroll
        for (int q=0;q<8;++q) h += wn[q]*(X[q][ci]-mx[ci])*(Y[q][cj]-my[cj]);
        Hf[ci*3+cj] = wred(h);
      }
    kabsch(Hf, R);
    #pragma unroll
    for (int c=0;c<3;++c) t[c] = my[c] - (R[c*3+0]*mx[0] + R[c*3+1]*mx[1] + R[c*3+2]*mx[2]);
}

// 3x3 inverse, pivoted Gauss-Jordan (mirrors jnp.linalg.inv up to ulps)
__device__ static void inv3(const float* __restrict__ Kin, float* __restrict__ out)
{
    float a[3][6];
    for (int r=0;r<3;++r) for (int c=0;c<3;++c) { a[r][c]=Kin[r*3+c]; a[r][c+3] = (r==c)?1.f:0.f; }
    for (int col=0; col<3; ++col) {
        int piv = col;
        for (int r=col+1;r<3;++r) if (fabsf(a[r][col]) > fabsf(a[piv][col])) piv = r;
        if (piv != col) for (int c=0;c<6;++c) { float tt=a[col][c]; a[col][c]=a[piv][c]; a[piv][c]=tt; }
        float pv = a[col][col];
        for (int c=0;c<6;++c) a[col][c] /= pv;
        for (int r=0;r<3;++r) if (r != col) {
            float f = a[r][col];
            if (f != 0.f) for (int c=0;c<6;++c) a[r][c] -= f * a[col][c];
        }
    }
    for (int r=0;r<3;++r) for (int c=0;c<3;++c) out[r*3+c] = a[r][c+3];
}

// ---------------- workspace layout ----------------
static const size_t OFF_CNTS = 0;                                           // u32[ITM*NB*CHUNKS]
static const size_t OFF_SC   = OFF_CNTS + (size_t)ITM*NB*CHUNKS*4;          // f32[ITM*NB*ITR]
static const size_t OFF_LV   = OFF_SC   + (size_t)ITM*NB*ITR*4;             // f32[ITM*NB*ITR]
static const size_t OFF_SAMP = OFF_LV   + (size_t)ITM*NB*ITR*4;             // f32[ITM*NB*NSAMP*8]
static const size_t OFF_CAND = OFF_SAMP + (size_t)ITM*NB*NSAMP*8*4;         // u64[ITM*NB*CHUNKS*SLOTS]

// ---------------- Kernel A: ILP-4 threefry + atomic-free per-wave queues ----------------
// Hot loop has ZERO memory ops with return values: queue position comes from
// ballot+mbcnt (VALU/SALU only), ds_write is fire-and-forget.
__global__ __launch_bounds__(256) void kA(const float* __restrict__ mat, Keys keys,
                                          u64* __restrict__ candC, u32* __restrict__ cnts)
{
    __shared__ u64 lists[ITM][SLOTS];   // 8 KB
    __shared__ u32 lcnt[ITM];
    __shared__ u64 q[4][WQ];            // 11 KB
    __shared__ u32 wcnt[4];
    int tid = threadIdx.x;
    int lane = tid & 63;
    int wid = tid >> 6;
    u64 lmask_lt = (1ull << lane) - 1ull;
    if (tid < ITM) lcnt[tid] = 0;
    __syncthreads();
    int b = blockIdx.y;
    int chunk = blockIdx.x;
    const float* rowb = mat + (size_t)b * ROWN;
    u32 jbase = (u32)chunk * 16384u + (u32)tid;
    for (int seg = 0; seg < 2; ++seg) {
        u32 cnt = 0;   // wave-uniform (SGPR): running count of this wave's queue
        for (int lp = 0; lp < 32; ++lp) {
            u32 j = jbase + (u32)((seg*32 + lp) << 8);
            u32 flat = ((u32)b << 20) | j;
            u32 bits[ITM];
            tf4(keys, flat, bits);
            #pragma unroll
            for (int i = 0; i < ITM; ++i) {
                bool hit = (bits[i] >= EARLY_TH9);     // ~2% of lanes
                u64 mask = __ballot(hit);
                if (hit) {
                    u32 pos = cnt + (u32)__popcll(mask & lmask_lt);
                    if (pos < (u32)WQ)
                        q[wid][pos] = ((u64)bits[i] << 32) | ((u64)(u32)i << 20) | (u64)j;
                }
                cnt += (u32)__popcll(mask);
            }
        }
        __syncthreads();                       // all wave queues written
        if (lane == 0) wcnt[wid] = (cnt > (u32)WQ) ? (u32)WQ : cnt;
        __syncthreads();
        // dense drain of the 4 wave queues (all 256 threads on each)
        for (int w = 0; w < 4; ++w) {
            u32 qn = wcnt[w];
            for (u32 t = tid; t < qn; t += 256) {
                u64 e  = q[w][t];
                u32 bits = (u32)(e >> 32);
                u32 i2 = ((u32)e >> 20) & 3u;
                u32 jj = (u32)e & 0xFFFFFu;
                float m  = rowb[jj];               // demand fetch (L2/L3), latency-hidden
                float u  = u_from_bits(bits);
                float g  = -logf(-logf(u));
                float v  = logf(m + 1e-12f) + g;
                if (v > 4.0f) {
                    u32 p = atomicAdd(&lcnt[i2], 1u);
                    if (p < (u32)SLOTS)
                        lists[i2][p] = ((u64)fkey(v) << 32) | (u64)(u32)(~jj);
                }
            }
        }
        __syncthreads();                       // drain reads done before next seg overwrites q
    }
    #pragma unroll
    for (int i = 0; i < ITM; ++i) {
        u32 n = lcnt[i]; if (n > (u32)SLOTS) n = SLOTS;
        for (u32 s = tid; s < n; s += 256)
            candC[(((size_t)(i*NB + b))*CHUNKS + chunk)*SLOTS + s] = lists[i][s];
    }
    if (tid < ITM) cnts[((size_t)(tid*NB + b))*CHUNKS + chunk] = min(lcnt[tid], (u32)SLOTS);
}

// ---------------- Kernel D: hist+cut+select+sort+backproject, one block per (iter,b) ----------------
__global__ __launch_bounds__(256) void kD(const float* __restrict__ mat,
        const float* __restrict__ kps0, const float* __restrict__ dep0,
        const float* __restrict__ kps1, const float* __restrict__ dep1,
        const float* __restrict__ K0, const float* __restrict__ K1,
        const u64* __restrict__ candC, const u32* __restrict__ cnts,
        float* __restrict__ samp)
{
    int ib = blockIdx.x;
    int b = ib % NB;
    int tid = threadIdx.x;
    __shared__ u32 hist[NBIN];     // 8 KB
    __shared__ u64 buf[2048];      // 16 KB
    __shared__ u32 ccnt[CHUNKS];
    __shared__ u32 gs[64];
    __shared__ u32 nkeep, cutkey_s;
    __shared__ float Ki[2][9];
    for (int idx = tid; idx < NBIN; idx += 256) hist[idx] = 0;
    for (int idx = tid; idx < 2048; idx += 256) buf[idx] = 0ull;
    if (tid < CHUNKS) ccnt[tid] = cnts[(size_t)ib*CHUNKS + tid];
    if (tid == 0) nkeep = 0;
    __syncthreads();
    const u64* cd = candC + (size_t)ib * CHUNKS * SLOTS;
    // pass 1: histogram of candidate keys
    for (int t = tid; t < CHUNKS*SLOTS; t += 256) {
        int c = t >> 8, s = t & (SLOTS-1);
        if ((u32)s < ccnt[c]) {
            u32 key = (u32)(cd[t] >> 32);
            u32 bin = (key - KBASE) >> 14;
            if (bin > (u32)(NBIN-1)) bin = NBIN-1;
            atomicAdd(&hist[bin], 1u);
        }
    }
    __syncthreads();
    // exact rank-512 cut bin
    if (tid < 64) {
        u32 ssum = 0;
        int top = NBIN-1 - tid*32;
        for (int k = 0; k < 32; ++k) ssum += hist[top - k];
        gs[tid] = ssum;
    }
    __syncthreads();
    if (tid == 0) {
        u32 cum = 0; int cutbin = -1;
        for (int g = 0; g < 64; ++g) {
            if (cum + gs[g] >= (u32)NSAMP) {
                int t2 = NBIN-1 - g*32;
                for (int k = 0; k < 32; ++k) {
                    u32 c = hist[t2 - k];
                    if (cum + c >= (u32)NSAMP) { cutbin = t2 - k; break; }
                    cum += c;
                }
                break;
            }
            cum += gs[g];
        }
        cutkey_s = (cutbin >= 0) ? (KBASE + ((u32)cutbin << 14)) : 0u;
    }
    __syncthreads();
    u32 cutkey = cutkey_s;
    // pass 2: filter >= cutkey into sort buffer
    for (int t = tid; t < CHUNKS*SLOTS; t += 256) {
        int c = t >> 8, s = t & (SLOTS-1);
        if ((u32)s < ccnt[c]) {
            u64 cv = cd[t];
            if ((u32)(cv >> 32) >= cutkey) {
                u32 p = atomicAdd(&nkeep, 1u);
                if (p < 2048u) buf[p] = cv;
            }
        }
    }
    __syncthreads();
    // bitonic ascending; pads (0) sink to the front; top-512 = buf[2047-r]
    for (int k = 2; k <= 2048; k <<= 1) {
        for (int j = k >> 1; j > 0; j >>= 1) {
            for (int i2 = tid; i2 < 2048; i2 += 256) {
                int ixj = i2 ^ j;
                if (ixj > i2) {
                    bool up = ((i2 & k) == 0);
                    u64 a = buf[i2], c2 = buf[ixj];
                    bool dosw = up ? (a > c2) : (a < c2);
                    if (dosw) { buf[i2] = c2; buf[ixj] = a; }
                }
            }
            __syncthreads();
        }
    }
    if (tid == 0) { inv3(K0 + (size_t)b*9, Ki[0]); inv3(K1 + (size_t)b*9, Ki[1]); }
    __syncthreads();
    for (int r = tid; r < NSAMP; r += 256) {
        u64 c = buf[2047 - r];
        u32 j = (~(u32)(c & 0xFFFFFFFFull)) & (u32)(ROWN - 1);
        int i0 = (int)(j >> 10);
        int i1 = (int)(j & 1023u);
        float uu0 = kps0[(size_t)b*2*NKP + i0];
        float vv0 = kps0[(size_t)b*2*NKP + NKP + i0];
        float dd0 = dep0[(size_t)b*2*NKP + i0];
        float uu1 = kps1[(size_t)b*2*NKP + i1];
        float vv1 = kps1[(size_t)b*2*NKP + NKP + i1];
        float dd1 = dep1[(size_t)b*2*NKP + i1];
        float r0 = Ki[0][0]*uu0 + Ki[0][1]*vv0 + Ki[0][2];
        float r1 = Ki[0][3]*uu0 + Ki[0][4]*vv0 + Ki[0][5];
        float r2 = Ki[0][6]*uu0 + Ki[0][7]*vv0 + Ki[0][8];
        float q0 = Ki[1][0]*uu1 + Ki[1][1]*vv1 + Ki[1][2];
        float q1 = Ki[1][3]*uu1 + Ki[1][4]*vv1 + Ki[1][5];
        float q2 = Ki[1][6]*uu1 + Ki[1][7]*vv1 + Ki[1][8];
        float w = mat[(size_t)b*ROWN + j];
        float* sp = samp + ((size_t)ib*NSAMP + r)*8;
        sp[0] = dd0*r0; sp[1] = dd0*r1; sp[2] = dd0*r2;
        sp[3] = dd1*q0; sp[4] = dd1*q1; sp[5] = dd1*q2;
        sp[6] = logf(w + 1e-12f);
        sp[7] = 0.f;
    }
}

// ---------------- Kernel E: one wave per RANSAC hypothesis ----------------
__global__ __launch_bounds__(64) void kE(const float* __restrict__ samp, const float* __restrict__ Tmat,
                                         Keys keys, float* __restrict__ scoreArr, float* __restrict__ lvArr)
{
    int blk = blockIdx.x;
    int kk = blk & 7;
    int ib = blk >> 3;
    int i = ib / NB;
    int b = ib % NB;
    int lane = threadIdx.x;
    const float* s = samp + (size_t)ib * NSAMP * 8;
    float X[8][3], Y[8][3], lw[8];
    #pragma unroll
    for (int q = 0; q < 8; ++q) {
        const float4* p = reinterpret_cast<const float4*>(s + (size_t)(q*64 + lane)*8);
        float4 a0 = p[0], a1 = p[1];
        X[q][0]=a0.x; X[q][1]=a0.y; X[q][2]=a0.z;
        Y[q][0]=a0.w; Y[q][1]=a1.x; Y[q][2]=a1.y;
        lw[q]=a1.z;
    }
    // inner gumbel + composite keys
    u64 comp[8];
    #pragma unroll
    for (int q = 0; q < 8; ++q) {
        u32 j = (u32)(q*64 + lane);
        u32 o0,o1; tf2x32(keys.kr[i][kk][0], keys.kr[i][kk][1], 0u, (u32)(b*NSAMP) + j, o0,o1);
        float u = u_from_bits(o0^o1);
        float g = -logf(-logf(u));
        float v = lw[q] + g;
        comp[q] = ((u64)fkey(v) << 32) | (u64)(u32)(~j);
    }
    // top-5 (value desc, index asc) via 5 wave arg-max rounds
    int ridx[5];
    #pragma unroll
    for (int r = 0; r < 5; ++r) {
        u64 m = comp[0];
        #pragma unroll
        for (int q=1;q<8;++q) if (comp[q] > m) m = comp[q];
        #pragma unroll
        for (int o=1;o<64;o<<=1) { u64 x = shfl_xor_u64(m,o); if (x > m) m = x; }
        ridx[r] = (int)((~(u32)(m & 0xFFFFFFFFull)) & (u32)(NSAMP-1));
        #pragma unroll
        for (int q=0;q<8;++q) if (comp[q] == m) comp[q] = 0ull;
    }
    // 5-point Procrustes (uniform weights) — all lanes compute identically
    float Xk[5][3], Yk[5][3];
    #pragma unroll
    for (int r=0;r<5;++r) {
        const float* p = s + (size_t)ridx[r]*8;
        Xk[r][0]=p[0]; Xk[r][1]=p[1]; Xk[r][2]=p[2];
        Yk[r][0]=p[3]; Yk[r][1]=p[4]; Yk[r][2]=p[5];
    }
    float S5 = 5.0f + 1e-8f;
    float wn5 = 1.0f / S5;
    float mx[3]={0,0,0}, my[3]={0,0,0};
    #pragma unroll
    for (int r=0;r<5;++r) {
        #pragma unroll
        for (int c=0;c<3;++c) { mx[c] += wn5*Xk[r][c]; my[c] += wn5*Yk[r][c]; }
    }
    float Hf[9] = {0,0,0,0,0,0,0,0,0};
    #pragma unroll
    for (int r=0;r<5;++r)
      #pragma unroll
      for (int ci=0;ci<3;++ci)
        #pragma unroll
        for (int cj=0;cj<3;++cj)
          Hf[ci*3+cj] += wn5*(Xk[r][ci]-mx[ci])*(Yk[r][cj]-my[cj]);
    float Rpre[9], tpre[3];
    kabsch(Hf, Rpre);
    #pragma unroll
    for (int c=0;c<3;++c) tpre[c] = my[c] - (Rpre[c*3+0]*mx[0] + Rpre[c*3+1]*mx[1] + Rpre[c*3+2]*mx[2]);
    // score over all 512 samples
    const float BETAF = (float)(5.0/0.15);
    float partial = 0.f;
    #pragma unroll
    for (int q=0;q<8;++q) {
        float d = dist1(Rpre, tpre, X[q], Y[q]);
        float z = BETAF * (0.15f - d);
        partial += 1.0f / (1.0f + expf(-z));
    }
    float score = wred(partial);
    // refinement (4 steps, exact do-gating)
    float inlref[8];
    #pragma unroll
    for (int q=0;q<8;++q) {
        int j = q*64 + lane;
        inlref[q] = (j==ridx[0] || j==ridx[1] || j==ridx[2] || j==ridx[3] || j==ridx[4]) ? 1.0f : 0.0f;
    }
    float Rd[9], td[3];
    #pragma unroll
    for (int c2=0;c2<9;++c2) Rd[c2]=Rpre[c2];
    td[0]=tpre[0]; td[1]=tpre[1]; td[2]=tpre[2];
    float inl_pre = 0.f;
    for (int step=0; step<4; ++step) {
        float inl[8]; float csum = 0.f;
        #pragma unroll
        for (int q=0;q<8;++q) {
            float d = dist1(Rd, td, X[q], Y[q]);
            inl[q] = (d < 0.15f) ? 1.0f : 0.0f;
            csum += inl[q];
        }
        float cnt = wred(csum);
        bool doit = (cnt >= 5.0f) && (cnt > inl_pre);
        inl_pre = cnt;
        if (doit) {
            #pragma unroll
            for (int q=0;q<8;++q) inlref[q] = inl[q];
            proc512(X, Y, inlref, Rd, td);
        }
    }
    // final Procrustes + pose loss
    float Rfin[9], tfin[3];
    proc512(X, Y, inlref, Rfin, tfin);
    const float* Tb = Tmat + (size_t)b*16;
    float tr = 0.f;
    #pragma unroll
    for (int ci=0;ci<3;++ci)
      #pragma unroll
      for (int cj=0;cj<3;++cj)
        tr += Rfin[ci*3+cj] * Tb[ci*4+cj];
    float cosang = (tr - 1.0f) * 0.5f;
    cosang = fminf(fmaxf(cosang, -0.999999f), 0.999999f);
    float ang = acosf(cosang);
    float d0 = tfin[0]-Tb[3], d1 = tfin[1]-Tb[7], d2 = tfin[2]-Tb[11];
    float terr = sqrtf(d0*d0 + d1*d1 + d2*d2);
    float lr = 0.5f * tanhf(ang / 0.5f);
    float lt = 0.5f * tanhf(terr / 0.5f);
    float lv = 0.5f * (lr + lt);
    if (lane == 0) { scoreArr[blk] = score; lvArr[blk] = lv; }
}

// ---------------- Kernel F: softmax mixing + output ----------------
__global__ void kF(const float* __restrict__ scoreArr, const float* __restrict__ lvArr, float* __restrict__ out)
{
    int b = threadIdx.x;
    if (b >= NB) return;
    const float NULLSC = (float)(0.35 * 512.0);
    float total = 0.f;
    for (int i = 0; i < ITM; ++i) {
        float x[9], lvv[9], ee[9];
        for (int k = 0; k < 8; ++k) {
            x[k] = scoreArr[(i*NB + b)*ITR + k] / 10.0f;
            lvv[k] = lvArr[(i*NB + b)*ITR + k];
        }
        x[8] = NULLSC / 10.0f;
        lvv[8] = 0.5f;
        float m = x[0];
        for (int k = 1; k < 9; ++k) m = fmaxf(m, x[k]);
        float Ssum = 0.f;
        for (int k = 0; k < 9; ++k) { ee[k] = expf(x[k] - m); Ssum += ee[k]; }
        float acc = 0.f;
        for (int k = 0; k < 9; ++k) acc += lvv[k] * (ee[k] / Ssum);
        total += acc;
    }
    out[b] = total / 4.0f;
}

// ---------------- host ----------------
extern "C" void kernel_launch(void* const* d_in, const int* in_sizes, int n_in,
                              void* d_out, int out_size, void* d_ws, size_t ws_size,
                              hipStream_t stream)
{
    (void)in_sizes; (void)n_in; (void)out_size; (void)ws_size;
    const float* mat  = (const float*)d_in[0];
    const float* kps0 = (const float*)d_in[1];
    const float* dep0 = (const float*)d_in[2];
    const float* kps1 = (const float*)d_in[3];
    const float* dep1 = (const float*)d_in[4];
    const float* K0   = (const float*)d_in[5];
    const float* K1   = (const float*)d_in[6];
    const float* Tm   = (const float*)d_in[8];
    float* out = (float*)d_out;

    // JAX key schedule: key(42) -> (0,42); split() in partitionable (fold-like) mode
    Keys keys;
    {
        u32 k0 = 0u, k1 = 42u;
        for (int i = 0; i < ITM; ++i) {
            u32 a0,a1,b0,b1;
            tf2x32(k0,k1, 0u,0u, a0,a1);
            tf2x32(k0,k1, 0u,1u, b0,b1);
            k0=a0; k1=a1; keys.km[i][0]=b0; keys.km[i][1]=b1;
            for (int kk = 0; kk < ITR; ++kk) {
                tf2x32(k0,k1, 0u,0u, a0,a1);
                tf2x32(k0,k1, 0u,1u, b0,b1);
                k0=a0; k1=a1; keys.kr[i][kk][0]=b0; keys.kr[i][kk][1]=b1;
            }
        }
    }
    char* ws = (char*)d_ws;
    u32* cnts       = (u32*)(ws + OFF_CNTS);
    float* scoreArr = (float*)(ws + OFF_SC);
    float* lvArr    = (float*)(ws + OFF_LV);
    float* samp     = (float*)(ws + OFF_SAMP);
    u64* candC      = (u64*)(ws + OFF_CAND);

    kA<<<dim3(CHUNKS, NB), 256, 0, stream>>>(mat, keys, candC, cnts);
    kD<<<ITM*NB, 256, 0, stream>>>(mat, kps0, dep0, kps1, dep1, K0, K1, candC, cnts, samp);
    kE<<<ITM*NB*ITR, 64, 0, stream>>>(samp, Tm, keys, scoreArr, lvArr);
    kF<<<1, 64, 0, stream>>>(scoreArr, lvArr, out);
}

// Round 8
// 337.228 us; speedup vs baseline: 7.0042x; 1.1698x over previous
//
#include <hip/hip_runtime.h>
#include <stdint.h>

typedef unsigned long long u64;
typedef uint32_t u32;

#define NB 32            // batch
#define NKP 1024         // keypoints per image
#define ROWN (NKP*NKP)   // matches row length
#define NSAMP 512        // NUM_SAMPLES
#define ITM 4            // IT_MATCHES
#define ITR 8            // IT_RANSAC
#define NBIN 2048        // fine histogram bins over key range [2.0, 32.0)
#define KBASE 0xC0000000u  // monotone key of +2.0f
#define CHUNKS 64        // blocks per row (blockIdx.x)
#define SLOTS 256        // per-(i,chunk) candidate capacity (mean ~151, +8.6 sigma)
#define WQ 352           // per-wave queue capacity per window (mean ~165, +14.7 sigma)

struct Keys { u32 km[ITM][2]; u32 kr[ITM][ITR][2]; };

// ---------------- threefry2x32 (JAX-compatible, 20 rounds) ----------------
__host__ __device__ static inline u32 rotl32(u32 x, int d) { return __builtin_rotateleft32(x, (unsigned)d); }

__host__ __device__ static inline void tf2x32(u32 k0, u32 k1, u32 x0, u32 x1, u32& o0, u32& o1)
{
    u32 ks2 = k0 ^ k1 ^ 0x1BD11BDAu;
    x0 += k0; x1 += k1;
#define TFR(r) { x0 += x1; x1 = rotl32(x1, r); x1 ^= x0; }
    TFR(13) TFR(15) TFR(26) TFR(6)
    x0 += k1; x1 += ks2 + 1u;
    TFR(17) TFR(29) TFR(16) TFR(24)
    x0 += ks2; x1 += k0 + 2u;
    TFR(13) TFR(15) TFR(26) TFR(6)
    x0 += k0; x1 += k1 + 3u;
    TFR(17) TFR(29) TFR(16) TFR(24)
    x0 += k1; x1 += ks2 + 4u;
    TFR(13) TFR(15) TFR(26) TFR(6)
    x0 += ks2; x1 += k0 + 5u;
#undef TFR
    o0 = x0; o1 = x1;
}

// 4 keyed threefry chains advanced round-major in lockstep (ILP=4); value-identical to tf2x32.
__device__ static inline void tf4(const Keys& K, u32 flat, u32 bits[ITM])
{
    u32 x0[ITM], x1[ITM];
    #pragma unroll
    for (int i = 0; i < ITM; ++i) {
        x0[i] = K.km[i][0];
        x1[i] = flat + K.km[i][1];
    }
#define R4(rot) { _Pragma("unroll") \
    for (int i = 0; i < ITM; ++i) { x0[i] += x1[i]; x1[i] = rotl32(x1[i], rot); x1[i] ^= x0[i]; } }
#define INJ(a_expr, b_expr) { _Pragma("unroll") \
    for (int i = 0; i < ITM; ++i) { u32 k0 = K.km[i][0], k1 = K.km[i][1]; \
        u32 ks2 = k0 ^ k1 ^ 0x1BD11BDAu; (void)k0; (void)k1; (void)ks2; \
        x0[i] += (a_expr); x1[i] += (b_expr); } }
    R4(13) R4(15) R4(26) R4(6)
    INJ(k1,      ks2 + 1u)
    R4(17) R4(29) R4(16) R4(24)
    INJ(ks2,     k0 + 2u)
    R4(13) R4(15) R4(26) R4(6)
    INJ(k0,      k1 + 3u)
    R4(17) R4(29) R4(16) R4(24)
    INJ(k1,      ks2 + 4u)
    R4(13) R4(15) R4(26) R4(6)
    INJ(ks2,     k0 + 5u)
#undef R4
#undef INJ
    #pragma unroll
    for (int i = 0; i < ITM; ++i) bits[i] = x0[i] ^ x1[i];
}

// uniform(key, shape, 1e-6, 1-1e-6) bit-faithful to JAX (partitionable mode)
#define G_MINV 1e-6f
#define G_MAXV ((float)(1.0 - 1e-6))
#define G_SPAN (G_MAXV - G_MINV)

__device__ static inline float u_from_bits(u32 bits) {
    float f = __uint_as_float((bits >> 9) | 0x3f800000u) - 1.0f;
    float u = __fadd_rn(__fmul_rn(f, G_SPAN), G_MINV);  // no FMA contraction (match XLA)
    return fmaxf(G_MINV, u);
}

// integer early-out: bits >= 8220000<<9  <=>  u > ~0.97990, strict superset of the
// u > 0.981851 needed for gumbel > 4 - log(max m). Exact float path decides.
#define EARLY_TH9 (8220000u << 9)   // 4208640000

// monotone float->uint key (order-preserving for all non-NaN)
__device__ static inline u32 fkey(float v) {
    u32 u = __float_as_uint(v);
    return (u & 0x80000000u) ? ~u : (u | 0x80000000u);
}

// 64-lane butterfly sum (uniform result on all lanes)
__device__ static inline float wred(float v) {
    #pragma unroll
    for (int o = 1; o < 64; o <<= 1) v += __shfl_xor(v, o, 64);
    return v;
}

__device__ static inline u64 shfl_xor_u64(u64 v, int mask) {
    u32 lo = (u32)v, hi = (u32)(v >> 32);
    lo = __shfl_xor(lo, mask, 64);
    hi = __shfl_xor(hi, mask, 64);
    return ((u64)hi << 32) | (u64)lo;
}

// ---------------- 3x3 Kabsch via double-precision Jacobi SVD (5 sweeps) ----------------
__device__ static void kabsch(const float Hf[9], float Rf[9])
{
    double H00=Hf[0],H01=Hf[1],H02=Hf[2];
    double H10=Hf[3],H11=Hf[4],H12=Hf[5];
    double H20=Hf[6],H21=Hf[7],H22=Hf[8];
    double A00 = H00*H00 + H10*H10 + H20*H20;
    double A01 = H00*H01 + H10*H11 + H20*H21;
    double A02 = H00*H02 + H10*H12 + H20*H22;
    double A11 = H01*H01 + H11*H11 + H21*H21;
    double A12 = H01*H02 + H11*H12 + H21*H22;
    double A22 = H02*H02 + H12*H12 + H22*H22;
    double V00=1,V10=0,V20=0;
    double V01=0,V11=1,V21=0;
    double V02=0,V12=0,V22=1;
#define JROT(App,Aqq,Apq,Apr,Aqr, Vp0,Vp1,Vp2, Vq0,Vq1,Vq2) \
    if (fabs(Apq) > 0.0) { \
        double th = (Aqq - App) / (2.0 * Apq); \
        double tt = copysign(1.0, th) / (fabs(th) + sqrt(1.0 + th*th)); \
        double cc = 1.0 / sqrt(1.0 + tt*tt); \
        double ss = tt * cc; \
        double npp = App - tt*Apq, nqq = Aqq + tt*Apq; \
        double npr = cc*Apr - ss*Aqr, nqr = ss*Apr + cc*Aqr; \
        App = npp; Aqq = nqq; Apq = 0.0; Apr = npr; Aqr = nqr; \
        double tv; \
        tv = cc*Vp0 - ss*Vq0; Vq0 = ss*Vp0 + cc*Vq0; Vp0 = tv; \
        tv = cc*Vp1 - ss*Vq1; Vq1 = ss*Vp1 + cc*Vq1; Vp1 = tv; \
        tv = cc*Vp2 - ss*Vq2; Vq2 = ss*Vp2 + cc*Vq2; Vp2 = tv; \
    }
    for (int sw = 0; sw < 5; ++sw) {
        JROT(A00,A11,A01, A02,A12, V00,V10,V20, V01,V11,V21);
        JROT(A00,A22,A02, A01,A12, V00,V10,V20, V02,V12,V22);
        JROT(A11,A22,A12, A01,A02, V01,V11,V21, V02,V12,V22);
    }
#undef JROT
    double l0=A00, l1=A11, l2=A22;
    double e0[3]={V00,V10,V20}, e1[3]={V01,V11,V21}, e2[3]={V02,V12,V22};
    if (l0 < l1) { double t=l0;l0=l1;l1=t; for(int c=0;c<3;++c){double s=e0[c];e0[c]=e1[c];e1[c]=s;} }
    if (l0 < l2) { double t=l0;l0=l2;l2=t; for(int c=0;c<3;++c){double s=e0[c];e0[c]=e2[c];e2[c]=s;} }
    if (l1 < l2) { double t=l1;l1=l2;l2=t; for(int c=0;c<3;++c){double s=e1[c];e1[c]=e2[c];e2[c]=s;} }
    double u0[3], u1[3], u2[3];
#define HMUL(e,u) { u[0]=H00*e[0]+H01*e[1]+H02*e[2]; u[1]=H10*e[0]+H11*e[1]+H12*e[2]; u[2]=H20*e[0]+H21*e[1]+H22*e[2]; }
    HMUL(e0,u0) HMUL(e1,u1) HMUL(e2,u2)
#undef HMUL
    double s0 = sqrt(u0[0]*u0[0]+u0[1]*u0[1]+u0[2]*u0[2]);
    double s1 = sqrt(u1[0]*u1[0]+u1[1]*u1[1]+u1[2]*u1[2]);
    double s2 = sqrt(u2[0]*u2[0]+u2[1]*u2[1]+u2[2]*u2[2]);
    double eps = 1e-12 + 1e-6 * s0;
    if (s0 > 0.0) { u0[0]/=s0; u0[1]/=s0; u0[2]/=s0; } else { u0[0]=1.0; u0[1]=0.0; u0[2]=0.0; }
    if (s1 > eps) { u1[0]/=s1; u1[1]/=s1; u1[2]/=s1; }
    else {
        double ax0 = (fabs(u0[0]) < 0.9) ? 1.0 : 0.0;
        double ax1 = 1.0 - ax0;
        double dd = ax0*u0[0] + ax1*u0[1];
        double w0 = ax0 - dd*u0[0], w1 = ax1 - dd*u0[1], w2 = -dd*u0[2];
        double nn = sqrt(w0*w0+w1*w1+w2*w2);
        u1[0]=w0/nn; u1[1]=w1/nn; u1[2]=w2/nn;
    }
    if (s2 > eps) { u2[0]/=s2; u2[1]/=s2; u2[2]/=s2; }
    else {
        u2[0] = u0[1]*u1[2] - u0[2]*u1[1];
        u2[1] = u0[2]*u1[0] - u0[0]*u1[2];
        u2[2] = u0[0]*u1[1] - u0[1]*u1[0];
    }
    double M[3][3];
    #pragma unroll
    for (int i2=0;i2<3;++i2)
      #pragma unroll
      for (int j2=0;j2<3;++j2)
        M[i2][j2] = e0[i2]*u0[j2] + e1[i2]*u1[j2] + e2[i2]*u2[j2];
    double det = M[0][0]*(M[1][1]*M[2][2]-M[1][2]*M[2][1])
               - M[0][1]*(M[1][0]*M[2][2]-M[1][2]*M[2][0])
               + M[0][2]*(M[1][0]*M[2][1]-M[1][1]*M[2][0]);
    #pragma unroll
    for (int i2=0;i2<3;++i2)
      #pragma unroll
      for (int j2=0;j2<3;++j2)
        Rf[i2*3+j2] = (float)(e0[i2]*u0[j2] + e1[i2]*u1[j2] + det*(e2[i2]*u2[j2]));
}

__device__ static inline float dist1(const float R[9], const float t[3], const float x[3], const float y[3])
{
    float a = R[0]*x[0]+R[1]*x[1]+R[2]*x[2]+t[0]-y[0];
    float b = R[3]*x[0]+R[4]*x[1]+R[5]*x[2]+t[1]-y[1];
    float c = R[6]*x[0]+R[7]*x[1]+R[8]*x[2]+t[2]-y[2];
    return sqrtf(a*a+b*b+c*c);
}

// weighted Procrustes over the wave's 512 samples (8 per lane); uniform result
__device__ static void proc512(const float (&X)[8][3], const float (&Y)[8][3], const float (&w)[8],
                               float R[9], float t[3])
{
    float sw = 0.f;
    #pragma unroll
    for (int q=0;q<8;++q) sw += w[q];
    float S = wred(sw) + 1e-8f;
    float wn[8];
    #pragma unroll
    for (int q=0;q<8;++q) wn[q] = w[q] / S;
    float mx[3], my[3];
    #pragma unroll
    for (int c=0;c<3;++c) {
        float ax=0.f, ay=0.f;
        #pragma unroll
        for (int q=0;q<8;++q) { ax += wn[q]*X[q][c]; ay += wn[q]*Y[q][c]; }
        mx[c] = wred(ax); my[c] = wred(ay);
    }
    float Hf[9];
    #pragma unroll
    for (int ci=0;ci<3;++ci)
      #pragma unroll
      for (int cj=0;cj<3;++cj) {
        float h=0.f;
        #pragma unroll
        for (int q=0;q<8;++q) h += wn[q]*(X[q][ci]-mx[ci])*(Y[q][cj]-my[cj]);
        Hf[ci*3+cj] = wred(h);
      }
    kabsch(Hf, R);
    #pragma unroll
    for (int c=0;c<3;++c) t[c] = my[c] - (R[c*3+0]*mx[0] + R[c*3+1]*mx[1] + R[c*3+2]*mx[2]);
}

// 3x3 inverse, pivoted Gauss-Jordan (mirrors jnp.linalg.inv up to ulps)
__device__ static void inv3(const float* __restrict__ Kin, float* __restrict__ out)
{
    float a[3][6];
    for (int r=0;r<3;++r) for (int c=0;c<3;++c) { a[r][c]=Kin[r*3+c]; a[r][c+3] = (r==c)?1.f:0.f; }
    for (int col=0; col<3; ++col) {
        int piv = col;
        for (int r=col+1;r<3;++r) if (fabsf(a[r][col]) > fabsf(a[piv][col])) piv = r;
        if (piv != col) for (int c=0;c<6;++c) { float tt=a[col][c]; a[col][c]=a[piv][c]; a[piv][c]=tt; }
        float pv = a[col][col];
        for (int c=0;c<6;++c) a[col][c] /= pv;
        for (int r=0;r<3;++r) if (r != col) {
            float f = a[r][col];
            if (f != 0.f) for (int c=0;c<6;++c) a[r][c] -= f * a[col][c];
        }
    }
    for (int r=0;r<3;++r) for (int c=0;c<3;++c) out[r*3+c] = a[r][c+3];
}

// ---------------- workspace layout (unchanged from R7) ----------------
static const size_t OFF_CNTS = 0;                                           // u32[ITM*NB*CHUNKS]
static const size_t OFF_SC   = OFF_CNTS + (size_t)ITM*NB*CHUNKS*4;          // f32[ITM*NB*ITR]
static const size_t OFF_LV   = OFF_SC   + (size_t)ITM*NB*ITR*4;             // f32[ITM*NB*ITR]
static const size_t OFF_SAMP = OFF_LV   + (size_t)ITM*NB*ITR*4;             // (unused now)
static const size_t OFF_CAND = OFF_SAMP + (size_t)ITM*NB*NSAMP*8*4;         // u64[ITM*NB*CHUNKS*SLOTS]

// survivor post-processing (shared by kA drain)
__device__ static inline void drain1(u64 e, float m, u64 (*lists)[SLOTS], u32* lcnt)
{
    u32 bits = (u32)(e >> 32);
    u32 i2 = ((u32)e >> 20) & 3u;
    u32 jj = (u32)e & 0xFFFFFu;
    float u = u_from_bits(bits);
    float g = -logf(-logf(u));
    float v = logf(m + 1e-12f) + g;
    if (v > 4.0f) {
        u32 p = atomicAdd(&lcnt[i2], 1u);
        if (p < (u32)SLOTS) lists[i2][p] = ((u64)fkey(v) << 32) | (u64)(u32)(~jj);
    }
}

// ---------------- Kernel A: ILP-4 threefry + wave-private queues, own-wave batched drain ----
// No barriers in the seg loop (queues are wave-private); drain issues 4 scattered loads
// before first use (latency /4). One block-wide barrier total, before the epilogue.
__global__ __launch_bounds__(256) void kA(const float* __restrict__ mat, Keys keys,
                                          u64* __restrict__ candC, u32* __restrict__ cnts)
{
    __shared__ u64 lists[ITM][SLOTS];   // 8 KB
    __shared__ u32 lcnt[ITM];
    __shared__ u64 q[4][WQ];            // 11 KB
    int tid = threadIdx.x;
    int lane = tid & 63;
    int wid = tid >> 6;
    u64 lmask_lt = (1ull << lane) - 1ull;
    if (tid < ITM) lcnt[tid] = 0;
    __syncthreads();
    int b = blockIdx.y;
    int chunk = blockIdx.x;
    const float* rowb = mat + (size_t)b * ROWN;
    u32 jbase = (u32)chunk * 16384u + (u32)tid;
    for (int seg = 0; seg < 2; ++seg) {
        u32 cnt = 0;   // wave-uniform (SGPR): this wave's queue fill
        #pragma unroll 1
        for (int lp = 0; lp < 32; ++lp) {
            u32 j = jbase + (u32)((seg*32 + lp) << 8);
            u32 flat = ((u32)b << 20) | j;
            u32 bits[ITM];
            tf4(keys, flat, bits);
            #pragma unroll
            for (int i = 0; i < ITM; ++i) {
                bool hit = (bits[i] >= EARLY_TH9);     // ~2% of lanes
                u64 mask = __ballot(hit);
                if (hit) {
                    u32 pos = cnt + (u32)__popcll(mask & lmask_lt);
                    if (pos < (u32)WQ)
                        q[wid][pos] = ((u64)bits[i] << 32) | ((u64)(u32)i << 20) | (u64)j;
                }
                cnt += (u32)__popcll(mask);
            }
        }
        // own-wave drain: no barrier, 4-wide batched scatter loads
        u32 qn = (cnt > (u32)WQ) ? (u32)WQ : cnt;
        for (u32 t0 = (u32)lane; t0 < qn; t0 += 256) {
            u32 t1 = t0 + 64, t2 = t0 + 128, t3 = t0 + 192;
            u64 e0 = q[wid][t0];
            float m0 = rowb[(u32)e0 & 0xFFFFFu];
            u64 e1 = 0, e2 = 0, e3 = 0;
            float m1 = 0.f, m2 = 0.f, m3 = 0.f;
            if (t1 < qn) { e1 = q[wid][t1]; m1 = rowb[(u32)e1 & 0xFFFFFu]; }
            if (t2 < qn) { e2 = q[wid][t2]; m2 = rowb[(u32)e2 & 0xFFFFFu]; }
            if (t3 < qn) { e3 = q[wid][t3]; m3 = rowb[(u32)e3 & 0xFFFFFu]; }
            drain1(e0, m0, lists, lcnt);
            if (t1 < qn) drain1(e1, m1, lists, lcnt);
            if (t2 < qn) drain1(e2, m2, lists, lcnt);
            if (t3 < qn) drain1(e3, m3, lists, lcnt);
        }
    }
    __syncthreads();
    #pragma unroll
    for (int i = 0; i < ITM; ++i) {
        u32 n = lcnt[i]; if (n > (u32)SLOTS) n = SLOTS;
        for (u32 s = tid; s < n; s += 256)
            candC[(((size_t)(i*NB + b))*CHUNKS + chunk)*SLOTS + s] = lists[i][s];
    }
    if (tid < ITM) cnts[((size_t)(tid*NB + b))*CHUNKS + chunk] = min(lcnt[tid], (u32)SLOTS);
}

// ---------------- Kernel DE: hist+cut+sort+backproject (LDS) + 8 RANSAC waves ----------------
// One block per (iter,b), 512 threads. samp never touches global memory.
__global__ __launch_bounds__(512) void kDE(const float* __restrict__ mat,
        const float* __restrict__ kps0, const float* __restrict__ dep0,
        const float* __restrict__ kps1, const float* __restrict__ dep1,
        const float* __restrict__ K0, const float* __restrict__ K1,
        const float* __restrict__ Tmat, Keys keys,
        const u64* __restrict__ candC, const u32* __restrict__ cnts,
        float* __restrict__ scoreArr, float* __restrict__ lvArr)
{
    int ib = blockIdx.x;
    int b = ib % NB;
    int i = ib / NB;
    int tid = threadIdx.x;
    int lane = tid & 63;
    int wid = tid >> 6;
    __shared__ u32 hist[NBIN];          // 8 KB
    __shared__ u64 buf[1024];           // 8 KB (cut-bin occupancy ~4 => nkeep ~516 << 1024)
    __shared__ float sampL[NSAMP][9];   // 18 KB, stride 9 (9 coprime 32: conflict-free)
    __shared__ u32 ccnt[CHUNKS];
    __shared__ u32 gs[64];
    __shared__ u32 nkeep, cutkey_s;
    __shared__ float Ki[2][9];
    for (int idx = tid; idx < NBIN; idx += 512) hist[idx] = 0;
    for (int idx = tid; idx < 1024; idx += 512) buf[idx] = 0ull;
    if (tid < CHUNKS) ccnt[tid] = cnts[(size_t)ib*CHUNKS + tid];
    if (tid == 0) nkeep = 0;
    __syncthreads();
    const u64* cd = candC + (size_t)ib * CHUNKS * SLOTS;
    // pass 1: histogram of candidate keys
    for (int t = tid; t < CHUNKS*SLOTS; t += 512) {
        int c = t >> 8, s = t & (SLOTS-1);
        if ((u32)s < ccnt[c]) {
            u32 key = (u32)(cd[t] >> 32);
            u32 bin = (key - KBASE) >> 14;
            if (bin > (u32)(NBIN-1)) bin = NBIN-1;
            atomicAdd(&hist[bin], 1u);
        }
    }
    __syncthreads();
    // exact rank-512 cut bin
    if (tid < 64) {
        u32 ssum = 0;
        int top = NBIN-1 - tid*32;
        for (int k = 0; k < 32; ++k) ssum += hist[top - k];
        gs[tid] = ssum;
    }
    __syncthreads();
    if (tid == 0) {
        u32 cum = 0; int cutbin = -1;
        for (int g = 0; g < 64; ++g) {
            if (cum + gs[g] >= (u32)NSAMP) {
                int t2 = NBIN-1 - g*32;
                for (int k = 0; k < 32; ++k) {
                    u32 c = hist[t2 - k];
                    if (cum + c >= (u32)NSAMP) { cutbin = t2 - k; break; }
                    cum += c;
                }
                break;
            }
            cum += gs[g];
        }
        cutkey_s = (cutbin >= 0) ? (KBASE + ((u32)cutbin << 14)) : 0u;
    }
    __syncthreads();
    u32 cutkey = cutkey_s;
    // pass 2: filter >= cutkey into sort buffer
    for (int t = tid; t < CHUNKS*SLOTS; t += 512) {
        int c = t >> 8, s = t & (SLOTS-1);
        if ((u32)s < ccnt[c]) {
            u64 cv = cd[t];
            if ((u32)(cv >> 32) >= cutkey) {
                u32 p = atomicAdd(&nkeep, 1u);
                if (p < 1024u) buf[p] = cv;
            }
        }
    }
    __syncthreads();
    // bitonic ascending over 1024; pads (0) sink to front; top-512 = buf[1023-r]
    for (int k = 2; k <= 1024; k <<= 1) {
        for (int j = k >> 1; j > 0; j >>= 1) {
            for (int i2 = tid; i2 < 1024; i2 += 512) {
                int ixj = i2 ^ j;
                if (ixj > i2) {
                    bool up = ((i2 & k) == 0);
                    u64 a = buf[i2], c2 = buf[ixj];
                    bool dosw = up ? (a > c2) : (a < c2);
                    if (dosw) { buf[i2] = c2; buf[ixj] = a; }
                }
            }
            __syncthreads();
        }
    }
    if (tid == 0) { inv3(K0 + (size_t)b*9, Ki[0]); inv3(K1 + (size_t)b*9, Ki[1]); }
    __syncthreads();
    // backproject into LDS sample table
    {
        int r = tid;
        if (r < NSAMP) {
            u64 c = buf[1023 - r];
            u32 j = (~(u32)(c & 0xFFFFFFFFull)) & (u32)(ROWN - 1);
            int i0 = (int)(j >> 10);
            int i1 = (int)(j & 1023u);
            float uu0 = kps0[(size_t)b*2*NKP + i0];
            float vv0 = kps0[(size_t)b*2*NKP + NKP + i0];
            float dd0 = dep0[(size_t)b*2*NKP + i0];
            float uu1 = kps1[(size_t)b*2*NKP + i1];
            float vv1 = kps1[(size_t)b*2*NKP + NKP + i1];
            float dd1 = dep1[(size_t)b*2*NKP + i1];
            float r0 = Ki[0][0]*uu0 + Ki[0][1]*vv0 + Ki[0][2];
            float r1 = Ki[0][3]*uu0 + Ki[0][4]*vv0 + Ki[0][5];
            float r2 = Ki[0][6]*uu0 + Ki[0][7]*vv0 + Ki[0][8];
            float q0 = Ki[1][0]*uu1 + Ki[1][1]*vv1 + Ki[1][2];
            float q1 = Ki[1][3]*uu1 + Ki[1][4]*vv1 + Ki[1][5];
            float q2 = Ki[1][6]*uu1 + Ki[1][7]*vv1 + Ki[1][8];
            float w = mat[(size_t)b*ROWN + j];
            sampL[r][0] = dd0*r0; sampL[r][1] = dd0*r1; sampL[r][2] = dd0*r2;
            sampL[r][3] = dd1*q0; sampL[r][4] = dd1*q1; sampL[r][5] = dd1*q2;
            sampL[r][6] = logf(w + 1e-12f);
        }
    }
    __syncthreads();
    // ---- phase 2: wave `wid` runs RANSAC hypothesis kk = wid ----
    int kk = wid;
    float X[8][3], Y[8][3], lw[8];
    #pragma unroll
    for (int q2 = 0; q2 < 8; ++q2) {
        const float* sp = &sampL[q2*64 + lane][0];
        X[q2][0]=sp[0]; X[q2][1]=sp[1]; X[q2][2]=sp[2];
        Y[q2][0]=sp[3]; Y[q2][1]=sp[4]; Y[q2][2]=sp[5];
        lw[q2]=sp[6];
    }
    u64 comp[8];
    #pragma unroll
    for (int q2 = 0; q2 < 8; ++q2) {
        u32 j = (u32)(q2*64 + lane);
        u32 o0,o1; tf2x32(keys.kr[i][kk][0], keys.kr[i][kk][1], 0u, (u32)(b*NSAMP) + j, o0,o1);
        float u = u_from_bits(o0^o1);
        float g = -logf(-logf(u));
        float v = lw[q2] + g;
        comp[q2] = ((u64)fkey(v) << 32) | (u64)(u32)(~j);
    }
    int ridx[5];
    #pragma unroll
    for (int r = 0; r < 5; ++r) {
        u64 m = comp[0];
        #pragma unroll
        for (int q2=1;q2<8;++q2) if (comp[q2] > m) m = comp[q2];
        #pragma unroll
        for (int o=1;o<64;o<<=1) { u64 x = shfl_xor_u64(m,o); if (x > m) m = x; }
        ridx[r] = (int)((~(u32)(m & 0xFFFFFFFFull)) & (u32)(NSAMP-1));
        #pragma unroll
        for (int q2=0;q2<8;++q2) if (comp[q2] == m) comp[q2] = 0ull;
    }
    float Xk[5][3], Yk[5][3];
    #pragma unroll
    for (int r=0;r<5;++r) {
        const float* p = &sampL[ridx[r]][0];    // uniform row per wave: LDS broadcast
        Xk[r][0]=p[0]; Xk[r][1]=p[1]; Xk[r][2]=p[2];
        Yk[r][0]=p[3]; Yk[r][1]=p[4]; Yk[r][2]=p[5];
    }
    float S5 = 5.0f + 1e-8f;
    float wn5 = 1.0f / S5;
    float mx[3]={0,0,0}, my[3]={0,0,0};
    #pragma unroll
    for (int r=0;r<5;++r) {
        #pragma unroll
        for (int c=0;c<3;++c) { mx[c] += wn5*Xk[r][c]; my[c] += wn5*Yk[r][c]; }
    }
    float Hf[9] = {0,0,0,0,0,0,0,0,0};
    #pragma unroll
    for (int r=0;r<5;++r)
      #pragma unroll
      for (int ci=0;ci<3;++ci)
        #pragma unroll
        for (int cj=0;cj<3;++cj)
          Hf[ci*3+cj] += wn5*(Xk[r][ci]-mx[ci])*(Yk[r][cj]-my[cj]);
    float Rpre[9], tpre[3];
    kabsch(Hf, Rpre);
    #pragma unroll
    for (int c=0;c<3;++c) tpre[c] = my[c] - (Rpre[c*3+0]*mx[0] + Rpre[c*3+1]*mx[1] + Rpre[c*3+2]*mx[2]);
    const float BETAF = (float)(5.0/0.15);
    float partial = 0.f;
    #pragma unroll
    for (int q2=0;q2<8;++q2) {
        float d = dist1(Rpre, tpre, X[q2], Y[q2]);
        float z = BETAF * (0.15f - d);
        partial += 1.0f / (1.0f + expf(-z));
    }
    float score = wred(partial);
    float inlref[8];
    #pragma unroll
    for (int q2=0;q2<8;++q2) {
        int j = q2*64 + lane;
        inlref[q2] = (j==ridx[0] || j==ridx[1] || j==ridx[2] || j==ridx[3] || j==ridx[4]) ? 1.0f : 0.0f;
    }
    float Rd[9], td[3];
    #pragma unroll
    for (int c2=0;c2<9;++c2) Rd[c2]=Rpre[c2];
    td[0]=tpre[0]; td[1]=tpre[1]; td[2]=tpre[2];
    float inl_pre = 0.f;
    for (int step=0; step<4; ++step) {
        float inl[8]; float csum = 0.f;
        #pragma unroll
        for (int q2=0;q2<8;++q2) {
            float d = dist1(Rd, td, X[q2], Y[q2]);
            inl[q2] = (d < 0.15f) ? 1.0f : 0.0f;
            csum += inl[q2];
        }
        float cnt = wred(csum);
        bool doit = (cnt >= 5.0f) && (cnt > inl_pre);
        inl_pre = cnt;
        if (doit) {
            #pragma unroll
            for (int q2=0;q2<8;++q2) inlref[q2] = inl[q2];
            proc512(X, Y, inlref, Rd, td);
        }
    }
    float Rfin[9], tfin[3];
    proc512(X, Y, inlref, Rfin, tfin);
    const float* Tb = Tmat + (size_t)b*16;
    float tr = 0.f;
    #pragma unroll
    for (int ci=0;ci<3;++ci)
      #pragma unroll
      for (int cj=0;cj<3;++cj)
        tr += Rfin[ci*3+cj] * Tb[ci*4+cj];
    float cosang = (tr - 1.0f) * 0.5f;
    cosang = fminf(fmaxf(cosang, -0.999999f), 0.999999f);
    float ang = acosf(cosang);
    float d0 = tfin[0]-Tb[3], d1 = tfin[1]-Tb[7], d2 = tfin[2]-Tb[11];
    float terr = sqrtf(d0*d0 + d1*d1 + d2*d2);
    float lr = 0.5f * tanhf(ang / 0.5f);
    float lt = 0.5f * tanhf(terr / 0.5f);
    float lv = 0.5f * (lr + lt);
    if (lane == 0) { scoreArr[ib*ITR + kk] = score; lvArr[ib*ITR + kk] = lv; }
}

// ---------------- Kernel F: softmax mixing + output ----------------
__global__ void kF(const float* __restrict__ scoreArr, const float* __restrict__ lvArr, float* __restrict__ out)
{
    int b = threadIdx.x;
    if (b >= NB) return;
    const float NULLSC = (float)(0.35 * 512.0);
    float total = 0.f;
    for (int i = 0; i < ITM; ++i) {
        float x[9], lvv[9], ee[9];
        for (int k = 0; k < 8; ++k) {
            x[k] = scoreArr[(i*NB + b)*ITR + k] / 10.0f;
            lvv[k] = lvArr[(i*NB + b)*ITR + k];
        }
        x[8] = NULLSC / 10.0f;
        lvv[8] = 0.5f;
        float m = x[0];
        for (int k = 1; k < 9; ++k) m = fmaxf(m, x[k]);
        float Ssum = 0.f;
        for (int k = 0; k < 9; ++k) { ee[k] = expf(x[k] - m); Ssum += ee[k]; }
        float acc = 0.f;
        for (int k = 0; k < 9; ++k) acc += lvv[k] * (ee[k] / Ssum);
        total += acc;
    }
    out[b] = total / 4.0f;
}

// ---------------- host ----------------
extern "C" void kernel_launch(void* const* d_in, const int* in_sizes, int n_in,
                              void* d_out, int out_size, void* d_ws, size_t ws_size,
                              hipStream_t stream)
{
    (void)in_sizes; (void)n_in; (void)out_size; (void)ws_size;
    const float* mat  = (const float*)d_in[0];
    const float* kps0 = (const float*)d_in[1];
    const float* dep0 = (const float*)d_in[2];
    const float* kps1 = (const float*)d_in[3];
    const float* dep1 = (const float*)d_in[4];
    const float* K0   = (const float*)d_in[5];
    const float* K1   = (const float*)d_in[6];
    const float* Tm   = (const float*)d_in[8];
    float* out = (float*)d_out;

    // JAX key schedule: key(42) -> (0,42); split() in partitionable (fold-like) mode
    Keys keys;
    {
        u32 k0 = 0u, k1 = 42u;
        for (int i = 0; i < ITM; ++i) {
            u32 a0,a1,b0,b1;
            tf2x32(k0,k1, 0u,0u, a0,a1);
            tf2x32(k0,k1, 0u,1u, b0,b1);
            k0=a0; k1=a1; keys.km[i][0]=b0; keys.km[i][1]=b1;
            for (int kk = 0; kk < ITR; ++kk) {
                tf2x32(k0,k1, 0u,0u, a0,a1);
                tf2x32(k0,k1, 0u,1u, b0,b1);
                k0=a0; k1=a1; keys.kr[i][kk][0]=b0; keys.kr[i][kk][1]=b1;
            }
        }
    }
    char* ws = (char*)d_ws;
    u32* cnts       = (u32*)(ws + OFF_CNTS);
    float* scoreArr = (float*)(ws + OFF_SC);
    float* lvArr    = (float*)(ws + OFF_LV);
    u64* candC      = (u64*)(ws + OFF_CAND);

    kA<<<dim3(CHUNKS, NB), 256, 0, stream>>>(mat, keys, candC, cnts);
    kDE<<<ITM*NB, 512, 0, stream>>>(mat, kps0, dep0, kps1, dep1, K0, K1, Tm, keys,
                                    candC, cnts, scoreArr, lvArr);
    kF<<<1, 64, 0, stream>>>(scoreArr, lvArr, out);
}